// Round 10
// baseline (434.395 us; speedup 1.0000x reference)
//
#include <hip/hip_runtime.h>

// ---------------------------------------------------------------------------
// MalwareGNN: 3-layer GCN (transform -> normalized aggregate) + mean pool + FC
//   * detect int32 vs int64 indices on device (flag in ws)
//   * CSR build, NO global-atomic histograms, NO write amplification:
//       p1 k_bucket : 8 capacity-sliced range buckets of (dst,src) pairs
//       p2 k_bucket2: each range -> 64 capacity-sliced sub-buckets (512 total)
//       p3 k_subdeg : block-per-sub-bucket LDS histogram -> DENSE deg+dinv
//       scan        : deg -> rowptr
//       p4 k_csr    : block-per-sub-bucket, LDS cursors = rowptr[d]
//   * per layer: MFMA GEMM hs = bf16(dinv*(X@W)), 64x64 tile, swizzled LDS
//   * gather-aggregate: wave-per-node; lane owns FEATURE PAIR (2c,2c+1);
//     lower/upper 32 lanes process even/odd edges -> one ushort2 load covers
//     2 neighbor rows; bf16->f32 via bit-ops; __shfl_xor(32) epilogue
//   * self-loops analytic: out = relu(dinv*(hs[i]+sum hs[src])+b)
//   * mean-pool via per-graph binary search on sorted batch, then tiny FC
// ---------------------------------------------------------------------------

#define RGRP 8
#define NSUB 512
#define SUB_PER 64   // NSUB / RGRP
#define MAXNODES 256 // >= ceil(N/NSUB); N=100k -> 196

typedef __attribute__((ext_vector_type(8))) short bf16x8;
typedef __attribute__((ext_vector_type(4))) float f32x4;

__device__ __forceinline__ unsigned short f2bf(float x) {
  unsigned u = __float_as_uint(x);
  u += 0x7FFFu + ((u >> 16) & 1u);  // RNE
  return (unsigned short)(u >> 16);
}
__device__ __forceinline__ float bf2f(unsigned short h) {
  return __uint_as_float((unsigned)h << 16);
}

__global__ void k_detect(const unsigned* __restrict__ ei, int* __restrict__ flag) {
  __shared__ int any;
  if (threadIdx.x == 0) any = 0;
  __syncthreads();
  unsigned v = 0;
  for (int i = threadIdx.x; i < 8192; i += blockDim.x) v |= ei[2 * i + 1];
  if (v) atomicOr(&any, 1);
  __syncthreads();
  if (threadIdx.x == 0) *flag = (any == 0) ? 1 : 0;  // 1 => int64 indices
}

__device__ __forceinline__ int load_idx(const void* p, long long i, bool wide) {
  if (wide) {
    long long v = __builtin_nontemporal_load((const long long*)p + i);
    return (int)v;
  }
  return __builtin_nontemporal_load((const int*)p + i);
}

// p1: per-block chunk -> count 8 ranges in LDS, reserve, dense pair writes
__global__ __launch_bounds__(256) void k_bucket(const void* __restrict__ ei, int E,
                                                const int* __restrict__ flag,
                                                int cap1, int* __restrict__ bcur,
                                                long long* __restrict__ ebuf, int N) {
  __shared__ int sh_cnt[RGRP];
  __shared__ int sh_base[RGRP];
  __shared__ int sh_off[RGRP];
  const bool wide = (*flag != 0);
  const int chunk = (E + gridDim.x - 1) / gridDim.x;
  const int c0 = blockIdx.x * chunk;
  const int c1 = (c0 + chunk < E) ? c0 + chunk : E;
  if (threadIdx.x < RGRP) { sh_cnt[threadIdx.x] = 0; sh_off[threadIdx.x] = 0; }
  __syncthreads();
  for (int e = c0 + threadIdx.x; e < c1; e += 256) {
    const int d = load_idx(ei, (long long)E + e, wide);
    const int r = (int)(((long long)d * RGRP) / N);
    atomicAdd(&sh_cnt[r], 1);
  }
  __syncthreads();
  if (threadIdx.x < RGRP)
    sh_base[threadIdx.x] = atomicAdd(&bcur[threadIdx.x], sh_cnt[threadIdx.x]);
  __syncthreads();
  const long long cap = (long long)RGRP * cap1;
  for (int e = c0 + threadIdx.x; e < c1; e += 256) {
    const int d = load_idx(ei, (long long)E + e, wide);
    const int s = load_idx(ei, e, wide);
    const int r = (int)(((long long)d * RGRP) / N);
    const int o = atomicAdd(&sh_off[r], 1);
    long long pos = (long long)r * cap1 + sh_base[r] + o;
    if (pos >= cap) pos = cap - 1;  // paranoia clamp (slack makes this dead)
    ebuf[pos] = ((long long)(unsigned)d << 32) | (unsigned)s;
  }
}

// p2: range bucket -> 64 capacity-sliced sub-buckets
__global__ __launch_bounds__(256) void k_bucket2(const long long* __restrict__ ebuf,
                                                 const int* __restrict__ bcur,
                                                 int cap1, int cap2,
                                                 int* __restrict__ scur,
                                                 long long* __restrict__ ebuf2, int N) {
  __shared__ int cnt[SUB_PER];
  __shared__ int base[SUB_PER];
  __shared__ int off[SUB_PER];
  const int r = blockIdx.x & (RGRP - 1);
  const int cb = blockIdx.x >> 3;
  const int nch = gridDim.x >> 3;
  const long long e0 = (long long)r * cap1;
  const long long e1 = e0 + bcur[r];
  const int total = (int)(e1 - e0);
  const int chunk = (total + nch - 1) / nch;
  const long long c0 = e0 + (long long)cb * chunk;
  long long c1 = c0 + chunk;
  if (c1 > e1) c1 = e1;
  if (threadIdx.x < SUB_PER) { cnt[threadIdx.x] = 0; off[threadIdx.x] = 0; }
  __syncthreads();
  for (long long e = c0 + threadIdx.x; e < c1; e += 256) {
    const int d = (int)(ebuf[e] >> 32);
    const int ls = (int)(((long long)d * NSUB) / N) - r * SUB_PER;
    atomicAdd(&cnt[ls], 1);
  }
  __syncthreads();
  if (threadIdx.x < SUB_PER) {
    const int s = r * SUB_PER + threadIdx.x;
    base[threadIdx.x] = atomicAdd(&scur[s], cnt[threadIdx.x]);
  }
  __syncthreads();
  const long long cap = (long long)NSUB * cap2;
  for (long long e = c0 + threadIdx.x; e < c1; e += 256) {
    const long long v = ebuf[e];
    const int d = (int)(v >> 32);
    const int ls = (int)(((long long)d * NSUB) / N) - r * SUB_PER;
    const int o = atomicAdd(&off[ls], 1);
    long long pos = (long long)(r * SUB_PER + ls) * cap2 + base[ls] + o;
    if (pos >= cap) pos = cap - 1;  // paranoia clamp
    ebuf2[pos] = v;
  }
}

// p3: per-sub-bucket LDS histogram -> dense deg + dinv writes (fused)
__global__ __launch_bounds__(256) void k_subdeg(const long long* __restrict__ ebuf2,
                                                const int* __restrict__ scur, int cap2,
                                                int* __restrict__ deg,
                                                float* __restrict__ dinv, int N) {
  __shared__ int hist[MAXNODES];
  const int s = blockIdx.x;
  int nlo = (int)(((long long)N * s + NSUB - 1) / NSUB);
  int nhi = (int)(((long long)N * (s + 1) + NSUB - 1) / NSUB);
  if (nhi > N) nhi = N;
  const int nn = nhi - nlo;
  for (int i = threadIdx.x; i < nn; i += 256) hist[i] = 0;
  __syncthreads();
  const long long e0 = (long long)s * cap2;
  const long long e1 = e0 + scur[s];
  for (long long e = e0 + threadIdx.x; e < e1; e += 256) {
    const int d = (int)(__builtin_nontemporal_load(&ebuf2[e]) >> 32);
    atomicAdd(&hist[d - nlo], 1);
  }
  __syncthreads();
  for (int i = threadIdx.x; i < nn; i += 256) {
    const int h = hist[i];
    deg[nlo + i] = h;
    dinv[nlo + i] = rsqrtf((float)(h + 1));  // +1 self loop
  }
}

// ---- exclusive scan of deg[N] -> rowptr[N+1], 2048 items/block -------------
__global__ void k_scan_a(const int* __restrict__ deg, int N, int* __restrict__ bsum) {
  __shared__ int sh[256];
  int base = blockIdx.x * 2048;
  int s = 0;
  for (int i = threadIdx.x; i < 2048; i += 256) {
    int idx = base + i;
    s += (idx < N) ? deg[idx] : 0;
  }
  sh[threadIdx.x] = s;
  __syncthreads();
  for (int off = 128; off > 0; off >>= 1) {
    if (threadIdx.x < off) sh[threadIdx.x] += sh[threadIdx.x + off];
    __syncthreads();
  }
  if (threadIdx.x == 0) bsum[blockIdx.x] = sh[0];
}

__global__ void k_scan_b(int* __restrict__ bsum, int nb) {
  if (threadIdx.x == 0) {
    int run = 0;
    for (int i = 0; i < nb; ++i) { int v = bsum[i]; bsum[i] = run; run += v; }
    bsum[nb] = run;
  }
}

__global__ void k_scan_c(const int* __restrict__ deg, int N, const int* __restrict__ bsum,
                         int* __restrict__ rowptr, int nb) {
  __shared__ int sh[256];
  int base = blockIdx.x * 2048;
  int v[8];
  int s = 0;
#pragma unroll
  for (int j = 0; j < 8; ++j) {
    int idx = base + threadIdx.x * 8 + j;
    v[j] = (idx < N) ? deg[idx] : 0;
    s += v[j];
  }
  sh[threadIdx.x] = s;
  __syncthreads();
  for (int off = 1; off < 256; off <<= 1) {
    int t = (threadIdx.x >= off) ? sh[threadIdx.x - off] : 0;
    __syncthreads();
    sh[threadIdx.x] += t;
    __syncthreads();
  }
  int excl = (threadIdx.x ? sh[threadIdx.x - 1] : 0) + bsum[blockIdx.x];
#pragma unroll
  for (int j = 0; j < 8; ++j) {
    int idx = base + threadIdx.x * 8 + j;
    if (idx < N) rowptr[idx] = excl;
    excl += v[j];
  }
  if (blockIdx.x == gridDim.x - 1 && threadIdx.x == 255) rowptr[N] = bsum[nb];
}

// p4: block-per-sub-bucket; LDS cursors start at rowptr[d]
__global__ __launch_bounds__(256) void k_csr(const long long* __restrict__ ebuf2,
                                             const int* __restrict__ scur, int cap2,
                                             const int* __restrict__ rowptr,
                                             int* __restrict__ csr, int N) {
  __shared__ int lcur[MAXNODES];
  const int s = blockIdx.x;
  int nlo = (int)(((long long)N * s + NSUB - 1) / NSUB);
  int nhi = (int)(((long long)N * (s + 1) + NSUB - 1) / NSUB);
  if (nhi > N) nhi = N;
  const int nn = nhi - nlo;
  for (int i = threadIdx.x; i < nn; i += 256) lcur[i] = rowptr[nlo + i];
  __syncthreads();
  const long long e0 = (long long)s * cap2;
  const long long e1 = e0 + scur[s];
  for (long long e = e0 + threadIdx.x; e < e1; e += 256) {
    const long long v = __builtin_nontemporal_load(&ebuf2[e]);
    const int d = (int)(v >> 32);
    const int pos = atomicAdd(&lcur[d - nlo], 1);
    csr[pos] = (int)v;
  }
}

// ---- HS = bf16(dinv * (X @ W)) via MFMA ------------------------------------
template <int K>
__global__ __launch_bounds__(256) void k_gemm_mfma(const float* __restrict__ X,
                                                   const float* __restrict__ Wg,
                                                   const float* __restrict__ dinv,
                                                   unsigned short* __restrict__ HS,
                                                   int N) {
  __shared__ short Xl[64 * K];
  __shared__ short Wt[64 * K];
  const int t = threadIdx.x;
  const long long r0 = (long long)blockIdx.x * 64;
  const int rows = (int)((N - r0) < 64 ? (N - r0) : 64);

  // stage W^T (bf16, swizzled): Wt[n][k]
  for (int idx = t; idx < K * 64; idx += 256) {
    const int k = idx >> 6, n = idx & 63;
    Wt[n * K + (((k >> 3) ^ (n & 7)) << 3) + (k & 7)] = (short)f2bf(Wg[idx]);
  }
  // stage X (bf16, swizzled): chunks of 8 values
  const int CH = K / 8;
#pragma unroll
  for (int p = 0; p < K / 32; ++p) {
    const int c = p * 256 + t;  // c < 64*CH
    const int row = c / CH, ch = c % CH;
    const int src = (row < rows) ? row : 0;
    const float4 v0 = *(const float4*)&X[(r0 + src) * K + ch * 8];
    const float4 v1 = *(const float4*)&X[(r0 + src) * K + ch * 8 + 4];
    bf16x8 h;
    h[0] = (short)f2bf(v0.x); h[1] = (short)f2bf(v0.y);
    h[2] = (short)f2bf(v0.z); h[3] = (short)f2bf(v0.w);
    h[4] = (short)f2bf(v1.x); h[5] = (short)f2bf(v1.y);
    h[6] = (short)f2bf(v1.z); h[7] = (short)f2bf(v1.w);
    *(bf16x8*)&Xl[row * K + ((ch ^ (row & 7)) << 3)] = h;
  }
  __syncthreads();

  const int lane = t & 63, w = t >> 6;
  const int lo = lane & 15, hi = lane >> 4;
  const int rowa = w * 16 + lo;

  f32x4 acc[4];
#pragma unroll
  for (int i = 0; i < 4; ++i) acc[i] = (f32x4){0.f, 0.f, 0.f, 0.f};

  bf16x8 a[K / 32];
#pragma unroll
  for (int kk = 0; kk < K / 32; ++kk)
    a[kk] = *(const bf16x8*)&Xl[rowa * K + (((kk * 4 + hi) ^ (rowa & 7)) << 3)];

#pragma unroll
  for (int n0 = 0; n0 < 4; ++n0) {
    const int n = n0 * 16 + lo;
#pragma unroll
    for (int kk = 0; kk < K / 32; ++kk) {
      const bf16x8 b = *(const bf16x8*)&Wt[n * K + (((kk * 4 + hi) ^ (n & 7)) << 3)];
      acc[n0] = __builtin_amdgcn_mfma_f32_16x16x32_bf16(a[kk], b, acc[n0], 0, 0, 0);
    }
  }

  float dv[4];
#pragma unroll
  for (int r = 0; r < 4; ++r) {
    const int rr = w * 16 + hi * 4 + r;
    dv[r] = dinv[r0 + (rr < rows ? rr : 0)];
  }
#pragma unroll
  for (int n0 = 0; n0 < 4; ++n0) {
#pragma unroll
    for (int r = 0; r < 4; ++r) {
      const int rr = w * 16 + hi * 4 + r;
      if (rr < rows)
        HS[(r0 + rr) * 64 + n0 * 16 + lo] = f2bf(dv[r] * acc[n0][r]);
    }
  }
}

// ---- out[i] = relu(dinv[i]*(hs[i] + sum_{src in(i)} hs[src]) + b) ----------
// Lane owns feature pair (2c, 2c+1); lower/upper 32 lanes take even/odd
// edges. One ushort2 load covers 2 rows; bf16->f32 via bit-ops.
__global__ void k_agg(const unsigned short* __restrict__ HS, const int* __restrict__ rowptr,
                      const int* __restrict__ csr, const float* __restrict__ dinv,
                      const float* __restrict__ bias, float* __restrict__ OUT, int N) {
  const int lane = threadIdx.x & 63;
  const int wid = threadIdx.x >> 6;
  const int wavesPerBlock = blockDim.x >> 6;
  const int c = lane & 31;   // feature pair
  const int half = lane >> 5;
  const float b_lo = bias[2 * c];
  const float b_hi = bias[2 * c + 1];
  const unsigned* __restrict__ H32 = (const unsigned*)HS;  // row = 32 x u32
  for (int node = blockIdx.x * wavesPerBlock + wid; node < N;
       node += wavesPerBlock * gridDim.x) {
    const int s0 = rowptr[node], s1 = rowptr[node + 1];
    float alo0 = 0.f, ahi0 = 0.f, alo1 = 0.f, ahi1 = 0.f;
    if (half == 0) {  // self loop once
      const unsigned u = H32[(long long)node * 32 + c];
      alo0 += __uint_as_float(u << 16);
      ahi0 += __uint_as_float(u & 0xffff0000u);
    }
    for (int base = s0; base < s1; base += 64) {
      int m = s1 - base;
      if (m > 64) m = 64;
      const int idx = (base + lane < s1) ? csr[base + lane] : 0;
      const int npairs = m >> 1;
      int jj = 0;
      for (; jj + 2 <= npairs; jj += 2) {
        const int e0 = __shfl(idx, 2 * jj + half, 64);
        const int e1 = __shfl(idx, 2 * jj + 2 + half, 64);
        const unsigned u0 = H32[(long long)e0 * 32 + c];
        const unsigned u1 = H32[(long long)e1 * 32 + c];
        alo0 += __uint_as_float(u0 << 16);
        ahi0 += __uint_as_float(u0 & 0xffff0000u);
        alo1 += __uint_as_float(u1 << 16);
        ahi1 += __uint_as_float(u1 & 0xffff0000u);
      }
      for (; jj < npairs; ++jj) {
        const int e0 = __shfl(idx, 2 * jj + half, 64);
        const unsigned u0 = H32[(long long)e0 * 32 + c];
        alo0 += __uint_as_float(u0 << 16);
        ahi0 += __uint_as_float(u0 & 0xffff0000u);
      }
      if (m & 1) {  // odd tail edge, lower half only
        const int e = __shfl(idx, m - 1, 64);
        if (half == 0) {
          const unsigned u = H32[(long long)e * 32 + c];
          alo0 += __uint_as_float(u << 16);
          ahi0 += __uint_as_float(u & 0xffff0000u);
        }
      }
    }
    float alo = alo0 + alo1;
    float ahi = ahi0 + ahi1;
    alo += __shfl_xor(alo, 32, 64);
    ahi += __shfl_xor(ahi, 32, 64);
    if (half == 0) {
      const float dv = dinv[node];
      float2 o;
      o.x = fmaxf(fmaf(dv, alo, b_lo), 0.f);
      o.y = fmaxf(fmaf(dv, ahi, b_hi), 0.f);
      *(float2*)&OUT[(long long)node * 64 + 2 * c] = o;
    }
  }
}

// ---- mean pool per graph (batch is sorted) ---------------------------------
__global__ void k_pool(const float* __restrict__ H, const void* __restrict__ batch,
                       const int* __restrict__ flag, float* __restrict__ pooled, int N) {
  __shared__ int se[2];
  __shared__ float red[4][64];
  bool wide = (*flag != 0);
  int g = blockIdx.x;
  if (threadIdx.x < 2) {
    int target = g + threadIdx.x;
    int lo = 0, hi = N;
    while (lo < hi) {
      int mid = (lo + hi) >> 1;
      long long v = wide ? ((const long long*)batch)[mid] : (long long)((const int*)batch)[mid];
      if (v < target) lo = mid + 1; else hi = mid;
    }
    se[threadIdx.x] = lo;
  }
  __syncthreads();
  int s = se[0], e = se[1];
  int lane = threadIdx.x & 63, wid = threadIdx.x >> 6;
  float acc = 0.f;
  for (int r = s + wid; r < e; r += 4) acc += H[(long long)r * 64 + lane];
  red[wid][lane] = acc;
  __syncthreads();
  if (wid == 0) {
    float v = red[0][lane] + red[1][lane] + red[2][lane] + red[3][lane];
    float cnt = (float)(e - s);
    pooled[g * 64 + lane] = v / fmaxf(cnt, 1.f);
  }
}

__global__ void k_classify(const float* __restrict__ pooled, const float* __restrict__ Wc,
                           const float* __restrict__ bc, float* __restrict__ out, int total) {
  int t = blockIdx.x * blockDim.x + threadIdx.x;
  if (t >= total) return;
  int g = t / 10, c = t % 10;
  float acc = bc[c];
#pragma unroll
  for (int h = 0; h < 64; ++h) acc += pooled[g * 64 + h] * Wc[h * 10 + c];
  out[t] = acc;
}

extern "C" void kernel_launch(void* const* d_in, const int* in_sizes, int n_in,
                              void* d_out, int out_size, void* d_ws, size_t ws_size,
                              hipStream_t stream) {
  const float* x = (const float*)d_in[0];
  const void* ei = d_in[1];
  const void* batch = d_in[2];
  const float* W1 = (const float*)d_in[3];
  const float* b1 = (const float*)d_in[4];
  const float* W2 = (const float*)d_in[5];
  const float* b2 = (const float*)d_in[6];
  const float* W3 = (const float*)d_in[7];
  const float* b3 = (const float*)d_in[8];
  const float* Wc = (const float*)d_in[9];
  const float* bc = (const float*)d_in[10];
  float* out = (float*)d_out;

  const int N = in_sizes[0] / 128;
  const int E = in_sizes[1] / 2;
  const int G = out_size / 10;
  const int NB = (N + 2047) / 2048;
  const int cap1 = E / RGRP + E / RGRP / 16 + 256;   // ~6% slack
  const int cap2 = E / NSUB + E / NSUB / 8 + 64;     // ~12.5% slack

  char* W = (char*)d_ws;
  size_t off = 0;
  auto take = [&](size_t b) -> void* {
    void* p = W + off;
    off += (b + 255) & ~(size_t)255;
    return p;
  };
  int* flag = (int*)take(4);
  int* deg = (int*)take((size_t)4 * N);
  int* rowptr = (int*)take((size_t)4 * (N + 1));
  int* bsum = (int*)take((size_t)4 * (NB + 1));
  int* bcur = (int*)take((size_t)4 * RGRP);
  int* scur = (int*)take((size_t)4 * NSUB);
  float* dinv = (float*)take((size_t)4 * N);
  int* csr = (int*)take((size_t)4 * E);
  unsigned short* hs = (unsigned short*)take((size_t)2 * N * 64);
  // two big regions, time-shared: {ebuf}, {ebuf2 -> cur}
  size_t bigBytes = (size_t)8 * RGRP * cap1;
  if ((size_t)8 * NSUB * cap2 > bigBytes) bigBytes = (size_t)8 * NSUB * cap2;
  if ((size_t)4 * N * 64 > bigBytes) bigBytes = (size_t)4 * N * 64;
  void* big0 = take(bigBytes);
  void* big1 = take(bigBytes);
  float* pooled = (float*)take((size_t)4 * G * 64);
  (void)ws_size;

  long long* ebuf = (long long*)big0;
  long long* ebuf2 = (long long*)big1;
  float* cur = (float*)big0;  // layer outputs (f32) reuse big0 after k_bucket2
  // ebuf dead after k_bucket2; ebuf2 live until k_csr; cur first written by
  // k_agg (after k_csr) -> aliasing is safe.

  hipMemsetAsync(bcur, 0, (size_t)4 * RGRP, stream);
  hipMemsetAsync(scur, 0, (size_t)4 * NSUB, stream);

  k_detect<<<1, 256, 0, stream>>>((const unsigned*)ei, flag);
  k_bucket<<<1024, 256, 0, stream>>>(ei, E, flag, cap1, bcur, ebuf, N);
  k_bucket2<<<256, 256, 0, stream>>>(ebuf, bcur, cap1, cap2, scur, ebuf2, N);
  k_subdeg<<<NSUB, 256, 0, stream>>>(ebuf2, scur, cap2, deg, dinv, N);
  k_scan_a<<<NB, 256, 0, stream>>>(deg, N, bsum);
  k_scan_b<<<1, 64, 0, stream>>>(bsum, NB);
  k_scan_c<<<NB, 256, 0, stream>>>(deg, N, bsum, rowptr, NB);
  k_csr<<<NSUB, 256, 0, stream>>>(ebuf2, scur, cap2, rowptr, csr, N);

  const int TILES = (N + 63) / 64;
  // layer 1: x[N,128] @ W1 -> hs (bf16); aggregate -> cur (f32)
  k_gemm_mfma<128><<<TILES, 256, 0, stream>>>(x, W1, dinv, hs, N);
  k_agg<<<4096, 256, 0, stream>>>(hs, rowptr, csr, dinv, b1, cur, N);
  // layer 2
  k_gemm_mfma<64><<<TILES, 256, 0, stream>>>(cur, W2, dinv, hs, N);
  k_agg<<<4096, 256, 0, stream>>>(hs, rowptr, csr, dinv, b2, cur, N);
  // layer 3
  k_gemm_mfma<64><<<TILES, 256, 0, stream>>>(cur, W3, dinv, hs, N);
  k_agg<<<4096, 256, 0, stream>>>(hs, rowptr, csr, dinv, b3, cur, N);

  k_pool<<<G, 256, 0, stream>>>(cur, batch, flag, pooled, N);
  k_classify<<<(G * 10 + 255) / 256, 256, 0, stream>>>(pooled, Wc, bc, out, G * 10);
}

// Round 11
// 401.171 us; speedup vs baseline: 1.0828x; 1.0828x over previous
//
#include <hip/hip_runtime.h>

// ---------------------------------------------------------------------------
// MalwareGNN: 3-layer GCN (transform -> normalized aggregate) + mean pool + FC
//   * detect int32 vs int64 indices on device (flag in ws); index loads are
//     4B (low word) either way since values < 2^31
//   * CSR build, NO global-atomic histograms, NO write amplification:
//       p1 k_bucket : 8 capacity-sliced range buckets of (dst,src) pairs
//       p2 k_bucket2: each range -> 64 capacity-sliced sub-buckets (512 total)
//       p3 k_subdeg : block-per-sub-bucket LDS histogram -> DENSE deg+dinv
//       scan        : deg -> rowptr
//       p4 k_csr    : block-per-sub-bucket, LDS cursors = rowptr[d]
//   * per layer: MFMA GEMM hs = bf16(dinv*(X@W)), 64x64 tile, swizzled LDS;
//     layer-1 input f32, layers 2/3 input bf16 (cur is bf16 end-to-end; the
//     GEMM quantizes its input to bf16 at staging anyway -> no extra error)
//   * gather-aggregate: wave-per-node; lane owns feature pair; lower/upper 32
//     lanes take even/odd edges; 4 ushort2 loads in flight (latency test);
//     bf16 packed output
//   * mean-pool via per-graph binary search on sorted batch, then tiny FC
// ---------------------------------------------------------------------------

#define RGRP 8
#define NSUB 512
#define SUB_PER 64   // NSUB / RGRP
#define MAXNODES 256 // >= ceil(N/NSUB); N=100k -> 196

typedef __attribute__((ext_vector_type(8))) short bf16x8;
typedef __attribute__((ext_vector_type(4))) float f32x4;

__device__ __forceinline__ unsigned short f2bf(float x) {
  unsigned u = __float_as_uint(x);
  u += 0x7FFFu + ((u >> 16) & 1u);  // RNE
  return (unsigned short)(u >> 16);
}
__device__ __forceinline__ float bf2f(unsigned short h) {
  return __uint_as_float((unsigned)h << 16);
}

__global__ void k_detect(const unsigned* __restrict__ ei, int* __restrict__ flag) {
  __shared__ int any;
  if (threadIdx.x == 0) any = 0;
  __syncthreads();
  unsigned v = 0;
  for (int i = threadIdx.x; i < 8192; i += blockDim.x) v |= ei[2 * i + 1];
  if (v) atomicOr(&any, 1);
  __syncthreads();
  if (threadIdx.x == 0) *flag = (any == 0) ? 1 : 0;  // 1 => int64 indices
}

// low 4B of index i (values < 2^31 so low word == value)
__device__ __forceinline__ int idx32(const int* p, long long i, bool wide) {
  return __builtin_nontemporal_load(p + (wide ? 2 * i : i));
}

// p1: per-block chunk -> count 8 ranges in LDS, reserve, dense pair writes
__global__ __launch_bounds__(256) void k_bucket(const void* __restrict__ eiv, int E,
                                                const int* __restrict__ flag,
                                                int cap1, int* __restrict__ bcur,
                                                long long* __restrict__ ebuf, int N) {
  __shared__ int sh_cnt[RGRP];
  __shared__ int sh_base[RGRP];
  __shared__ int sh_off[RGRP];
  const int* ei = (const int*)eiv;
  const bool wide = (*flag != 0);
  const int chunk = (E + gridDim.x - 1) / gridDim.x;
  const int c0 = blockIdx.x * chunk;
  const int c1 = (c0 + chunk < E) ? c0 + chunk : E;
  if (threadIdx.x < RGRP) { sh_cnt[threadIdx.x] = 0; sh_off[threadIdx.x] = 0; }
  __syncthreads();
  for (int e = c0 + threadIdx.x; e < c1; e += 256) {
    const int d = idx32(ei, (long long)E + e, wide);
    const int r = (int)(((long long)d * RGRP) / N);
    atomicAdd(&sh_cnt[r], 1);
  }
  __syncthreads();
  if (threadIdx.x < RGRP)
    sh_base[threadIdx.x] = atomicAdd(&bcur[threadIdx.x], sh_cnt[threadIdx.x]);
  __syncthreads();
  const long long cap = (long long)RGRP * cap1;
  for (int e = c0 + threadIdx.x; e < c1; e += 256) {
    const int d = idx32(ei, (long long)E + e, wide);
    const int s = idx32(ei, e, wide);
    const int r = (int)(((long long)d * RGRP) / N);
    const int o = atomicAdd(&sh_off[r], 1);
    long long pos = (long long)r * cap1 + sh_base[r] + o;
    if (pos >= cap) pos = cap - 1;  // paranoia clamp (slack makes this dead)
    ebuf[pos] = ((long long)(unsigned)d << 32) | (unsigned)s;
  }
}

// p2: range bucket -> 64 capacity-sliced sub-buckets
__global__ __launch_bounds__(256) void k_bucket2(const long long* __restrict__ ebuf,
                                                 const int* __restrict__ bcur,
                                                 int cap1, int cap2,
                                                 int* __restrict__ scur,
                                                 long long* __restrict__ ebuf2, int N) {
  __shared__ int cnt[SUB_PER];
  __shared__ int base[SUB_PER];
  __shared__ int off[SUB_PER];
  const int r = blockIdx.x & (RGRP - 1);
  const int cb = blockIdx.x >> 3;
  const int nch = gridDim.x >> 3;
  const long long e0 = (long long)r * cap1;
  const long long e1 = e0 + bcur[r];
  const int total = (int)(e1 - e0);
  const int chunk = (total + nch - 1) / nch;
  const long long c0 = e0 + (long long)cb * chunk;
  long long c1 = c0 + chunk;
  if (c1 > e1) c1 = e1;
  if (threadIdx.x < SUB_PER) { cnt[threadIdx.x] = 0; off[threadIdx.x] = 0; }
  __syncthreads();
  for (long long e = c0 + threadIdx.x; e < c1; e += 256) {
    const int d = (int)(ebuf[e] >> 32);
    const int ls = (int)(((long long)d * NSUB) / N) - r * SUB_PER;
    atomicAdd(&cnt[ls], 1);
  }
  __syncthreads();
  if (threadIdx.x < SUB_PER) {
    const int s = r * SUB_PER + threadIdx.x;
    base[threadIdx.x] = atomicAdd(&scur[s], cnt[threadIdx.x]);
  }
  __syncthreads();
  const long long cap = (long long)NSUB * cap2;
  for (long long e = c0 + threadIdx.x; e < c1; e += 256) {
    const long long v = ebuf[e];
    const int d = (int)(v >> 32);
    const int ls = (int)(((long long)d * NSUB) / N) - r * SUB_PER;
    const int o = atomicAdd(&off[ls], 1);
    long long pos = (long long)(r * SUB_PER + ls) * cap2 + base[ls] + o;
    if (pos >= cap) pos = cap - 1;  // paranoia clamp
    ebuf2[pos] = v;
  }
}

// p3: per-sub-bucket LDS histogram -> dense deg + dinv writes (fused)
__global__ __launch_bounds__(256) void k_subdeg(const long long* __restrict__ ebuf2,
                                                const int* __restrict__ scur, int cap2,
                                                int* __restrict__ deg,
                                                float* __restrict__ dinv, int N) {
  __shared__ int hist[MAXNODES];
  const int s = blockIdx.x;
  int nlo = (int)(((long long)N * s + NSUB - 1) / NSUB);
  int nhi = (int)(((long long)N * (s + 1) + NSUB - 1) / NSUB);
  if (nhi > N) nhi = N;
  const int nn = nhi - nlo;
  for (int i = threadIdx.x; i < nn; i += 256) hist[i] = 0;
  __syncthreads();
  const long long e0 = (long long)s * cap2;
  const long long e1 = e0 + scur[s];
  for (long long e = e0 + threadIdx.x; e < e1; e += 256) {
    const int d = (int)(__builtin_nontemporal_load(&ebuf2[e]) >> 32);
    atomicAdd(&hist[d - nlo], 1);
  }
  __syncthreads();
  for (int i = threadIdx.x; i < nn; i += 256) {
    const int h = hist[i];
    deg[nlo + i] = h;
    dinv[nlo + i] = rsqrtf((float)(h + 1));  // +1 self loop
  }
}

// ---- exclusive scan of deg[N] -> rowptr[N+1], 2048 items/block -------------
__global__ void k_scan_a(const int* __restrict__ deg, int N, int* __restrict__ bsum) {
  __shared__ int sh[256];
  int base = blockIdx.x * 2048;
  int s = 0;
  for (int i = threadIdx.x; i < 2048; i += 256) {
    int idx = base + i;
    s += (idx < N) ? deg[idx] : 0;
  }
  sh[threadIdx.x] = s;
  __syncthreads();
  for (int off = 128; off > 0; off >>= 1) {
    if (threadIdx.x < off) sh[threadIdx.x] += sh[threadIdx.x + off];
    __syncthreads();
  }
  if (threadIdx.x == 0) bsum[blockIdx.x] = sh[0];
}

__global__ void k_scan_b(int* __restrict__ bsum, int nb) {
  if (threadIdx.x == 0) {
    int run = 0;
    for (int i = 0; i < nb; ++i) { int v = bsum[i]; bsum[i] = run; run += v; }
    bsum[nb] = run;
  }
}

__global__ void k_scan_c(const int* __restrict__ deg, int N, const int* __restrict__ bsum,
                         int* __restrict__ rowptr, int nb) {
  __shared__ int sh[256];
  int base = blockIdx.x * 2048;
  int v[8];
  int s = 0;
#pragma unroll
  for (int j = 0; j < 8; ++j) {
    int idx = base + threadIdx.x * 8 + j;
    v[j] = (idx < N) ? deg[idx] : 0;
    s += v[j];
  }
  sh[threadIdx.x] = s;
  __syncthreads();
  for (int off = 1; off < 256; off <<= 1) {
    int t = (threadIdx.x >= off) ? sh[threadIdx.x - off] : 0;
    __syncthreads();
    sh[threadIdx.x] += t;
    __syncthreads();
  }
  int excl = (threadIdx.x ? sh[threadIdx.x - 1] : 0) + bsum[blockIdx.x];
#pragma unroll
  for (int j = 0; j < 8; ++j) {
    int idx = base + threadIdx.x * 8 + j;
    if (idx < N) rowptr[idx] = excl;
    excl += v[j];
  }
  if (blockIdx.x == gridDim.x - 1 && threadIdx.x == 255) rowptr[N] = bsum[nb];
}

// p4: block-per-sub-bucket; LDS cursors start at rowptr[d]
__global__ __launch_bounds__(256) void k_csr(const long long* __restrict__ ebuf2,
                                             const int* __restrict__ scur, int cap2,
                                             const int* __restrict__ rowptr,
                                             int* __restrict__ csr, int N) {
  __shared__ int lcur[MAXNODES];
  const int s = blockIdx.x;
  int nlo = (int)(((long long)N * s + NSUB - 1) / NSUB);
  int nhi = (int)(((long long)N * (s + 1) + NSUB - 1) / NSUB);
  if (nhi > N) nhi = N;
  const int nn = nhi - nlo;
  for (int i = threadIdx.x; i < nn; i += 256) lcur[i] = rowptr[nlo + i];
  __syncthreads();
  const long long e0 = (long long)s * cap2;
  const long long e1 = e0 + scur[s];
  for (long long e = e0 + threadIdx.x; e < e1; e += 256) {
    const long long v = __builtin_nontemporal_load(&ebuf2[e]);
    const int d = (int)(v >> 32);
    const int pos = atomicAdd(&lcur[d - nlo], 1);
    csr[pos] = (int)v;
  }
}

// ---- HS = bf16(dinv * (X @ W)) via MFMA; input f32 (layer 1) or bf16 -------
template <int K, bool BF16IN>
__global__ __launch_bounds__(256) void k_gemm_mfma(const void* __restrict__ Xv,
                                                   const float* __restrict__ Wg,
                                                   const float* __restrict__ dinv,
                                                   unsigned short* __restrict__ HS,
                                                   int N) {
  __shared__ short Xl[64 * K];
  __shared__ short Wt[64 * K];
  const int t = threadIdx.x;
  const long long r0 = (long long)blockIdx.x * 64;
  const int rows = (int)((N - r0) < 64 ? (N - r0) : 64);

  // stage W^T (bf16, swizzled): Wt[n][k]
  for (int idx = t; idx < K * 64; idx += 256) {
    const int k = idx >> 6, n = idx & 63;
    Wt[n * K + (((k >> 3) ^ (n & 7)) << 3) + (k & 7)] = (short)f2bf(Wg[idx]);
  }
  // stage X (bf16, swizzled): chunks of 8 values
  const int CH = K / 8;
#pragma unroll
  for (int p = 0; p < K / 32; ++p) {
    const int c = p * 256 + t;  // c < 64*CH
    const int row = c / CH, ch = c % CH;
    const int src = (row < rows) ? row : 0;
    bf16x8 h;
    if constexpr (BF16IN) {
      h = *(const bf16x8*)&((const unsigned short*)Xv)[(r0 + src) * K + ch * 8];
    } else {
      const float* X = (const float*)Xv;
      const float4 v0 = *(const float4*)&X[(r0 + src) * K + ch * 8];
      const float4 v1 = *(const float4*)&X[(r0 + src) * K + ch * 8 + 4];
      h[0] = (short)f2bf(v0.x); h[1] = (short)f2bf(v0.y);
      h[2] = (short)f2bf(v0.z); h[3] = (short)f2bf(v0.w);
      h[4] = (short)f2bf(v1.x); h[5] = (short)f2bf(v1.y);
      h[6] = (short)f2bf(v1.z); h[7] = (short)f2bf(v1.w);
    }
    *(bf16x8*)&Xl[row * K + ((ch ^ (row & 7)) << 3)] = h;
  }
  __syncthreads();

  const int lane = t & 63, w = t >> 6;
  const int lo = lane & 15, hi = lane >> 4;
  const int rowa = w * 16 + lo;

  f32x4 acc[4];
#pragma unroll
  for (int i = 0; i < 4; ++i) acc[i] = (f32x4){0.f, 0.f, 0.f, 0.f};

  bf16x8 a[K / 32];
#pragma unroll
  for (int kk = 0; kk < K / 32; ++kk)
    a[kk] = *(const bf16x8*)&Xl[rowa * K + (((kk * 4 + hi) ^ (rowa & 7)) << 3)];

#pragma unroll
  for (int n0 = 0; n0 < 4; ++n0) {
    const int n = n0 * 16 + lo;
#pragma unroll
    for (int kk = 0; kk < K / 32; ++kk) {
      const bf16x8 b = *(const bf16x8*)&Wt[n * K + (((kk * 4 + hi) ^ (n & 7)) << 3)];
      acc[n0] = __builtin_amdgcn_mfma_f32_16x16x32_bf16(a[kk], b, acc[n0], 0, 0, 0);
    }
  }

  float dv[4];
#pragma unroll
  for (int r = 0; r < 4; ++r) {
    const int rr = w * 16 + hi * 4 + r;
    dv[r] = dinv[r0 + (rr < rows ? rr : 0)];
  }
#pragma unroll
  for (int n0 = 0; n0 < 4; ++n0) {
#pragma unroll
    for (int r = 0; r < 4; ++r) {
      const int rr = w * 16 + hi * 4 + r;
      if (rr < rows)
        HS[(r0 + rr) * 64 + n0 * 16 + lo] = f2bf(dv[r] * acc[n0][r]);
    }
  }
}

// ---- out[i] = bf16(relu(dinv[i]*(hs[i] + sum hs[src]) + b)) ----------------
// Lane owns feature pair (2c, 2c+1); lower/upper 32 lanes take even/odd
// edges; 4 ushort2 loads in flight (latency A/B); bf16 packed output.
__global__ void k_agg(const unsigned short* __restrict__ HS, const int* __restrict__ rowptr,
                      const int* __restrict__ csr, const float* __restrict__ dinv,
                      const float* __restrict__ bias, unsigned* __restrict__ OUT, int N) {
  const int lane = threadIdx.x & 63;
  const int wid = threadIdx.x >> 6;
  const int wavesPerBlock = blockDim.x >> 6;
  const int c = lane & 31;   // feature pair
  const int half = lane >> 5;
  const float b_lo = bias[2 * c];
  const float b_hi = bias[2 * c + 1];
  const unsigned* __restrict__ H32 = (const unsigned*)HS;  // row = 32 x u32
  for (int node = blockIdx.x * wavesPerBlock + wid; node < N;
       node += wavesPerBlock * gridDim.x) {
    const int s0 = rowptr[node], s1 = rowptr[node + 1];
    float alo0 = 0.f, ahi0 = 0.f, alo1 = 0.f, ahi1 = 0.f;
    float alo2 = 0.f, ahi2 = 0.f, alo3 = 0.f, ahi3 = 0.f;
    if (half == 0) {  // self loop once
      const unsigned u = H32[(long long)node * 32 + c];
      alo0 += __uint_as_float(u << 16);
      ahi0 += __uint_as_float(u & 0xffff0000u);
    }
    for (int base = s0; base < s1; base += 64) {
      int m = s1 - base;
      if (m > 64) m = 64;
      const int idx = (base + lane < s1) ? csr[base + lane] : 0;
      const int npairs = m >> 1;
      int jj = 0;
      for (; jj + 4 <= npairs; jj += 4) {  // 4 loads in flight per lane
        const int e0 = __shfl(idx, 2 * jj + half, 64);
        const int e1 = __shfl(idx, 2 * jj + 2 + half, 64);
        const int e2 = __shfl(idx, 2 * jj + 4 + half, 64);
        const int e3 = __shfl(idx, 2 * jj + 6 + half, 64);
        const unsigned u0 = H32[(long long)e0 * 32 + c];
        const unsigned u1 = H32[(long long)e1 * 32 + c];
        const unsigned u2 = H32[(long long)e2 * 32 + c];
        const unsigned u3 = H32[(long long)e3 * 32 + c];
        alo0 += __uint_as_float(u0 << 16);
        ahi0 += __uint_as_float(u0 & 0xffff0000u);
        alo1 += __uint_as_float(u1 << 16);
        ahi1 += __uint_as_float(u1 & 0xffff0000u);
        alo2 += __uint_as_float(u2 << 16);
        ahi2 += __uint_as_float(u2 & 0xffff0000u);
        alo3 += __uint_as_float(u3 << 16);
        ahi3 += __uint_as_float(u3 & 0xffff0000u);
      }
      for (; jj < npairs; ++jj) {
        const int e0 = __shfl(idx, 2 * jj + half, 64);
        const unsigned u0 = H32[(long long)e0 * 32 + c];
        alo0 += __uint_as_float(u0 << 16);
        ahi0 += __uint_as_float(u0 & 0xffff0000u);
      }
      if (m & 1) {  // odd tail edge, lower half only
        const int e = __shfl(idx, m - 1, 64);
        if (half == 0) {
          const unsigned u = H32[(long long)e * 32 + c];
          alo0 += __uint_as_float(u << 16);
          ahi0 += __uint_as_float(u & 0xffff0000u);
        }
      }
    }
    float alo = (alo0 + alo1) + (alo2 + alo3);
    float ahi = (ahi0 + ahi1) + (ahi2 + ahi3);
    alo += __shfl_xor(alo, 32, 64);
    ahi += __shfl_xor(ahi, 32, 64);
    if (half == 0) {
      const float dv = dinv[node];
      const unsigned short o0 = f2bf(fmaxf(fmaf(dv, alo, b_lo), 0.f));
      const unsigned short o1 = f2bf(fmaxf(fmaf(dv, ahi, b_hi), 0.f));
      OUT[(long long)node * 32 + c] = (unsigned)o0 | ((unsigned)o1 << 16);
    }
  }
}

// ---- mean pool per graph (batch is sorted; H is bf16) ----------------------
__global__ void k_pool(const unsigned short* __restrict__ H, const void* __restrict__ batch,
                       const int* __restrict__ flag, float* __restrict__ pooled, int N) {
  __shared__ int se[2];
  __shared__ float red[4][64];
  bool wide = (*flag != 0);
  int g = blockIdx.x;
  if (threadIdx.x < 2) {
    int target = g + threadIdx.x;
    int lo = 0, hi = N;
    while (lo < hi) {
      int mid = (lo + hi) >> 1;
      long long v = wide ? ((const long long*)batch)[mid] : (long long)((const int*)batch)[mid];
      if (v < target) lo = mid + 1; else hi = mid;
    }
    se[threadIdx.x] = lo;
  }
  __syncthreads();
  int s = se[0], e = se[1];
  int lane = threadIdx.x & 63, wid = threadIdx.x >> 6;
  float acc = 0.f;
  for (int r = s + wid; r < e; r += 4) acc += bf2f(H[(long long)r * 64 + lane]);
  red[wid][lane] = acc;
  __syncthreads();
  if (wid == 0) {
    float v = red[0][lane] + red[1][lane] + red[2][lane] + red[3][lane];
    float cnt = (float)(e - s);
    pooled[g * 64 + lane] = v / fmaxf(cnt, 1.f);
  }
}

__global__ void k_classify(const float* __restrict__ pooled, const float* __restrict__ Wc,
                           const float* __restrict__ bc, float* __restrict__ out, int total) {
  int t = blockIdx.x * blockDim.x + threadIdx.x;
  if (t >= total) return;
  int g = t / 10, c = t % 10;
  float acc = bc[c];
#pragma unroll
  for (int h = 0; h < 64; ++h) acc += pooled[g * 64 + h] * Wc[h * 10 + c];
  out[t] = acc;
}

extern "C" void kernel_launch(void* const* d_in, const int* in_sizes, int n_in,
                              void* d_out, int out_size, void* d_ws, size_t ws_size,
                              hipStream_t stream) {
  const float* x = (const float*)d_in[0];
  const void* ei = d_in[1];
  const void* batch = d_in[2];
  const float* W1 = (const float*)d_in[3];
  const float* b1 = (const float*)d_in[4];
  const float* W2 = (const float*)d_in[5];
  const float* b2 = (const float*)d_in[6];
  const float* W3 = (const float*)d_in[7];
  const float* b3 = (const float*)d_in[8];
  const float* Wc = (const float*)d_in[9];
  const float* bc = (const float*)d_in[10];
  float* out = (float*)d_out;

  const int N = in_sizes[0] / 128;
  const int E = in_sizes[1] / 2;
  const int G = out_size / 10;
  const int NB = (N + 2047) / 2048;
  const int cap1 = E / RGRP + E / RGRP / 16 + 256;   // ~6% slack
  const int cap2 = E / NSUB + E / NSUB / 8 + 64;     // ~12.5% slack

  char* W = (char*)d_ws;
  size_t off = 0;
  auto take = [&](size_t b) -> void* {
    void* p = W + off;
    off += (b + 255) & ~(size_t)255;
    return p;
  };
  int* flag = (int*)take(4);
  int* deg = (int*)take((size_t)4 * N);
  int* rowptr = (int*)take((size_t)4 * (N + 1));
  int* bsum = (int*)take((size_t)4 * (NB + 1));
  int* bcur = (int*)take((size_t)4 * RGRP);
  int* scur = (int*)take((size_t)4 * NSUB);
  float* dinv = (float*)take((size_t)4 * N);
  int* csr = (int*)take((size_t)4 * E);
  unsigned short* hs = (unsigned short*)take((size_t)2 * N * 64);
  unsigned short* cur = (unsigned short*)take((size_t)2 * N * 64);
  // two big regions for the build, time-shared with nothing afterwards
  size_t bigBytes = (size_t)8 * RGRP * cap1;
  if ((size_t)8 * NSUB * cap2 > bigBytes) bigBytes = (size_t)8 * NSUB * cap2;
  void* big0 = take(bigBytes);
  void* big1 = take(bigBytes);
  float* pooled = (float*)take((size_t)4 * G * 64);
  (void)ws_size;

  long long* ebuf = (long long*)big0;
  long long* ebuf2 = (long long*)big1;

  hipMemsetAsync(bcur, 0, (size_t)4 * RGRP, stream);
  hipMemsetAsync(scur, 0, (size_t)4 * NSUB, stream);

  k_detect<<<1, 256, 0, stream>>>((const unsigned*)ei, flag);
  k_bucket<<<1024, 256, 0, stream>>>(ei, E, flag, cap1, bcur, ebuf, N);
  k_bucket2<<<256, 256, 0, stream>>>(ebuf, bcur, cap1, cap2, scur, ebuf2, N);
  k_subdeg<<<NSUB, 256, 0, stream>>>(ebuf2, scur, cap2, deg, dinv, N);
  k_scan_a<<<NB, 256, 0, stream>>>(deg, N, bsum);
  k_scan_b<<<1, 64, 0, stream>>>(bsum, NB);
  k_scan_c<<<NB, 256, 0, stream>>>(deg, N, bsum, rowptr, NB);
  k_csr<<<NSUB, 256, 0, stream>>>(ebuf2, scur, cap2, rowptr, csr, N);

  const int TILES = (N + 63) / 64;
  // layer 1: x[N,128] (f32) @ W1 -> hs (bf16); aggregate -> cur (bf16)
  k_gemm_mfma<128, false><<<TILES, 256, 0, stream>>>(x, W1, dinv, hs, N);
  k_agg<<<4096, 256, 0, stream>>>(hs, rowptr, csr, dinv, b1, (unsigned*)cur, N);
  // layer 2 (bf16 in)
  k_gemm_mfma<64, true><<<TILES, 256, 0, stream>>>(cur, W2, dinv, hs, N);
  k_agg<<<4096, 256, 0, stream>>>(hs, rowptr, csr, dinv, b2, (unsigned*)cur, N);
  // layer 3 (bf16 in)
  k_gemm_mfma<64, true><<<TILES, 256, 0, stream>>>(cur, W3, dinv, hs, N);
  k_agg<<<4096, 256, 0, stream>>>(hs, rowptr, csr, dinv, b3, (unsigned*)cur, N);

  k_pool<<<G, 256, 0, stream>>>(cur, batch, flag, pooled, N);
  k_classify<<<(G * 10 + 255) / 256, 256, 0, stream>>>(pooled, Wc, bc, out, G * 10);
}

// Round 12
// 374.682 us; speedup vs baseline: 1.1594x; 1.0707x over previous
//
#include <hip/hip_runtime.h>

// ---------------------------------------------------------------------------
// MalwareGNN: 3-layer GCN (transform -> normalized aggregate) + mean pool + FC
//   * detect int32 vs int64 indices on device; index loads are 4B low-words
//   * CSR build (no global-atomic histograms, no write amplification):
//       p1 k_bucket : 8 range buckets, per-wave BALLOT multisplit (no per-edge
//                     LDS atomics), dense slice writes
//       p2 k_bucket2: range -> 64 sub-buckets each (512 total), LDS counts
//       k_sscan     : 1-block exclusive scan of the 512 sub-bucket sizes
//       k_build     : per-sub-bucket FUSED: LDS hist -> LDS prefix -> rowptr
//                     + dinv writes -> LDS-cursor csr scatter (2nd pass L2-hot)
//   * per layer: MFMA GEMM hs = bf16(dinv*(X@W)), 64x64 tile, swizzled LDS;
//     layer-1 input f32, layers 2/3 bf16 (cur bf16 end-to-end)
//   * gather-aggregate: lane = (quarter q, feature-quad c4); one uint2 load
//     covers 4 rows/512B per wave-instr; 2-level shfl_xor fold; bf16 output
//   * mean-pool via per-graph binary search on sorted batch, then tiny FC
// ---------------------------------------------------------------------------

#define RGRP 8
#define NSUB 512
#define SUB_PER 64   // NSUB / RGRP
#define MAXNODES 256 // >= ceil(N/NSUB); N=100k -> 196

typedef __attribute__((ext_vector_type(8))) short bf16x8;
typedef __attribute__((ext_vector_type(4))) float f32x4;

__device__ __forceinline__ unsigned short f2bf(float x) {
  unsigned u = __float_as_uint(x);
  u += 0x7FFFu + ((u >> 16) & 1u);  // RNE
  return (unsigned short)(u >> 16);
}
__device__ __forceinline__ float bf2f(unsigned short h) {
  return __uint_as_float((unsigned)h << 16);
}
__device__ __forceinline__ float uf(unsigned u) { return __uint_as_float(u); }

__global__ void k_detect(const unsigned* __restrict__ ei, int* __restrict__ flag) {
  __shared__ int any;
  if (threadIdx.x == 0) any = 0;
  __syncthreads();
  unsigned v = 0;
  for (int i = threadIdx.x; i < 8192; i += blockDim.x) v |= ei[2 * i + 1];
  if (v) atomicOr(&any, 1);
  __syncthreads();
  if (threadIdx.x == 0) *flag = (any == 0) ? 1 : 0;  // 1 => int64 indices
}

// low 4B of index i (values < 2^31 so low word == value)
__device__ __forceinline__ int idx32(const int* p, long long i, bool wide) {
  return __builtin_nontemporal_load(p + (wide ? 2 * i : i));
}

// p1: ballot-multisplit range bucketing. Uniform iteration count keeps all
// lanes active for ballots/shfl; 1 LDS atomic per bin per wave per iter.
__global__ __launch_bounds__(256) void k_bucket(const void* __restrict__ eiv, int E,
                                                const int* __restrict__ flag,
                                                int cap1, int* __restrict__ bcur,
                                                long long* __restrict__ ebuf, int N) {
  __shared__ int sh_cnt[RGRP];
  __shared__ int sh_base[RGRP];
  __shared__ int sh_off[RGRP];
  const int* ei = (const int*)eiv;
  const bool wide = (*flag != 0);
  const int tid = threadIdx.x;
  const int lane = tid & 63;
  const int chunk = (E + gridDim.x - 1) / gridDim.x;
  const int c0 = blockIdx.x * chunk;
  const int c1 = (c0 + chunk < E) ? c0 + chunk : E;
  const int iters = (c1 - c0 + 255) >> 8;
  if (tid < RGRP) { sh_cnt[tid] = 0; sh_off[tid] = 0; }
  __syncthreads();
  // count pass: per-wave register accumulation, one LDS atomic per bin at end
  int wcnt = 0;
  for (int it = 0; it < iters; ++it) {
    const int e = c0 + it * 256 + tid;
    int r = RGRP;
    if (e < c1) {
      const int d = idx32(ei, (long long)E + e, wide);
      r = (int)(((long long)d * RGRP) / N);
    }
#pragma unroll
    for (int j = 0; j < RGRP; ++j) {
      const unsigned long long mj = __ballot(r == j);
      if (lane == j) wcnt += __popcll(mj);
    }
  }
  if (lane < RGRP) atomicAdd(&sh_cnt[lane], wcnt);
  __syncthreads();
  if (tid < RGRP) sh_base[tid] = atomicAdd(&bcur[tid], sh_cnt[tid]);
  __syncthreads();
  const int basereg = (lane < RGRP) ? sh_base[lane] : 0;
  // write pass: rank via ballot+popc, per-wave batch reserve via 8 LDS atomics
  for (int it = 0; it < iters; ++it) {
    const int e = c0 + it * 256 + tid;
    const bool valid = e < c1;
    int r = RGRP, d = 0, s = 0;
    if (valid) {
      d = idx32(ei, (long long)E + e, wide);
      s = idx32(ei, e, wide);
      r = (int)(((long long)d * RGRP) / N);
    }
    unsigned long long mym = 0;
    int myrank = 0;
#pragma unroll
    for (int j = 0; j < RGRP; ++j) {
      const unsigned long long mj = __ballot(r == j);
      if (r == j) myrank = __popcll(mj & ((1ull << lane) - 1ull));
      if (lane == j) mym = mj;
    }
    int old = 0;
    if (lane < RGRP) old = atomicAdd(&sh_off[lane], __popcll(mym));
    const int rs = (r < RGRP) ? r : 0;
    const int obase = __shfl(old, rs, 64);
    const int gbase = __shfl(basereg, rs, 64);
    if (valid) {
      const long long pos = (long long)r * cap1 + gbase + obase + myrank;
      ebuf[pos] = ((long long)(unsigned)d << 32) | (unsigned)s;
    }
  }
}

// p2: range bucket -> 64 capacity-sliced sub-buckets
__global__ __launch_bounds__(256) void k_bucket2(const long long* __restrict__ ebuf,
                                                 const int* __restrict__ bcur,
                                                 int cap1, int cap2,
                                                 int* __restrict__ scur,
                                                 long long* __restrict__ ebuf2, int N) {
  __shared__ int cnt[SUB_PER];
  __shared__ int base[SUB_PER];
  __shared__ int off[SUB_PER];
  const int r = blockIdx.x & (RGRP - 1);
  const int cb = blockIdx.x >> 3;
  const int nch = gridDim.x >> 3;
  const long long e0 = (long long)r * cap1;
  const long long e1 = e0 + bcur[r];
  const int total = (int)(e1 - e0);
  const int chunk = (total + nch - 1) / nch;
  const long long c0 = e0 + (long long)cb * chunk;
  long long c1 = c0 + chunk;
  if (c1 > e1) c1 = e1;
  if (threadIdx.x < SUB_PER) { cnt[threadIdx.x] = 0; off[threadIdx.x] = 0; }
  __syncthreads();
  for (long long e = c0 + threadIdx.x; e < c1; e += 256) {
    const int d = (int)(ebuf[e] >> 32);
    const int ls = (int)(((long long)d * NSUB) / N) - r * SUB_PER;
    atomicAdd(&cnt[ls], 1);
  }
  __syncthreads();
  if (threadIdx.x < SUB_PER) {
    const int s = r * SUB_PER + threadIdx.x;
    base[threadIdx.x] = atomicAdd(&scur[s], cnt[threadIdx.x]);
  }
  __syncthreads();
  const long long cap = (long long)NSUB * cap2;
  for (long long e = c0 + threadIdx.x; e < c1; e += 256) {
    const long long v = ebuf[e];
    const int d = (int)(v >> 32);
    const int ls = (int)(((long long)d * NSUB) / N) - r * SUB_PER;
    const int o = atomicAdd(&off[ls], 1);
    long long pos = (long long)(r * SUB_PER + ls) * cap2 + base[ls] + o;
    if (pos >= cap) pos = cap - 1;  // paranoia clamp
    ebuf2[pos] = v;
  }
}

// exclusive scan of scur[512] -> sbase[513] (one block, 256 threads)
__global__ void k_sscan(const int* __restrict__ scur, int* __restrict__ sbase) {
  __shared__ int p[256];
  const int t = threadIdx.x;
  const int s0 = scur[2 * t], s1 = scur[2 * t + 1];
  const int v = s0 + s1;
  p[t] = v;
  __syncthreads();
  for (int off = 1; off < 256; off <<= 1) {
    const int tv = (t >= off) ? p[t - off] : 0;
    __syncthreads();
    p[t] += tv;
    __syncthreads();
  }
  const int excl = p[t] - v;
  sbase[2 * t] = excl;
  sbase[2 * t + 1] = excl + s0;
  if (t == 255) sbase[NSUB] = p[t];
}

// FUSED per-sub-bucket: hist -> prefix -> rowptr+dinv -> csr scatter
__global__ __launch_bounds__(256) void k_build(const long long* __restrict__ ebuf2,
                                               const int* __restrict__ scur, int cap2,
                                               const int* __restrict__ sbase,
                                               int* __restrict__ rowptr,
                                               float* __restrict__ dinv,
                                               int* __restrict__ csr, int N) {
  __shared__ int hist[256];
  __shared__ int pref[256];
  const int s = blockIdx.x;
  const int t = threadIdx.x;
  int nlo = (int)(((long long)N * s + NSUB - 1) / NSUB);
  int nhi = (int)(((long long)N * (s + 1) + NSUB - 1) / NSUB);
  if (nhi > N) nhi = N;
  const int nn = nhi - nlo;
  hist[t] = 0;
  __syncthreads();
  const long long e0 = (long long)s * cap2;
  const long long e1 = e0 + scur[s];
  for (long long e = e0 + t; e < e1; e += 256) {
    const int d = (int)(__builtin_nontemporal_load(&ebuf2[e]) >> 32);
    atomicAdd(&hist[d - nlo], 1);
  }
  __syncthreads();
  const int h = hist[t];
  pref[t] = h;
  __syncthreads();
  for (int off = 1; off < 256; off <<= 1) {
    const int tv = (t >= off) ? pref[t - off] : 0;
    __syncthreads();
    pref[t] += tv;
    __syncthreads();
  }
  const int cur0 = sbase[s] + pref[t] - h;  // exclusive prefix -> cursor
  if (t < nn) {
    rowptr[nlo + t] = cur0;
    dinv[nlo + t] = rsqrtf((float)(h + 1));  // +1 self loop
  }
  if (s == NSUB - 1 && t == 0) rowptr[N] = sbase[NSUB];
  __syncthreads();
  hist[t] = cur0;  // LDS cursors
  __syncthreads();
  for (long long e = e0 + t; e < e1; e += 256) {  // 2nd pass: L2-hot
    const long long v = ebuf2[e];
    const int d = (int)(v >> 32);
    const int pos = atomicAdd(&hist[d - nlo], 1);
    csr[pos] = (int)v;
  }
}

// ---- HS = bf16(dinv * (X @ W)) via MFMA; input f32 (layer 1) or bf16 -------
template <int K, bool BF16IN>
__global__ __launch_bounds__(256) void k_gemm_mfma(const void* __restrict__ Xv,
                                                   const float* __restrict__ Wg,
                                                   const float* __restrict__ dinv,
                                                   unsigned short* __restrict__ HS,
                                                   int N) {
  __shared__ short Xl[64 * K];
  __shared__ short Wt[64 * K];
  const int t = threadIdx.x;
  const long long r0 = (long long)blockIdx.x * 64;
  const int rows = (int)((N - r0) < 64 ? (N - r0) : 64);

  // stage W^T (bf16, swizzled): Wt[n][k]
  for (int idx = t; idx < K * 64; idx += 256) {
    const int k = idx >> 6, n = idx & 63;
    Wt[n * K + (((k >> 3) ^ (n & 7)) << 3) + (k & 7)] = (short)f2bf(Wg[idx]);
  }
  // stage X (bf16, swizzled): chunks of 8 values
  const int CH = K / 8;
#pragma unroll
  for (int p = 0; p < K / 32; ++p) {
    const int c = p * 256 + t;  // c < 64*CH
    const int row = c / CH, ch = c % CH;
    const int src = (row < rows) ? row : 0;
    bf16x8 h;
    if constexpr (BF16IN) {
      h = *(const bf16x8*)&((const unsigned short*)Xv)[(r0 + src) * K + ch * 8];
    } else {
      const float* X = (const float*)Xv;
      const float4 v0 = *(const float4*)&X[(r0 + src) * K + ch * 8];
      const float4 v1 = *(const float4*)&X[(r0 + src) * K + ch * 8 + 4];
      h[0] = (short)f2bf(v0.x); h[1] = (short)f2bf(v0.y);
      h[2] = (short)f2bf(v0.z); h[3] = (short)f2bf(v0.w);
      h[4] = (short)f2bf(v1.x); h[5] = (short)f2bf(v1.y);
      h[6] = (short)f2bf(v1.z); h[7] = (short)f2bf(v1.w);
    }
    *(bf16x8*)&Xl[row * K + ((ch ^ (row & 7)) << 3)] = h;
  }
  __syncthreads();

  const int lane = t & 63, w = t >> 6;
  const int lo = lane & 15, hi = lane >> 4;
  const int rowa = w * 16 + lo;

  f32x4 acc[4];
#pragma unroll
  for (int i = 0; i < 4; ++i) acc[i] = (f32x4){0.f, 0.f, 0.f, 0.f};

  bf16x8 a[K / 32];
#pragma unroll
  for (int kk = 0; kk < K / 32; ++kk)
    a[kk] = *(const bf16x8*)&Xl[rowa * K + (((kk * 4 + hi) ^ (rowa & 7)) << 3)];

#pragma unroll
  for (int n0 = 0; n0 < 4; ++n0) {
    const int n = n0 * 16 + lo;
#pragma unroll
    for (int kk = 0; kk < K / 32; ++kk) {
      const bf16x8 b = *(const bf16x8*)&Wt[n * K + (((kk * 4 + hi) ^ (n & 7)) << 3)];
      acc[n0] = __builtin_amdgcn_mfma_f32_16x16x32_bf16(a[kk], b, acc[n0], 0, 0, 0);
    }
  }

  float dv[4];
#pragma unroll
  for (int r = 0; r < 4; ++r) {
    const int rr = w * 16 + hi * 4 + r;
    dv[r] = dinv[r0 + (rr < rows ? rr : 0)];
  }
#pragma unroll
  for (int n0 = 0; n0 < 4; ++n0) {
#pragma unroll
    for (int r = 0; r < 4; ++r) {
      const int rr = w * 16 + hi * 4 + r;
      if (rr < rows)
        HS[(r0 + rr) * 64 + n0 * 16 + lo] = f2bf(dv[r] * acc[n0][r]);
    }
  }
}

// ---- out[i] = bf16(relu(dinv[i]*(hs[i] + sum hs[src]) + b)) ----------------
// lane = (q = lane>>4, c4 = lane&15): features 4c4..4c4+3 via one uint2 (8B);
// quarter q processes edges e % 4 == q -> one wave load covers 4 rows (512B).
__global__ void k_agg(const unsigned short* __restrict__ HS, const int* __restrict__ rowptr,
                      const int* __restrict__ csr, const float* __restrict__ dinv,
                      const float* __restrict__ bias, unsigned* __restrict__ OUT, int N) {
  const int lane = threadIdx.x & 63;
  const int wid = threadIdx.x >> 6;
  const int wpb = blockDim.x >> 6;
  const int c4 = lane & 15;
  const int q = lane >> 4;
  const float b0 = bias[4 * c4 + 0], b1 = bias[4 * c4 + 1];
  const float b2 = bias[4 * c4 + 2], b3 = bias[4 * c4 + 3];
  const uint2* __restrict__ H8 = (const uint2*)HS;  // row = 16 x uint2
  uint2* __restrict__ O8 = (uint2*)OUT;
  const unsigned M = 0xffff0000u;
  for (int node = blockIdx.x * wpb + wid; node < N; node += wpb * gridDim.x) {
    const int s0 = rowptr[node], s1 = rowptr[node + 1];
    float a0 = 0.f, a1 = 0.f, a2 = 0.f, a3 = 0.f;
    float c0 = 0.f, c1 = 0.f, c2 = 0.f, c3 = 0.f;
    if (q == 0) {  // self loop
      const uint2 u = H8[(long long)node * 16 + c4];
      a0 += uf(u.x << 16); a1 += uf(u.x & M);
      a2 += uf(u.y << 16); a3 += uf(u.y & M);
    }
    for (int base = s0; base < s1; base += 64) {
      int m = s1 - base;
      if (m > 64) m = 64;
      const int idx = (base + lane < s1) ? csr[base + lane] : 0;
      const int ng = m >> 2;  // groups of 4 edges
      int g = 0;
      for (; g + 2 <= ng; g += 2) {  // 2 loads in flight x 4 rows each
        const int e0 = __shfl(idx, 4 * g + q, 64);
        const int e1 = __shfl(idx, 4 * g + 4 + q, 64);
        const uint2 u0 = H8[(long long)e0 * 16 + c4];
        const uint2 u1 = H8[(long long)e1 * 16 + c4];
        a0 += uf(u0.x << 16); a1 += uf(u0.x & M);
        a2 += uf(u0.y << 16); a3 += uf(u0.y & M);
        c0 += uf(u1.x << 16); c1 += uf(u1.x & M);
        c2 += uf(u1.y << 16); c3 += uf(u1.y & M);
      }
      for (; g < ng; ++g) {
        const int e0 = __shfl(idx, 4 * g + q, 64);
        const uint2 u0 = H8[(long long)e0 * 16 + c4];
        a0 += uf(u0.x << 16); a1 += uf(u0.x & M);
        a2 += uf(u0.y << 16); a3 += uf(u0.y & M);
      }
      const int r = m & 3;
      if (r) {  // leftover edges (m&~3)..m-1; quarter q takes one if q < r
        const int e = __shfl(idx, (m & ~3) + (q < r ? q : 0), 64);
        if (q < r) {
          const uint2 u = H8[(long long)e * 16 + c4];
          a0 += uf(u.x << 16); a1 += uf(u.x & M);
          a2 += uf(u.y << 16); a3 += uf(u.y & M);
        }
      }
    }
    a0 += c0; a1 += c1; a2 += c2; a3 += c3;
    a0 += __shfl_xor(a0, 16, 64); a0 += __shfl_xor(a0, 32, 64);
    a1 += __shfl_xor(a1, 16, 64); a1 += __shfl_xor(a1, 32, 64);
    a2 += __shfl_xor(a2, 16, 64); a2 += __shfl_xor(a2, 32, 64);
    a3 += __shfl_xor(a3, 16, 64); a3 += __shfl_xor(a3, 32, 64);
    if (q == 0) {
      const float dv = dinv[node];
      const unsigned short o0 = f2bf(fmaxf(fmaf(dv, a0, b0), 0.f));
      const unsigned short o1 = f2bf(fmaxf(fmaf(dv, a1, b1), 0.f));
      const unsigned short o2 = f2bf(fmaxf(fmaf(dv, a2, b2), 0.f));
      const unsigned short o3 = f2bf(fmaxf(fmaf(dv, a3, b3), 0.f));
      uint2 o;
      o.x = (unsigned)o0 | ((unsigned)o1 << 16);
      o.y = (unsigned)o2 | ((unsigned)o3 << 16);
      O8[(long long)node * 16 + c4] = o;
    }
  }
}

// ---- mean pool per graph (batch is sorted; H is bf16) ----------------------
__global__ void k_pool(const unsigned short* __restrict__ H, const void* __restrict__ batch,
                       const int* __restrict__ flag, float* __restrict__ pooled, int N) {
  __shared__ int se[2];
  __shared__ float red[4][64];
  bool wide = (*flag != 0);
  int g = blockIdx.x;
  if (threadIdx.x < 2) {
    int target = g + threadIdx.x;
    int lo = 0, hi = N;
    while (lo < hi) {
      int mid = (lo + hi) >> 1;
      long long v = wide ? ((const long long*)batch)[mid] : (long long)((const int*)batch)[mid];
      if (v < target) lo = mid + 1; else hi = mid;
    }
    se[threadIdx.x] = lo;
  }
  __syncthreads();
  int s = se[0], e = se[1];
  int lane = threadIdx.x & 63, wid = threadIdx.x >> 6;
  float acc = 0.f;
  for (int r = s + wid; r < e; r += 4) acc += bf2f(H[(long long)r * 64 + lane]);
  red[wid][lane] = acc;
  __syncthreads();
  if (wid == 0) {
    float v = red[0][lane] + red[1][lane] + red[2][lane] + red[3][lane];
    float cnt = (float)(e - s);
    pooled[g * 64 + lane] = v / fmaxf(cnt, 1.f);
  }
}

__global__ void k_classify(const float* __restrict__ pooled, const float* __restrict__ Wc,
                           const float* __restrict__ bc, float* __restrict__ out, int total) {
  int t = blockIdx.x * blockDim.x + threadIdx.x;
  if (t >= total) return;
  int g = t / 10, c = t % 10;
  float acc = bc[c];
#pragma unroll
  for (int h = 0; h < 64; ++h) acc += pooled[g * 64 + h] * Wc[h * 10 + c];
  out[t] = acc;
}

extern "C" void kernel_launch(void* const* d_in, const int* in_sizes, int n_in,
                              void* d_out, int out_size, void* d_ws, size_t ws_size,
                              hipStream_t stream) {
  const float* x = (const float*)d_in[0];
  const void* ei = d_in[1];
  const void* batch = d_in[2];
  const float* W1 = (const float*)d_in[3];
  const float* b1 = (const float*)d_in[4];
  const float* W2 = (const float*)d_in[5];
  const float* b2 = (const float*)d_in[6];
  const float* W3 = (const float*)d_in[7];
  const float* b3 = (const float*)d_in[8];
  const float* Wc = (const float*)d_in[9];
  const float* bc = (const float*)d_in[10];
  float* out = (float*)d_out;

  const int N = in_sizes[0] / 128;
  const int E = in_sizes[1] / 2;
  const int G = out_size / 10;
  const int cap1 = E / RGRP + E / RGRP / 16 + 256;  // ~6% slack
  const int cap2 = E / NSUB + E / NSUB / 8 + 64;    // ~12.5% slack

  char* W = (char*)d_ws;
  size_t off = 0;
  auto take = [&](size_t b) -> void* {
    void* p = W + off;
    off += (b + 255) & ~(size_t)255;
    return p;
  };
  int* flag = (int*)take(4);
  int* rowptr = (int*)take((size_t)4 * (N + 1));
  int* bcur = (int*)take((size_t)4 * RGRP);
  int* scur = (int*)take((size_t)4 * NSUB);
  int* sbase = (int*)take((size_t)4 * (NSUB + 1));
  float* dinv = (float*)take((size_t)4 * N);
  int* csr = (int*)take((size_t)4 * E);
  unsigned short* hs = (unsigned short*)take((size_t)2 * N * 64);
  unsigned short* cur = (unsigned short*)take((size_t)2 * N * 64);
  size_t bigBytes = (size_t)8 * RGRP * cap1;
  if ((size_t)8 * NSUB * cap2 > bigBytes) bigBytes = (size_t)8 * NSUB * cap2;
  void* big0 = take(bigBytes);
  void* big1 = take(bigBytes);
  float* pooled = (float*)take((size_t)4 * G * 64);
  (void)ws_size;

  long long* ebuf = (long long*)big0;
  long long* ebuf2 = (long long*)big1;

  hipMemsetAsync(bcur, 0, (size_t)4 * RGRP, stream);
  hipMemsetAsync(scur, 0, (size_t)4 * NSUB, stream);

  k_detect<<<1, 256, 0, stream>>>((const unsigned*)ei, flag);
  k_bucket<<<1024, 256, 0, stream>>>(ei, E, flag, cap1, bcur, ebuf, N);
  k_bucket2<<<512, 256, 0, stream>>>(ebuf, bcur, cap1, cap2, scur, ebuf2, N);
  k_sscan<<<1, 256, 0, stream>>>(scur, sbase);
  k_build<<<NSUB, 256, 0, stream>>>(ebuf2, scur, cap2, sbase, rowptr, dinv, csr, N);

  const int TILES = (N + 63) / 64;
  // layer 1: x[N,128] (f32) @ W1 -> hs (bf16); aggregate -> cur (bf16)
  k_gemm_mfma<128, false><<<TILES, 256, 0, stream>>>(x, W1, dinv, hs, N);
  k_agg<<<4096, 256, 0, stream>>>(hs, rowptr, csr, dinv, b1, (unsigned*)cur, N);
  // layer 2 (bf16 in)
  k_gemm_mfma<64, true><<<TILES, 256, 0, stream>>>(cur, W2, dinv, hs, N);
  k_agg<<<4096, 256, 0, stream>>>(hs, rowptr, csr, dinv, b2, (unsigned*)cur, N);
  // layer 3 (bf16 in)
  k_gemm_mfma<64, true><<<TILES, 256, 0, stream>>>(cur, W3, dinv, hs, N);
  k_agg<<<4096, 256, 0, stream>>>(hs, rowptr, csr, dinv, b3, (unsigned*)cur, N);

  k_pool<<<G, 256, 0, stream>>>(cur, batch, flag, pooled, N);
  k_classify<<<(G * 10 + 255) / 256, 256, 0, stream>>>(pooled, Wc, bc, out, G * 10);
}

// Round 13
// 365.568 us; speedup vs baseline: 1.1883x; 1.0249x over previous
//
#include <hip/hip_runtime.h>

// ---------------------------------------------------------------------------
// MalwareGNN: 3-layer GCN (transform -> normalized aggregate) + mean pool + FC
//   * detect int32 vs int64 indices on device; index loads are 4B low-words
//   * CSR build (single-pass partition, no global-atomic histograms):
//       k_part : one pass -> 512 capacity-sliced sub-buckets of PACKED u32
//                edges ((d_local<<24)|src; d_local<196, src<2^24). LDS
//                512-bin count -> 512 global atomics/block -> dense runs.
//       k_sscan: 1-block exclusive scan of the 512 sub-bucket sizes
//       k_build: per-sub-bucket FUSED: LDS hist -> LDS prefix -> rowptr+dinv
//                -> LDS-cursor csr scatter (2nd pass L2-hot)
//   * per layer: MFMA GEMM hs = bf16(dinv*(X@W)), 64x64 tile, swizzled LDS;
//     layer-1 input f32, layers 2/3 bf16 (cur bf16 end-to-end)
//   * gather-aggregate (AT STRUCTURAL FLOOR: 158MB L2-miss gather @ ~2.8TB/s;
//     R10-R12 instruction cuts left dur unchanged): lane = (quarter, feature-
//     quad); one uint2 load covers 4 rows/512B per wave-instr; bf16 output
//   * mean-pool via per-graph binary search on sorted batch, then tiny FC
// ---------------------------------------------------------------------------

#define NSUB 512
#define MAXNODES 256 // >= ceil(N/NSUB); N=100k -> 196 (also packing bound)

typedef __attribute__((ext_vector_type(8))) short bf16x8;
typedef __attribute__((ext_vector_type(4))) float f32x4;

__device__ __forceinline__ unsigned short f2bf(float x) {
  unsigned u = __float_as_uint(x);
  u += 0x7FFFu + ((u >> 16) & 1u);  // RNE
  return (unsigned short)(u >> 16);
}
__device__ __forceinline__ float bf2f(unsigned short h) {
  return __uint_as_float((unsigned)h << 16);
}
__device__ __forceinline__ float uf(unsigned u) { return __uint_as_float(u); }

__global__ void k_detect(const unsigned* __restrict__ ei, int* __restrict__ flag) {
  __shared__ int any;
  if (threadIdx.x == 0) any = 0;
  __syncthreads();
  unsigned v = 0;
  for (int i = threadIdx.x; i < 8192; i += blockDim.x) v |= ei[2 * i + 1];
  if (v) atomicOr(&any, 1);
  __syncthreads();
  if (threadIdx.x == 0) *flag = (any == 0) ? 1 : 0;  // 1 => int64 indices
}

// low 4B of index i (values < 2^31 so low word == value)
__device__ __forceinline__ int idx32(const int* p, long long i, bool wide) {
  return __builtin_nontemporal_load(p + (wide ? 2 * i : i));
}

// single-pass 512-bin partition with packed 4B edges
__global__ __launch_bounds__(256) void k_part(const void* __restrict__ eiv, int E,
                                              const int* __restrict__ flag, int cap2,
                                              int* __restrict__ scur,
                                              unsigned* __restrict__ ebuf2, int N) {
  __shared__ int cnt[NSUB];
  __shared__ int base[NSUB];
  __shared__ int off[NSUB];
  const int* ei = (const int*)eiv;
  const bool wide = (*flag != 0);
  const int tid = threadIdx.x;
  const int chunk = (E + gridDim.x - 1) / gridDim.x;
  const int c0 = blockIdx.x * chunk;
  const int c1 = (c0 + chunk < E) ? c0 + chunk : E;
  for (int i = tid; i < NSUB; i += 256) { cnt[i] = 0; off[i] = 0; }
  __syncthreads();
  for (int e = c0 + tid; e < c1; e += 256) {
    const int d = idx32(ei, (long long)E + e, wide);
    const int b = (int)(((long long)d * NSUB) / N);
    atomicAdd(&cnt[b], 1);
  }
  __syncthreads();
  for (int i = tid; i < NSUB; i += 256) base[i] = atomicAdd(&scur[i], cnt[i]);
  __syncthreads();
  const long long cap = (long long)NSUB * cap2;
  for (int e = c0 + tid; e < c1; e += 256) {
    const int d = idx32(ei, (long long)E + e, wide);
    const int s = idx32(ei, e, wide);
    const int b = (int)(((long long)d * NSUB) / N);
    const int nlo = (int)(((long long)N * b + NSUB - 1) / NSUB);
    const int o = atomicAdd(&off[b], 1);
    long long pos = (long long)b * cap2 + base[b] + o;
    if (pos >= cap) pos = cap - 1;  // paranoia clamp (slack makes this dead)
    ebuf2[pos] = ((unsigned)(d - nlo) << 24) | (unsigned)s;
  }
}

// exclusive scan of scur[512] -> sbase[513] (one block, 256 threads)
__global__ void k_sscan(const int* __restrict__ scur, int* __restrict__ sbase) {
  __shared__ int p[256];
  const int t = threadIdx.x;
  const int s0 = scur[2 * t], s1 = scur[2 * t + 1];
  const int v = s0 + s1;
  p[t] = v;
  __syncthreads();
  for (int off = 1; off < 256; off <<= 1) {
    const int tv = (t >= off) ? p[t - off] : 0;
    __syncthreads();
    p[t] += tv;
    __syncthreads();
  }
  const int excl = p[t] - v;
  sbase[2 * t] = excl;
  sbase[2 * t + 1] = excl + s0;
  if (t == 255) sbase[NSUB] = p[t];
}

// FUSED per-sub-bucket: hist -> prefix -> rowptr+dinv -> csr scatter
__global__ __launch_bounds__(256) void k_build(const unsigned* __restrict__ ebuf2,
                                               const int* __restrict__ scur, int cap2,
                                               const int* __restrict__ sbase,
                                               int* __restrict__ rowptr,
                                               float* __restrict__ dinv,
                                               int* __restrict__ csr, int N) {
  __shared__ int hist[256];
  __shared__ int pref[256];
  const int s = blockIdx.x;
  const int t = threadIdx.x;
  int nlo = (int)(((long long)N * s + NSUB - 1) / NSUB);
  int nhi = (int)(((long long)N * (s + 1) + NSUB - 1) / NSUB);
  if (nhi > N) nhi = N;
  const int nn = nhi - nlo;
  hist[t] = 0;
  __syncthreads();
  const long long e0 = (long long)s * cap2;
  const long long e1 = e0 + scur[s];
  for (long long e = e0 + t; e < e1; e += 256) {
    const unsigned v = __builtin_nontemporal_load(&ebuf2[e]);
    atomicAdd(&hist[v >> 24], 1);
  }
  __syncthreads();
  const int h = hist[t];
  pref[t] = h;
  __syncthreads();
  for (int off = 1; off < 256; off <<= 1) {
    const int tv = (t >= off) ? pref[t - off] : 0;
    __syncthreads();
    pref[t] += tv;
    __syncthreads();
  }
  const int cur0 = sbase[s] + pref[t] - h;  // exclusive prefix -> cursor
  if (t < nn) {
    rowptr[nlo + t] = cur0;
    dinv[nlo + t] = rsqrtf((float)(h + 1));  // +1 self loop
  }
  if (s == NSUB - 1 && t == 0) rowptr[N] = sbase[NSUB];
  __syncthreads();
  hist[t] = cur0;  // LDS cursors
  __syncthreads();
  for (long long e = e0 + t; e < e1; e += 256) {  // 2nd pass: L2-hot
    const unsigned v = ebuf2[e];
    const int pos = atomicAdd(&hist[v >> 24], 1);
    csr[pos] = (int)(v & 0x00FFFFFFu);
  }
}

// ---- HS = bf16(dinv * (X @ W)) via MFMA; input f32 (layer 1) or bf16 -------
template <int K, bool BF16IN>
__global__ __launch_bounds__(256) void k_gemm_mfma(const void* __restrict__ Xv,
                                                   const float* __restrict__ Wg,
                                                   const float* __restrict__ dinv,
                                                   unsigned short* __restrict__ HS,
                                                   int N) {
  __shared__ short Xl[64 * K];
  __shared__ short Wt[64 * K];
  const int t = threadIdx.x;
  const long long r0 = (long long)blockIdx.x * 64;
  const int rows = (int)((N - r0) < 64 ? (N - r0) : 64);

  // stage W^T (bf16, swizzled): Wt[n][k]
  for (int idx = t; idx < K * 64; idx += 256) {
    const int k = idx >> 6, n = idx & 63;
    Wt[n * K + (((k >> 3) ^ (n & 7)) << 3) + (k & 7)] = (short)f2bf(Wg[idx]);
  }
  // stage X (bf16, swizzled): chunks of 8 values
  const int CH = K / 8;
#pragma unroll
  for (int p = 0; p < K / 32; ++p) {
    const int c = p * 256 + t;  // c < 64*CH
    const int row = c / CH, ch = c % CH;
    const int src = (row < rows) ? row : 0;
    bf16x8 h;
    if constexpr (BF16IN) {
      h = *(const bf16x8*)&((const unsigned short*)Xv)[(r0 + src) * K + ch * 8];
    } else {
      const float* X = (const float*)Xv;
      const float4 v0 = *(const float4*)&X[(r0 + src) * K + ch * 8];
      const float4 v1 = *(const float4*)&X[(r0 + src) * K + ch * 8 + 4];
      h[0] = (short)f2bf(v0.x); h[1] = (short)f2bf(v0.y);
      h[2] = (short)f2bf(v0.z); h[3] = (short)f2bf(v0.w);
      h[4] = (short)f2bf(v1.x); h[5] = (short)f2bf(v1.y);
      h[6] = (short)f2bf(v1.z); h[7] = (short)f2bf(v1.w);
    }
    *(bf16x8*)&Xl[row * K + ((ch ^ (row & 7)) << 3)] = h;
  }
  __syncthreads();

  const int lane = t & 63, w = t >> 6;
  const int lo = lane & 15, hi = lane >> 4;
  const int rowa = w * 16 + lo;

  f32x4 acc[4];
#pragma unroll
  for (int i = 0; i < 4; ++i) acc[i] = (f32x4){0.f, 0.f, 0.f, 0.f};

  bf16x8 a[K / 32];
#pragma unroll
  for (int kk = 0; kk < K / 32; ++kk)
    a[kk] = *(const bf16x8*)&Xl[rowa * K + (((kk * 4 + hi) ^ (rowa & 7)) << 3)];

#pragma unroll
  for (int n0 = 0; n0 < 4; ++n0) {
    const int n = n0 * 16 + lo;
#pragma unroll
    for (int kk = 0; kk < K / 32; ++kk) {
      const bf16x8 b = *(const bf16x8*)&Wt[n * K + (((kk * 4 + hi) ^ (n & 7)) << 3)];
      acc[n0] = __builtin_amdgcn_mfma_f32_16x16x32_bf16(a[kk], b, acc[n0], 0, 0, 0);
    }
  }

  float dv[4];
#pragma unroll
  for (int r = 0; r < 4; ++r) {
    const int rr = w * 16 + hi * 4 + r;
    dv[r] = dinv[r0 + (rr < rows ? rr : 0)];
  }
#pragma unroll
  for (int n0 = 0; n0 < 4; ++n0) {
#pragma unroll
    for (int r = 0; r < 4; ++r) {
      const int rr = w * 16 + hi * 4 + r;
      if (rr < rows)
        HS[(r0 + rr) * 64 + n0 * 16 + lo] = f2bf(dv[r] * acc[n0][r]);
    }
  }
}

// ---- out[i] = bf16(relu(dinv[i]*(hs[i] + sum hs[src]) + b)) ----------------
// lane = (q = lane>>4, c4 = lane&15): features 4c4..4c4+3 via one uint2 (8B);
// quarter q processes edges e % 4 == q -> one wave load covers 4 rows (512B).
__global__ void k_agg(const unsigned short* __restrict__ HS, const int* __restrict__ rowptr,
                      const int* __restrict__ csr, const float* __restrict__ dinv,
                      const float* __restrict__ bias, unsigned* __restrict__ OUT, int N) {
  const int lane = threadIdx.x & 63;
  const int wid = threadIdx.x >> 6;
  const int wpb = blockDim.x >> 6;
  const int c4 = lane & 15;
  const int q = lane >> 4;
  const float b0 = bias[4 * c4 + 0], b1 = bias[4 * c4 + 1];
  const float b2 = bias[4 * c4 + 2], b3 = bias[4 * c4 + 3];
  const uint2* __restrict__ H8 = (const uint2*)HS;  // row = 16 x uint2
  uint2* __restrict__ O8 = (uint2*)OUT;
  const unsigned M = 0xffff0000u;
  for (int node = blockIdx.x * wpb + wid; node < N; node += wpb * gridDim.x) {
    const int s0 = rowptr[node], s1 = rowptr[node + 1];
    float a0 = 0.f, a1 = 0.f, a2 = 0.f, a3 = 0.f;
    float c0 = 0.f, c1 = 0.f, c2 = 0.f, c3 = 0.f;
    if (q == 0) {  // self loop
      const uint2 u = H8[(long long)node * 16 + c4];
      a0 += uf(u.x << 16); a1 += uf(u.x & M);
      a2 += uf(u.y << 16); a3 += uf(u.y & M);
    }
    for (int base = s0; base < s1; base += 64) {
      int m = s1 - base;
      if (m > 64) m = 64;
      const int idx = (base + lane < s1) ? csr[base + lane] : 0;
      const int ng = m >> 2;  // groups of 4 edges
      int g = 0;
      for (; g + 2 <= ng; g += 2) {  // 2 loads in flight x 4 rows each
        const int e0 = __shfl(idx, 4 * g + q, 64);
        const int e1 = __shfl(idx, 4 * g + 4 + q, 64);
        const uint2 u0 = H8[(long long)e0 * 16 + c4];
        const uint2 u1 = H8[(long long)e1 * 16 + c4];
        a0 += uf(u0.x << 16); a1 += uf(u0.x & M);
        a2 += uf(u0.y << 16); a3 += uf(u0.y & M);
        c0 += uf(u1.x << 16); c1 += uf(u1.x & M);
        c2 += uf(u1.y << 16); c3 += uf(u1.y & M);
      }
      for (; g < ng; ++g) {
        const int e0 = __shfl(idx, 4 * g + q, 64);
        const uint2 u0 = H8[(long long)e0 * 16 + c4];
        a0 += uf(u0.x << 16); a1 += uf(u0.x & M);
        a2 += uf(u0.y << 16); a3 += uf(u0.y & M);
      }
      const int r = m & 3;
      if (r) {  // leftover edges; quarter q takes one if q < r
        const int e = __shfl(idx, (m & ~3) + (q < r ? q : 0), 64);
        if (q < r) {
          const uint2 u = H8[(long long)e * 16 + c4];
          a0 += uf(u.x << 16); a1 += uf(u.x & M);
          a2 += uf(u.y << 16); a3 += uf(u.y & M);
        }
      }
    }
    a0 += c0; a1 += c1; a2 += c2; a3 += c3;
    a0 += __shfl_xor(a0, 16, 64); a0 += __shfl_xor(a0, 32, 64);
    a1 += __shfl_xor(a1, 16, 64); a1 += __shfl_xor(a1, 32, 64);
    a2 += __shfl_xor(a2, 16, 64); a2 += __shfl_xor(a2, 32, 64);
    a3 += __shfl_xor(a3, 16, 64); a3 += __shfl_xor(a3, 32, 64);
    if (q == 0) {
      const float dv = dinv[node];
      const unsigned short o0 = f2bf(fmaxf(fmaf(dv, a0, b0), 0.f));
      const unsigned short o1 = f2bf(fmaxf(fmaf(dv, a1, b1), 0.f));
      const unsigned short o2 = f2bf(fmaxf(fmaf(dv, a2, b2), 0.f));
      const unsigned short o3 = f2bf(fmaxf(fmaf(dv, a3, b3), 0.f));
      uint2 o;
      o.x = (unsigned)o0 | ((unsigned)o1 << 16);
      o.y = (unsigned)o2 | ((unsigned)o3 << 16);
      O8[(long long)node * 16 + c4] = o;
    }
  }
}

// ---- mean pool per graph (batch is sorted; H is bf16) ----------------------
__global__ void k_pool(const unsigned short* __restrict__ H, const void* __restrict__ batch,
                       const int* __restrict__ flag, float* __restrict__ pooled, int N) {
  __shared__ int se[2];
  __shared__ float red[4][64];
  bool wide = (*flag != 0);
  int g = blockIdx.x;
  if (threadIdx.x < 2) {
    int target = g + threadIdx.x;
    int lo = 0, hi = N;
    while (lo < hi) {
      int mid = (lo + hi) >> 1;
      long long v = wide ? ((const long long*)batch)[mid] : (long long)((const int*)batch)[mid];
      if (v < target) lo = mid + 1; else hi = mid;
    }
    se[threadIdx.x] = lo;
  }
  __syncthreads();
  int s = se[0], e = se[1];
  int lane = threadIdx.x & 63, wid = threadIdx.x >> 6;
  float acc = 0.f;
  for (int r = s + wid; r < e; r += 4) acc += bf2f(H[(long long)r * 64 + lane]);
  red[wid][lane] = acc;
  __syncthreads();
  if (wid == 0) {
    float v = red[0][lane] + red[1][lane] + red[2][lane] + red[3][lane];
    float cnt = (float)(e - s);
    pooled[g * 64 + lane] = v / fmaxf(cnt, 1.f);
  }
}

__global__ void k_classify(const float* __restrict__ pooled, const float* __restrict__ Wc,
                           const float* __restrict__ bc, float* __restrict__ out, int total) {
  int t = blockIdx.x * blockDim.x + threadIdx.x;
  if (t >= total) return;
  int g = t / 10, c = t % 10;
  float acc = bc[c];
#pragma unroll
  for (int h = 0; h < 64; ++h) acc += pooled[g * 64 + h] * Wc[h * 10 + c];
  out[t] = acc;
}

extern "C" void kernel_launch(void* const* d_in, const int* in_sizes, int n_in,
                              void* d_out, int out_size, void* d_ws, size_t ws_size,
                              hipStream_t stream) {
  const float* x = (const float*)d_in[0];
  const void* ei = d_in[1];
  const void* batch = d_in[2];
  const float* W1 = (const float*)d_in[3];
  const float* b1 = (const float*)d_in[4];
  const float* W2 = (const float*)d_in[5];
  const float* b2 = (const float*)d_in[6];
  const float* W3 = (const float*)d_in[7];
  const float* b3 = (const float*)d_in[8];
  const float* Wc = (const float*)d_in[9];
  const float* bc = (const float*)d_in[10];
  float* out = (float*)d_out;

  const int N = in_sizes[0] / 128;
  const int E = in_sizes[1] / 2;
  const int G = out_size / 10;
  const int cap2 = E / NSUB + E / NSUB / 8 + 64;  // ~12.5% slack (>=10 sigma)

  char* W = (char*)d_ws;
  size_t off = 0;
  auto take = [&](size_t b) -> void* {
    void* p = W + off;
    off += (b + 255) & ~(size_t)255;
    return p;
  };
  int* flag = (int*)take(4);
  int* rowptr = (int*)take((size_t)4 * (N + 1));
  int* scur = (int*)take((size_t)4 * NSUB);
  int* sbase = (int*)take((size_t)4 * (NSUB + 1));
  float* dinv = (float*)take((size_t)4 * N);
  int* csr = (int*)take((size_t)4 * E);
  unsigned short* hs = (unsigned short*)take((size_t)2 * N * 64);
  unsigned short* cur = (unsigned short*)take((size_t)2 * N * 64);
  unsigned* ebuf2 = (unsigned*)take((size_t)4 * NSUB * cap2);
  float* pooled = (float*)take((size_t)4 * G * 64);
  (void)ws_size;

  hipMemsetAsync(scur, 0, (size_t)4 * NSUB, stream);

  k_detect<<<1, 256, 0, stream>>>((const unsigned*)ei, flag);
  k_part<<<256, 256, 0, stream>>>(ei, E, flag, cap2, scur, ebuf2, N);
  k_sscan<<<1, 256, 0, stream>>>(scur, sbase);
  k_build<<<NSUB, 256, 0, stream>>>(ebuf2, scur, cap2, sbase, rowptr, dinv, csr, N);

  const int TILES = (N + 63) / 64;
  // layer 1: x[N,128] (f32) @ W1 -> hs (bf16); aggregate -> cur (bf16)
  k_gemm_mfma<128, false><<<TILES, 256, 0, stream>>>(x, W1, dinv, hs, N);
  k_agg<<<4096, 256, 0, stream>>>(hs, rowptr, csr, dinv, b1, (unsigned*)cur, N);
  // layer 2 (bf16 in)
  k_gemm_mfma<64, true><<<TILES, 256, 0, stream>>>(cur, W2, dinv, hs, N);
  k_agg<<<4096, 256, 0, stream>>>(hs, rowptr, csr, dinv, b2, (unsigned*)cur, N);
  // layer 3 (bf16 in)
  k_gemm_mfma<64, true><<<TILES, 256, 0, stream>>>(cur, W3, dinv, hs, N);
  k_agg<<<4096, 256, 0, stream>>>(hs, rowptr, csr, dinv, b3, (unsigned*)cur, N);

  k_pool<<<G, 256, 0, stream>>>(cur, batch, flag, pooled, N);
  k_classify<<<(G * 10 + 255) / 256, 256, 0, stream>>>(pooled, Wc, bc, out, G * 10);
}

// Round 14
// 343.989 us; speedup vs baseline: 1.2628x; 1.0627x over previous
//
#include <hip/hip_runtime.h>

// ---------------------------------------------------------------------------
// MalwareGNN: 3-layer GCN (transform -> normalized aggregate) + mean pool + FC
//   * detect int32 vs int64 indices on device; index loads are 4B low-words
//   * CSR build (single-pass partition, no global-atomic histograms):
//       k_part : grid 512 x block 1024 (100% occupancy cap) -> 512 capacity-
//                sliced sub-buckets of PACKED u32 edges ((d_local<<24)|src).
//                LDS 512-bin count -> 512 global atomics/block -> dense runs.
//       k_sscan: 1-block exclusive scan of the 512 sub-bucket sizes
//       k_build: per-sub-bucket FUSED (512 thr): LDS hist -> prefix ->
//                rowptr+dinv -> LDS-cursor csr scatter (2nd pass L2-hot)
//   * per layer: MFMA GEMM hs = bf16(dinv*(X@W)), 64x64 tile, swizzled LDS;
//     layer-1 input f32, layers 2/3 bf16 (cur bf16 end-to-end)
//   * gather-aggregate (AT STRUCTURAL FLOOR: 158MB L2-miss gather @ ~2.8TB/s)
//   * mean-pool via per-graph binary search on sorted batch, then tiny FC
// ---------------------------------------------------------------------------

#define NSUB 512
#define MAXNODES 256 // >= ceil(N/NSUB); N=100k -> 196 (also packing bound)

typedef __attribute__((ext_vector_type(8))) short bf16x8;
typedef __attribute__((ext_vector_type(4))) float f32x4;

__device__ __forceinline__ unsigned short f2bf(float x) {
  unsigned u = __float_as_uint(x);
  u += 0x7FFFu + ((u >> 16) & 1u);  // RNE
  return (unsigned short)(u >> 16);
}
__device__ __forceinline__ float bf2f(unsigned short h) {
  return __uint_as_float((unsigned)h << 16);
}
__device__ __forceinline__ float uf(unsigned u) { return __uint_as_float(u); }

__global__ void k_detect(const unsigned* __restrict__ ei, int* __restrict__ flag) {
  __shared__ int any;
  if (threadIdx.x == 0) any = 0;
  __syncthreads();
  unsigned v = 0;
  for (int i = threadIdx.x; i < 8192; i += blockDim.x) v |= ei[2 * i + 1];
  if (v) atomicOr(&any, 1);
  __syncthreads();
  if (threadIdx.x == 0) *flag = (any == 0) ? 1 : 0;  // 1 => int64 indices
}

// low 4B of index i (values < 2^31 so low word == value)
__device__ __forceinline__ int idx32(const int* p, long long i, bool wide) {
  return __builtin_nontemporal_load(p + (wide ? 2 * i : i));
}

// single-pass 512-bin partition, packed 4B edges; 1024 threads/block for
// occupancy (2 blocks/CU = 100% cap), 512 blocks keeps bin runs ~12 edges.
__global__ __launch_bounds__(1024) void k_part(const void* __restrict__ eiv, int E,
                                               const int* __restrict__ flag, int cap2,
                                               int* __restrict__ scur,
                                               unsigned* __restrict__ ebuf2, int N) {
  __shared__ int cnt[NSUB];
  __shared__ int base[NSUB];
  __shared__ int off[NSUB];
  const int* ei = (const int*)eiv;
  const bool wide = (*flag != 0);
  const int tid = threadIdx.x;
  const int chunk = (E + gridDim.x - 1) / gridDim.x;
  const int c0 = blockIdx.x * chunk;
  const int c1 = (c0 + chunk < E) ? c0 + chunk : E;
  for (int i = tid; i < NSUB; i += 1024) { cnt[i] = 0; off[i] = 0; }
  __syncthreads();
  for (int e = c0 + tid; e < c1; e += 1024) {
    const int d = idx32(ei, (long long)E + e, wide);
    const int b = (int)(((long long)d * NSUB) / N);
    atomicAdd(&cnt[b], 1);
  }
  __syncthreads();
  for (int i = tid; i < NSUB; i += 1024) base[i] = atomicAdd(&scur[i], cnt[i]);
  __syncthreads();
  const long long cap = (long long)NSUB * cap2;
  for (int e = c0 + tid; e < c1; e += 1024) {
    const int d = idx32(ei, (long long)E + e, wide);
    const int s = idx32(ei, e, wide);
    const int b = (int)(((long long)d * NSUB) / N);
    const int nlo = (int)(((long long)N * b + NSUB - 1) / NSUB);
    const int o = atomicAdd(&off[b], 1);
    long long pos = (long long)b * cap2 + base[b] + o;
    if (pos >= cap) pos = cap - 1;  // paranoia clamp (slack makes this dead)
    ebuf2[pos] = ((unsigned)(d - nlo) << 24) | (unsigned)s;
  }
}

// exclusive scan of scur[512] -> sbase[513] (one block, 256 threads)
__global__ void k_sscan(const int* __restrict__ scur, int* __restrict__ sbase) {
  __shared__ int p[256];
  const int t = threadIdx.x;
  const int s0 = scur[2 * t], s1 = scur[2 * t + 1];
  const int v = s0 + s1;
  p[t] = v;
  __syncthreads();
  for (int off = 1; off < 256; off <<= 1) {
    const int tv = (t >= off) ? p[t - off] : 0;
    __syncthreads();
    p[t] += tv;
    __syncthreads();
  }
  const int excl = p[t] - v;
  sbase[2 * t] = excl;
  sbase[2 * t + 1] = excl + s0;
  if (t == 255) sbase[NSUB] = p[t];
}

// FUSED per-sub-bucket (512 threads): hist -> prefix -> rowptr+dinv -> scatter
__global__ __launch_bounds__(512) void k_build(const unsigned* __restrict__ ebuf2,
                                               const int* __restrict__ scur, int cap2,
                                               const int* __restrict__ sbase,
                                               int* __restrict__ rowptr,
                                               float* __restrict__ dinv,
                                               int* __restrict__ csr, int N) {
  __shared__ int hist[256];
  __shared__ int pref[256];
  const int s = blockIdx.x;
  const int t = threadIdx.x;
  int nlo = (int)(((long long)N * s + NSUB - 1) / NSUB);
  int nhi = (int)(((long long)N * (s + 1) + NSUB - 1) / NSUB);
  if (nhi > N) nhi = N;
  const int nn = nhi - nlo;
  if (t < 256) hist[t] = 0;
  __syncthreads();
  const long long e0 = (long long)s * cap2;
  const long long e1 = e0 + scur[s];
  for (long long e = e0 + t; e < e1; e += 512) {
    const unsigned v = __builtin_nontemporal_load(&ebuf2[e]);
    atomicAdd(&hist[v >> 24], 1);
  }
  __syncthreads();
  int h = 0;
  if (t < 256) {
    h = hist[t];
    pref[t] = h;
  }
  __syncthreads();
  for (int off = 1; off < 256; off <<= 1) {
    int tv = 0;
    if (t < 256 && t >= off) tv = pref[t - off];
    __syncthreads();
    if (t < 256) pref[t] += tv;
    __syncthreads();
  }
  if (t < 256) {
    const int cur0 = sbase[s] + pref[t] - h;  // exclusive prefix -> cursor
    if (t < nn) {
      rowptr[nlo + t] = cur0;
      dinv[nlo + t] = rsqrtf((float)(h + 1));  // +1 self loop
    }
    hist[t] = cur0;  // LDS cursors
  }
  if (s == NSUB - 1 && t == 0) rowptr[N] = sbase[NSUB];
  __syncthreads();
  for (long long e = e0 + t; e < e1; e += 512) {  // 2nd pass: L2-hot
    const unsigned v = ebuf2[e];
    const int pos = atomicAdd(&hist[v >> 24], 1);
    csr[pos] = (int)(v & 0x00FFFFFFu);
  }
}

// ---- HS = bf16(dinv * (X @ W)) via MFMA; input f32 (layer 1) or bf16 -------
template <int K, bool BF16IN>
__global__ __launch_bounds__(256) void k_gemm_mfma(const void* __restrict__ Xv,
                                                   const float* __restrict__ Wg,
                                                   const float* __restrict__ dinv,
                                                   unsigned short* __restrict__ HS,
                                                   int N) {
  __shared__ short Xl[64 * K];
  __shared__ short Wt[64 * K];
  const int t = threadIdx.x;
  const long long r0 = (long long)blockIdx.x * 64;
  const int rows = (int)((N - r0) < 64 ? (N - r0) : 64);

  // stage W^T (bf16, swizzled): Wt[n][k]
  for (int idx = t; idx < K * 64; idx += 256) {
    const int k = idx >> 6, n = idx & 63;
    Wt[n * K + (((k >> 3) ^ (n & 7)) << 3) + (k & 7)] = (short)f2bf(Wg[idx]);
  }
  // stage X (bf16, swizzled): chunks of 8 values
  const int CH = K / 8;
#pragma unroll
  for (int p = 0; p < K / 32; ++p) {
    const int c = p * 256 + t;  // c < 64*CH
    const int row = c / CH, ch = c % CH;
    const int src = (row < rows) ? row : 0;
    bf16x8 h;
    if constexpr (BF16IN) {
      h = *(const bf16x8*)&((const unsigned short*)Xv)[(r0 + src) * K + ch * 8];
    } else {
      const float* X = (const float*)Xv;
      const float4 v0 = *(const float4*)&X[(r0 + src) * K + ch * 8];
      const float4 v1 = *(const float4*)&X[(r0 + src) * K + ch * 8 + 4];
      h[0] = (short)f2bf(v0.x); h[1] = (short)f2bf(v0.y);
      h[2] = (short)f2bf(v0.z); h[3] = (short)f2bf(v0.w);
      h[4] = (short)f2bf(v1.x); h[5] = (short)f2bf(v1.y);
      h[6] = (short)f2bf(v1.z); h[7] = (short)f2bf(v1.w);
    }
    *(bf16x8*)&Xl[row * K + ((ch ^ (row & 7)) << 3)] = h;
  }
  __syncthreads();

  const int lane = t & 63, w = t >> 6;
  const int lo = lane & 15, hi = lane >> 4;
  const int rowa = w * 16 + lo;

  f32x4 acc[4];
#pragma unroll
  for (int i = 0; i < 4; ++i) acc[i] = (f32x4){0.f, 0.f, 0.f, 0.f};

  bf16x8 a[K / 32];
#pragma unroll
  for (int kk = 0; kk < K / 32; ++kk)
    a[kk] = *(const bf16x8*)&Xl[rowa * K + (((kk * 4 + hi) ^ (rowa & 7)) << 3)];

#pragma unroll
  for (int n0 = 0; n0 < 4; ++n0) {
    const int n = n0 * 16 + lo;
#pragma unroll
    for (int kk = 0; kk < K / 32; ++kk) {
      const bf16x8 b = *(const bf16x8*)&Wt[n * K + (((kk * 4 + hi) ^ (n & 7)) << 3)];
      acc[n0] = __builtin_amdgcn_mfma_f32_16x16x32_bf16(a[kk], b, acc[n0], 0, 0, 0);
    }
  }

  float dv[4];
#pragma unroll
  for (int r = 0; r < 4; ++r) {
    const int rr = w * 16 + hi * 4 + r;
    dv[r] = dinv[r0 + (rr < rows ? rr : 0)];
  }
#pragma unroll
  for (int n0 = 0; n0 < 4; ++n0) {
#pragma unroll
    for (int r = 0; r < 4; ++r) {
      const int rr = w * 16 + hi * 4 + r;
      if (rr < rows)
        HS[(r0 + rr) * 64 + n0 * 16 + lo] = f2bf(dv[r] * acc[n0][r]);
    }
  }
}

// ---- out[i] = bf16(relu(dinv[i]*(hs[i] + sum hs[src]) + b)) ----------------
// lane = (q = lane>>4, c4 = lane&15): features 4c4..4c4+3 via one uint2 (8B);
// quarter q processes edges e % 4 == q -> one wave load covers 4 rows (512B).
__global__ void k_agg(const unsigned short* __restrict__ HS, const int* __restrict__ rowptr,
                      const int* __restrict__ csr, const float* __restrict__ dinv,
                      const float* __restrict__ bias, unsigned* __restrict__ OUT, int N) {
  const int lane = threadIdx.x & 63;
  const int wid = threadIdx.x >> 6;
  const int wpb = blockDim.x >> 6;
  const int c4 = lane & 15;
  const int q = lane >> 4;
  const float b0 = bias[4 * c4 + 0], b1 = bias[4 * c4 + 1];
  const float b2 = bias[4 * c4 + 2], b3 = bias[4 * c4 + 3];
  const uint2* __restrict__ H8 = (const uint2*)HS;  // row = 16 x uint2
  uint2* __restrict__ O8 = (uint2*)OUT;
  const unsigned M = 0xffff0000u;
  for (int node = blockIdx.x * wpb + wid; node < N; node += wpb * gridDim.x) {
    const int s0 = rowptr[node], s1 = rowptr[node + 1];
    float a0 = 0.f, a1 = 0.f, a2 = 0.f, a3 = 0.f;
    float c0 = 0.f, c1 = 0.f, c2 = 0.f, c3 = 0.f;
    if (q == 0) {  // self loop
      const uint2 u = H8[(long long)node * 16 + c4];
      a0 += uf(u.x << 16); a1 += uf(u.x & M);
      a2 += uf(u.y << 16); a3 += uf(u.y & M);
    }
    for (int base = s0; base < s1; base += 64) {
      int m = s1 - base;
      if (m > 64) m = 64;
      const int idx = (base + lane < s1) ? csr[base + lane] : 0;
      const int ng = m >> 2;  // groups of 4 edges
      int g = 0;
      for (; g + 2 <= ng; g += 2) {  // 2 loads in flight x 4 rows each
        const int e0 = __shfl(idx, 4 * g + q, 64);
        const int e1 = __shfl(idx, 4 * g + 4 + q, 64);
        const uint2 u0 = H8[(long long)e0 * 16 + c4];
        const uint2 u1 = H8[(long long)e1 * 16 + c4];
        a0 += uf(u0.x << 16); a1 += uf(u0.x & M);
        a2 += uf(u0.y << 16); a3 += uf(u0.y & M);
        c0 += uf(u1.x << 16); c1 += uf(u1.x & M);
        c2 += uf(u1.y << 16); c3 += uf(u1.y & M);
      }
      for (; g < ng; ++g) {
        const int e0 = __shfl(idx, 4 * g + q, 64);
        const uint2 u0 = H8[(long long)e0 * 16 + c4];
        a0 += uf(u0.x << 16); a1 += uf(u0.x & M);
        a2 += uf(u0.y << 16); a3 += uf(u0.y & M);
      }
      const int r = m & 3;
      if (r) {  // leftover edges; quarter q takes one if q < r
        const int e = __shfl(idx, (m & ~3) + (q < r ? q : 0), 64);
        if (q < r) {
          const uint2 u = H8[(long long)e * 16 + c4];
          a0 += uf(u.x << 16); a1 += uf(u.x & M);
          a2 += uf(u.y << 16); a3 += uf(u.y & M);
        }
      }
    }
    a0 += c0; a1 += c1; a2 += c2; a3 += c3;
    a0 += __shfl_xor(a0, 16, 64); a0 += __shfl_xor(a0, 32, 64);
    a1 += __shfl_xor(a1, 16, 64); a1 += __shfl_xor(a1, 32, 64);
    a2 += __shfl_xor(a2, 16, 64); a2 += __shfl_xor(a2, 32, 64);
    a3 += __shfl_xor(a3, 16, 64); a3 += __shfl_xor(a3, 32, 64);
    if (q == 0) {
      const float dv = dinv[node];
      const unsigned short o0 = f2bf(fmaxf(fmaf(dv, a0, b0), 0.f));
      const unsigned short o1 = f2bf(fmaxf(fmaf(dv, a1, b1), 0.f));
      const unsigned short o2 = f2bf(fmaxf(fmaf(dv, a2, b2), 0.f));
      const unsigned short o3 = f2bf(fmaxf(fmaf(dv, a3, b3), 0.f));
      uint2 o;
      o.x = (unsigned)o0 | ((unsigned)o1 << 16);
      o.y = (unsigned)o2 | ((unsigned)o3 << 16);
      O8[(long long)node * 16 + c4] = o;
    }
  }
}

// ---- mean pool per graph (batch is sorted; H is bf16) ----------------------
__global__ void k_pool(const unsigned short* __restrict__ H, const void* __restrict__ batch,
                       const int* __restrict__ flag, float* __restrict__ pooled, int N) {
  __shared__ int se[2];
  __shared__ float red[4][64];
  bool wide = (*flag != 0);
  int g = blockIdx.x;
  if (threadIdx.x < 2) {
    int target = g + threadIdx.x;
    int lo = 0, hi = N;
    while (lo < hi) {
      int mid = (lo + hi) >> 1;
      long long v = wide ? ((const long long*)batch)[mid] : (long long)((const int*)batch)[mid];
      if (v < target) lo = mid + 1; else hi = mid;
    }
    se[threadIdx.x] = lo;
  }
  __syncthreads();
  int s = se[0], e = se[1];
  int lane = threadIdx.x & 63, wid = threadIdx.x >> 6;
  float acc = 0.f;
  for (int r = s + wid; r < e; r += 4) acc += bf2f(H[(long long)r * 64 + lane]);
  red[wid][lane] = acc;
  __syncthreads();
  if (wid == 0) {
    float v = red[0][lane] + red[1][lane] + red[2][lane] + red[3][lane];
    float cnt = (float)(e - s);
    pooled[g * 64 + lane] = v / fmaxf(cnt, 1.f);
  }
}

__global__ void k_classify(const float* __restrict__ pooled, const float* __restrict__ Wc,
                           const float* __restrict__ bc, float* __restrict__ out, int total) {
  int t = blockIdx.x * blockDim.x + threadIdx.x;
  if (t >= total) return;
  int g = t / 10, c = t % 10;
  float acc = bc[c];
#pragma unroll
  for (int h = 0; h < 64; ++h) acc += pooled[g * 64 + h] * Wc[h * 10 + c];
  out[t] = acc;
}

extern "C" void kernel_launch(void* const* d_in, const int* in_sizes, int n_in,
                              void* d_out, int out_size, void* d_ws, size_t ws_size,
                              hipStream_t stream) {
  const float* x = (const float*)d_in[0];
  const void* ei = d_in[1];
  const void* batch = d_in[2];
  const float* W1 = (const float*)d_in[3];
  const float* b1 = (const float*)d_in[4];
  const float* W2 = (const float*)d_in[5];
  const float* b2 = (const float*)d_in[6];
  const float* W3 = (const float*)d_in[7];
  const float* b3 = (const float*)d_in[8];
  const float* Wc = (const float*)d_in[9];
  const float* bc = (const float*)d_in[10];
  float* out = (float*)d_out;

  const int N = in_sizes[0] / 128;
  const int E = in_sizes[1] / 2;
  const int G = out_size / 10;
  const int cap2 = E / NSUB + E / NSUB / 8 + 64;  // ~12.5% slack (>=10 sigma)

  char* W = (char*)d_ws;
  size_t off = 0;
  auto take = [&](size_t b) -> void* {
    void* p = W + off;
    off += (b + 255) & ~(size_t)255;
    return p;
  };
  int* flag = (int*)take(4);
  int* rowptr = (int*)take((size_t)4 * (N + 1));
  int* scur = (int*)take((size_t)4 * NSUB);
  int* sbase = (int*)take((size_t)4 * (NSUB + 1));
  float* dinv = (float*)take((size_t)4 * N);
  int* csr = (int*)take((size_t)4 * E);
  unsigned short* hs = (unsigned short*)take((size_t)2 * N * 64);
  unsigned short* cur = (unsigned short*)take((size_t)2 * N * 64);
  unsigned* ebuf2 = (unsigned*)take((size_t)4 * NSUB * cap2);
  float* pooled = (float*)take((size_t)4 * G * 64);
  (void)ws_size;

  hipMemsetAsync(scur, 0, (size_t)4 * NSUB, stream);

  k_detect<<<1, 256, 0, stream>>>((const unsigned*)ei, flag);
  k_part<<<512, 1024, 0, stream>>>(ei, E, flag, cap2, scur, ebuf2, N);
  k_sscan<<<1, 256, 0, stream>>>(scur, sbase);
  k_build<<<NSUB, 512, 0, stream>>>(ebuf2, scur, cap2, sbase, rowptr, dinv, csr, N);

  const int TILES = (N + 63) / 64;
  // layer 1: x[N,128] (f32) @ W1 -> hs (bf16); aggregate -> cur (bf16)
  k_gemm_mfma<128, false><<<TILES, 256, 0, stream>>>(x, W1, dinv, hs, N);
  k_agg<<<4096, 256, 0, stream>>>(hs, rowptr, csr, dinv, b1, (unsigned*)cur, N);
  // layer 2 (bf16 in)
  k_gemm_mfma<64, true><<<TILES, 256, 0, stream>>>(cur, W2, dinv, hs, N);
  k_agg<<<4096, 256, 0, stream>>>(hs, rowptr, csr, dinv, b2, (unsigned*)cur, N);
  // layer 3 (bf16 in)
  k_gemm_mfma<64, true><<<TILES, 256, 0, stream>>>(cur, W3, dinv, hs, N);
  k_agg<<<4096, 256, 0, stream>>>(hs, rowptr, csr, dinv, b3, (unsigned*)cur, N);

  k_pool<<<G, 256, 0, stream>>>(cur, batch, flag, pooled, N);
  k_classify<<<(G * 10 + 255) / 256, 256, 0, stream>>>(pooled, Wc, bc, out, G * 10);
}

// Round 15
// 330.146 us; speedup vs baseline: 1.3158x; 1.0419x over previous
//
#include <hip/hip_runtime.h>

// ---------------------------------------------------------------------------
// MalwareGNN: 3-layer GCN (transform -> normalized aggregate) + mean pool + FC
//   * CSR build: k_part (512x1024, per-block int64-detect inlined, packed u32
//     edges) -> k_build (inline scur-scan, fused hist/prefix/rowptr/dinv/csr)
//   * layer 1: MFMA GEMM x(f32)@W1 -> hsA (bf16, dinv-scaled)
//   * FUSED agg+gemm (layers 1->2, 2->3): block owns 64 nodes; gather-agg
//     into swizzled LDS X-tile -> in-block K=64 MFMA with W_{l+1} -> hs out
//     (double-buffered hsA/hsB; kills global cur traffic + 2 launches)
//   * agg3 standalone (gather floor: 158MB L2-miss @ ~3TB/s) -> bf16 cur
//   * k_poolcls: mean-pool per graph + fused 10-class FC
//   8 dispatches total (was 13).
// ---------------------------------------------------------------------------

#define NSUB 512
#define MAXNODES 256 // >= ceil(N/NSUB); N=100k -> 196 (also packing bound)

typedef __attribute__((ext_vector_type(8))) short bf16x8;
typedef __attribute__((ext_vector_type(4))) float f32x4;

__device__ __forceinline__ unsigned short f2bf(float x) {
  unsigned u = __float_as_uint(x);
  u += 0x7FFFu + ((u >> 16) & 1u);  // RNE
  return (unsigned short)(u >> 16);
}
__device__ __forceinline__ float bf2f(unsigned short h) {
  return __uint_as_float((unsigned)h << 16);
}
__device__ __forceinline__ float uf(unsigned u) { return __uint_as_float(u); }

// low 4B of index i (values < 2^31 so low word == value)
__device__ __forceinline__ int idx32(const int* p, long long i, bool wide) {
  return __builtin_nontemporal_load(p + (wide ? 2 * i : i));
}

// single-pass 512-bin partition, packed 4B edges; per-block int64 detection
// (block 0 publishes flag for k_poolcls)
__global__ __launch_bounds__(1024) void k_part(const void* __restrict__ eiv, int E,
                                               int* __restrict__ flag, int cap2,
                                               int* __restrict__ scur,
                                               unsigned* __restrict__ ebuf2, int N) {
  __shared__ int cnt[NSUB];
  __shared__ int base[NSUB];
  __shared__ int off[NSUB];
  __shared__ int s_any;
  const unsigned* eu = (const unsigned*)eiv;
  const int* ei = (const int*)eiv;
  const int tid = threadIdx.x;
  if (tid == 0) s_any = 0;
  __syncthreads();
  unsigned vv = 0;
  for (int i = tid; i < 8192; i += 1024) vv |= eu[2 * i + 1];
  if (vv) atomicOr(&s_any, 1);
  for (int i = tid; i < NSUB; i += 1024) { cnt[i] = 0; off[i] = 0; }
  __syncthreads();
  const bool wide = (s_any == 0);  // int64: high words of first 8192 all zero
  if (blockIdx.x == 0 && tid == 0) *flag = wide ? 1 : 0;
  const int chunk = (E + gridDim.x - 1) / gridDim.x;
  const int c0 = blockIdx.x * chunk;
  const int c1 = (c0 + chunk < E) ? c0 + chunk : E;
  for (int e = c0 + tid; e < c1; e += 1024) {
    const int d = idx32(ei, (long long)E + e, wide);
    const int b = (int)(((long long)d * NSUB) / N);
    atomicAdd(&cnt[b], 1);
  }
  __syncthreads();
  for (int i = tid; i < NSUB; i += 1024) base[i] = atomicAdd(&scur[i], cnt[i]);
  __syncthreads();
  const long long cap = (long long)NSUB * cap2;
  for (int e = c0 + tid; e < c1; e += 1024) {
    const int d = idx32(ei, (long long)E + e, wide);
    const int s = idx32(ei, e, wide);
    const int b = (int)(((long long)d * NSUB) / N);
    const int nlo = (int)(((long long)N * b + NSUB - 1) / NSUB);
    const int o = atomicAdd(&off[b], 1);
    long long pos = (long long)b * cap2 + base[b] + o;
    if (pos >= cap) pos = cap - 1;  // paranoia clamp (slack makes this dead)
    ebuf2[pos] = ((unsigned)(d - nlo) << 24) | (unsigned)s;
  }
}

// FUSED per-sub-bucket (512 thr): inline scur scan -> hist -> prefix ->
// rowptr+dinv -> LDS-cursor csr scatter (2nd pass L2-hot)
__global__ __launch_bounds__(512) void k_build(const unsigned* __restrict__ ebuf2,
                                               const int* __restrict__ scur, int cap2,
                                               int* __restrict__ rowptr,
                                               float* __restrict__ dinv,
                                               int* __restrict__ csr, int N) {
  __shared__ int sc[NSUB];
  __shared__ int hist[256];
  __shared__ int pref[256];
  const int s = blockIdx.x;
  const int t = threadIdx.x;
  if (t < NSUB) sc[t] = scur[t];
  __syncthreads();
  for (int off = 1; off < NSUB; off <<= 1) {
    int tv = 0;
    if (t < NSUB && t >= off) tv = sc[t - off];
    __syncthreads();
    if (t < NSUB) sc[t] += tv;
    __syncthreads();
  }
  const int mycnt = scur[s];
  const int sb = sc[s] - mycnt;       // exclusive base for this sub-bucket
  const int total = sc[NSUB - 1];
  int nlo = (int)(((long long)N * s + NSUB - 1) / NSUB);
  int nhi = (int)(((long long)N * (s + 1) + NSUB - 1) / NSUB);
  if (nhi > N) nhi = N;
  const int nn = nhi - nlo;
  if (t < 256) hist[t] = 0;
  __syncthreads();
  const long long e0 = (long long)s * cap2;
  const long long e1 = e0 + mycnt;
  for (long long e = e0 + t; e < e1; e += 512) {
    const unsigned v = __builtin_nontemporal_load(&ebuf2[e]);
    atomicAdd(&hist[v >> 24], 1);
  }
  __syncthreads();
  int h = 0;
  if (t < 256) {
    h = hist[t];
    pref[t] = h;
  }
  __syncthreads();
  for (int off = 1; off < 256; off <<= 1) {
    int tv = 0;
    if (t < 256 && t >= off) tv = pref[t - off];
    __syncthreads();
    if (t < 256) pref[t] += tv;
    __syncthreads();
  }
  if (t < 256) {
    const int cur0 = sb + pref[t] - h;  // exclusive prefix -> cursor
    if (t < nn) {
      rowptr[nlo + t] = cur0;
      dinv[nlo + t] = rsqrtf((float)(h + 1));  // +1 self loop
    }
    hist[t] = cur0;  // LDS cursors
  }
  if (s == NSUB - 1 && t == 0) rowptr[N] = total;
  __syncthreads();
  for (long long e = e0 + t; e < e1; e += 512) {  // 2nd pass: L2-hot
    const unsigned v = ebuf2[e];
    const int pos = atomicAdd(&hist[v >> 24], 1);
    csr[pos] = (int)(v & 0x00FFFFFFu);
  }
}

// ---- HS = bf16(dinv * (X @ W)) via MFMA; layer-1 (f32 input, K=128) --------
template <int K, bool BF16IN>
__global__ __launch_bounds__(256) void k_gemm_mfma(const void* __restrict__ Xv,
                                                   const float* __restrict__ Wg,
                                                   const float* __restrict__ dinv,
                                                   unsigned short* __restrict__ HS,
                                                   int N) {
  __shared__ short Xl[64 * K];
  __shared__ short Wt[64 * K];
  const int t = threadIdx.x;
  const long long r0 = (long long)blockIdx.x * 64;
  const int rows = (int)((N - r0) < 64 ? (N - r0) : 64);

  for (int idx = t; idx < K * 64; idx += 256) {
    const int k = idx >> 6, n = idx & 63;
    Wt[n * K + (((k >> 3) ^ (n & 7)) << 3) + (k & 7)] = (short)f2bf(Wg[idx]);
  }
  const int CH = K / 8;
#pragma unroll
  for (int p = 0; p < K / 32; ++p) {
    const int c = p * 256 + t;  // c < 64*CH
    const int row = c / CH, ch = c % CH;
    const int src = (row < rows) ? row : 0;
    bf16x8 h;
    if constexpr (BF16IN) {
      h = *(const bf16x8*)&((const unsigned short*)Xv)[(r0 + src) * K + ch * 8];
    } else {
      const float* X = (const float*)Xv;
      const float4 v0 = *(const float4*)&X[(r0 + src) * K + ch * 8];
      const float4 v1 = *(const float4*)&X[(r0 + src) * K + ch * 8 + 4];
      h[0] = (short)f2bf(v0.x); h[1] = (short)f2bf(v0.y);
      h[2] = (short)f2bf(v0.z); h[3] = (short)f2bf(v0.w);
      h[4] = (short)f2bf(v1.x); h[5] = (short)f2bf(v1.y);
      h[6] = (short)f2bf(v1.z); h[7] = (short)f2bf(v1.w);
    }
    *(bf16x8*)&Xl[row * K + ((ch ^ (row & 7)) << 3)] = h;
  }
  __syncthreads();

  const int lane = t & 63, w = t >> 6;
  const int lo = lane & 15, hi = lane >> 4;
  const int rowa = w * 16 + lo;

  f32x4 acc[4];
#pragma unroll
  for (int i = 0; i < 4; ++i) acc[i] = (f32x4){0.f, 0.f, 0.f, 0.f};

  bf16x8 a[K / 32];
#pragma unroll
  for (int kk = 0; kk < K / 32; ++kk)
    a[kk] = *(const bf16x8*)&Xl[rowa * K + (((kk * 4 + hi) ^ (rowa & 7)) << 3)];

#pragma unroll
  for (int n0 = 0; n0 < 4; ++n0) {
    const int n = n0 * 16 + lo;
#pragma unroll
    for (int kk = 0; kk < K / 32; ++kk) {
      const bf16x8 b = *(const bf16x8*)&Wt[n * K + (((kk * 4 + hi) ^ (n & 7)) << 3)];
      acc[n0] = __builtin_amdgcn_mfma_f32_16x16x32_bf16(a[kk], b, acc[n0], 0, 0, 0);
    }
  }

  float dv[4];
#pragma unroll
  for (int r = 0; r < 4; ++r) {
    const int rr = w * 16 + hi * 4 + r;
    dv[r] = dinv[r0 + (rr < rows ? rr : 0)];
  }
#pragma unroll
  for (int n0 = 0; n0 < 4; ++n0) {
#pragma unroll
    for (int r = 0; r < 4; ++r) {
      const int rr = w * 16 + hi * 4 + r;
      if (rr < rows)
        HS[(r0 + rr) * 64 + n0 * 16 + lo] = f2bf(dv[r] * acc[n0][r]);
    }
  }
}

// ---- FUSED agg + next-layer GEMM (K=64) ------------------------------------
// Block owns 64 consecutive nodes; wave wid handles 16. Gather-agg epilogue
// writes bf16 rows into the swizzled LDS X-tile; in-block MFMA with W_next.
__global__ __launch_bounds__(256) void k_agg_gemm(
    const unsigned short* __restrict__ HSin, const int* __restrict__ rowptr,
    const int* __restrict__ csr, const float* __restrict__ dinv,
    const float* __restrict__ bias, const float* __restrict__ Wg,
    unsigned short* __restrict__ HSout, int N) {
  __shared__ short Xl[64 * 64];
  __shared__ short Wt[64 * 64];
  const int t = threadIdx.x;
  const long long r0 = (long long)blockIdx.x * 64;
  const int rows = (int)((N - r0) < 64 ? (N - r0) : 64);
  for (int idx = t; idx < 64 * 64; idx += 256) {
    const int k = idx >> 6, n = idx & 63;
    Wt[n * 64 + (((k >> 3) ^ (n & 7)) << 3) + (k & 7)] = (short)f2bf(Wg[idx]);
  }
  if (rows < 64) {
    for (int i = t; i < 64 * 64; i += 256) Xl[i] = 0;
  }
  __syncthreads();

  const int lane = t & 63;
  const int wid = t >> 6;
  const int c4 = lane & 15;
  const int q = lane >> 4;
  const float bb0 = bias[4 * c4 + 0], bb1 = bias[4 * c4 + 1];
  const float bb2 = bias[4 * c4 + 2], bb3 = bias[4 * c4 + 3];
  const uint2* __restrict__ H8 = (const uint2*)HSin;
  const unsigned M = 0xffff0000u;
  for (int i = 0; i < 16; ++i) {
    const int row = wid * 16 + i;
    if (row >= rows) break;  // wave-uniform
    const int node = (int)(r0 + row);
    const int s0 = rowptr[node], s1 = rowptr[node + 1];
    float a0 = 0.f, a1 = 0.f, a2 = 0.f, a3 = 0.f;
    float c0 = 0.f, c1 = 0.f, c2 = 0.f, c3 = 0.f;
    if (q == 0) {  // self loop
      const uint2 u = H8[(long long)node * 16 + c4];
      a0 += uf(u.x << 16); a1 += uf(u.x & M);
      a2 += uf(u.y << 16); a3 += uf(u.y & M);
    }
    for (int base = s0; base < s1; base += 64) {
      int m = s1 - base;
      if (m > 64) m = 64;
      const int idx = (base + lane < s1) ? csr[base + lane] : 0;
      const int ng = m >> 2;
      int g = 0;
      for (; g + 2 <= ng; g += 2) {
        const int e0 = __shfl(idx, 4 * g + q, 64);
        const int e1 = __shfl(idx, 4 * g + 4 + q, 64);
        const uint2 u0 = H8[(long long)e0 * 16 + c4];
        const uint2 u1 = H8[(long long)e1 * 16 + c4];
        a0 += uf(u0.x << 16); a1 += uf(u0.x & M);
        a2 += uf(u0.y << 16); a3 += uf(u0.y & M);
        c0 += uf(u1.x << 16); c1 += uf(u1.x & M);
        c2 += uf(u1.y << 16); c3 += uf(u1.y & M);
      }
      for (; g < ng; ++g) {
        const int e0 = __shfl(idx, 4 * g + q, 64);
        const uint2 u0 = H8[(long long)e0 * 16 + c4];
        a0 += uf(u0.x << 16); a1 += uf(u0.x & M);
        a2 += uf(u0.y << 16); a3 += uf(u0.y & M);
      }
      const int rm = m & 3;
      if (rm) {
        const int e = __shfl(idx, (m & ~3) + (q < rm ? q : 0), 64);
        if (q < rm) {
          const uint2 u = H8[(long long)e * 16 + c4];
          a0 += uf(u.x << 16); a1 += uf(u.x & M);
          a2 += uf(u.y << 16); a3 += uf(u.y & M);
        }
      }
    }
    a0 += c0; a1 += c1; a2 += c2; a3 += c3;
    a0 += __shfl_xor(a0, 16, 64); a0 += __shfl_xor(a0, 32, 64);
    a1 += __shfl_xor(a1, 16, 64); a1 += __shfl_xor(a1, 32, 64);
    a2 += __shfl_xor(a2, 16, 64); a2 += __shfl_xor(a2, 32, 64);
    a3 += __shfl_xor(a3, 16, 64); a3 += __shfl_xor(a3, 32, 64);
    if (q == 0) {
      const float dv = dinv[node];
      const unsigned short o0 = f2bf(fmaxf(fmaf(dv, a0, bb0), 0.f));
      const unsigned short o1 = f2bf(fmaxf(fmaf(dv, a1, bb1), 0.f));
      const unsigned short o2 = f2bf(fmaxf(fmaf(dv, a2, bb2), 0.f));
      const unsigned short o3 = f2bf(fmaxf(fmaf(dv, a3, bb3), 0.f));
      uint2 o;
      o.x = (unsigned)o0 | ((unsigned)o1 << 16);
      o.y = (unsigned)o2 | ((unsigned)o3 << 16);
      const int ch = c4 >> 1;
      *(uint2*)&Xl[row * 64 + ((ch ^ (row & 7)) << 3) + (c4 & 1) * 4] = o;
    }
  }
  __syncthreads();

  // MFMA: K=64, same fragment scheme as k_gemm_mfma
  const int lo = lane & 15, hi = lane >> 4;
  const int rowa = wid * 16 + lo;
  f32x4 acc[4];
#pragma unroll
  for (int i = 0; i < 4; ++i) acc[i] = (f32x4){0.f, 0.f, 0.f, 0.f};
  bf16x8 a[2];
#pragma unroll
  for (int kk = 0; kk < 2; ++kk)
    a[kk] = *(const bf16x8*)&Xl[rowa * 64 + (((kk * 4 + hi) ^ (rowa & 7)) << 3)];
#pragma unroll
  for (int n0 = 0; n0 < 4; ++n0) {
    const int n = n0 * 16 + lo;
#pragma unroll
    for (int kk = 0; kk < 2; ++kk) {
      const bf16x8 b = *(const bf16x8*)&Wt[n * 64 + (((kk * 4 + hi) ^ (n & 7)) << 3)];
      acc[n0] = __builtin_amdgcn_mfma_f32_16x16x32_bf16(a[kk], b, acc[n0], 0, 0, 0);
    }
  }
  float dvv[4];
#pragma unroll
  for (int r = 0; r < 4; ++r) {
    const int rr = wid * 16 + hi * 4 + r;
    dvv[r] = dinv[r0 + (rr < rows ? rr : 0)];
  }
#pragma unroll
  for (int n0 = 0; n0 < 4; ++n0) {
#pragma unroll
    for (int r = 0; r < 4; ++r) {
      const int rr = wid * 16 + hi * 4 + r;
      if (rr < rows)
        HSout[(r0 + rr) * 64 + n0 * 16 + lo] = f2bf(dvv[r] * acc[n0][r]);
    }
  }
}

// ---- standalone agg (layer 3): bf16 packed output --------------------------
__global__ void k_agg(const unsigned short* __restrict__ HS, const int* __restrict__ rowptr,
                      const int* __restrict__ csr, const float* __restrict__ dinv,
                      const float* __restrict__ bias, unsigned* __restrict__ OUT, int N) {
  const int lane = threadIdx.x & 63;
  const int wid = threadIdx.x >> 6;
  const int wpb = blockDim.x >> 6;
  const int c4 = lane & 15;
  const int q = lane >> 4;
  const float b0 = bias[4 * c4 + 0], b1 = bias[4 * c4 + 1];
  const float b2 = bias[4 * c4 + 2], b3 = bias[4 * c4 + 3];
  const uint2* __restrict__ H8 = (const uint2*)HS;
  uint2* __restrict__ O8 = (uint2*)OUT;
  const unsigned M = 0xffff0000u;
  for (int node = blockIdx.x * wpb + wid; node < N; node += wpb * gridDim.x) {
    const int s0 = rowptr[node], s1 = rowptr[node + 1];
    float a0 = 0.f, a1 = 0.f, a2 = 0.f, a3 = 0.f;
    float c0 = 0.f, c1 = 0.f, c2 = 0.f, c3 = 0.f;
    if (q == 0) {
      const uint2 u = H8[(long long)node * 16 + c4];
      a0 += uf(u.x << 16); a1 += uf(u.x & M);
      a2 += uf(u.y << 16); a3 += uf(u.y & M);
    }
    for (int base = s0; base < s1; base += 64) {
      int m = s1 - base;
      if (m > 64) m = 64;
      const int idx = (base + lane < s1) ? csr[base + lane] : 0;
      const int ng = m >> 2;
      int g = 0;
      for (; g + 2 <= ng; g += 2) {
        const int e0 = __shfl(idx, 4 * g + q, 64);
        const int e1 = __shfl(idx, 4 * g + 4 + q, 64);
        const uint2 u0 = H8[(long long)e0 * 16 + c4];
        const uint2 u1 = H8[(long long)e1 * 16 + c4];
        a0 += uf(u0.x << 16); a1 += uf(u0.x & M);
        a2 += uf(u0.y << 16); a3 += uf(u0.y & M);
        c0 += uf(u1.x << 16); c1 += uf(u1.x & M);
        c2 += uf(u1.y << 16); c3 += uf(u1.y & M);
      }
      for (; g < ng; ++g) {
        const int e0 = __shfl(idx, 4 * g + q, 64);
        const uint2 u0 = H8[(long long)e0 * 16 + c4];
        a0 += uf(u0.x << 16); a1 += uf(u0.x & M);
        a2 += uf(u0.y << 16); a3 += uf(u0.y & M);
      }
      const int rm = m & 3;
      if (rm) {
        const int e = __shfl(idx, (m & ~3) + (q < rm ? q : 0), 64);
        if (q < rm) {
          const uint2 u = H8[(long long)e * 16 + c4];
          a0 += uf(u.x << 16); a1 += uf(u.x & M);
          a2 += uf(u.y << 16); a3 += uf(u.y & M);
        }
      }
    }
    a0 += c0; a1 += c1; a2 += c2; a3 += c3;
    a0 += __shfl_xor(a0, 16, 64); a0 += __shfl_xor(a0, 32, 64);
    a1 += __shfl_xor(a1, 16, 64); a1 += __shfl_xor(a1, 32, 64);
    a2 += __shfl_xor(a2, 16, 64); a2 += __shfl_xor(a2, 32, 64);
    a3 += __shfl_xor(a3, 16, 64); a3 += __shfl_xor(a3, 32, 64);
    if (q == 0) {
      const float dv = dinv[node];
      const unsigned short o0 = f2bf(fmaxf(fmaf(dv, a0, b0), 0.f));
      const unsigned short o1 = f2bf(fmaxf(fmaf(dv, a1, b1), 0.f));
      const unsigned short o2 = f2bf(fmaxf(fmaf(dv, a2, b2), 0.f));
      const unsigned short o3 = f2bf(fmaxf(fmaf(dv, a3, b3), 0.f));
      uint2 o;
      o.x = (unsigned)o0 | ((unsigned)o1 << 16);
      o.y = (unsigned)o2 | ((unsigned)o3 << 16);
      O8[(long long)node * 16 + c4] = o;
    }
  }
}

// ---- mean pool per graph + fused classifier --------------------------------
__global__ void k_poolcls(const unsigned short* __restrict__ H,
                          const void* __restrict__ batch, const int* __restrict__ flag,
                          const float* __restrict__ Wc, const float* __restrict__ bc,
                          float* __restrict__ out, int N) {
  __shared__ int se[2];
  __shared__ float red[4][64];
  __shared__ float pl[64];
  bool wide = (*flag != 0);
  int g = blockIdx.x;
  if (threadIdx.x < 2) {
    int target = g + threadIdx.x;
    int lo = 0, hi = N;
    while (lo < hi) {
      int mid = (lo + hi) >> 1;
      long long v = wide ? ((const long long*)batch)[mid] : (long long)((const int*)batch)[mid];
      if (v < target) lo = mid + 1; else hi = mid;
    }
    se[threadIdx.x] = lo;
  }
  __syncthreads();
  int s = se[0], e = se[1];
  int lane = threadIdx.x & 63, wid = threadIdx.x >> 6;
  float acc = 0.f;
  for (int r = s + wid; r < e; r += 4) acc += bf2f(H[(long long)r * 64 + lane]);
  red[wid][lane] = acc;
  __syncthreads();
  if (wid == 0) {
    float v = red[0][lane] + red[1][lane] + red[2][lane] + red[3][lane];
    float cnt = (float)(e - s);
    pl[lane] = v / fmaxf(cnt, 1.f);
  }
  __syncthreads();
  if (threadIdx.x < 10) {
    float a = bc[threadIdx.x];
#pragma unroll
    for (int h = 0; h < 64; ++h) a += pl[h] * Wc[h * 10 + threadIdx.x];
    out[g * 10 + threadIdx.x] = a;
  }
}

extern "C" void kernel_launch(void* const* d_in, const int* in_sizes, int n_in,
                              void* d_out, int out_size, void* d_ws, size_t ws_size,
                              hipStream_t stream) {
  const float* x = (const float*)d_in[0];
  const void* ei = d_in[1];
  const void* batch = d_in[2];
  const float* W1 = (const float*)d_in[3];
  const float* b1 = (const float*)d_in[4];
  const float* W2 = (const float*)d_in[5];
  const float* b2 = (const float*)d_in[6];
  const float* W3 = (const float*)d_in[7];
  const float* b3 = (const float*)d_in[8];
  const float* Wc = (const float*)d_in[9];
  const float* bc = (const float*)d_in[10];
  float* out = (float*)d_out;

  const int N = in_sizes[0] / 128;
  const int E = in_sizes[1] / 2;
  const int G = out_size / 10;
  const int cap2 = E / NSUB + E / NSUB / 8 + 64;  // ~12.5% slack (>=10 sigma)

  char* W = (char*)d_ws;
  size_t off = 0;
  auto take = [&](size_t b) -> void* {
    void* p = W + off;
    off += (b + 255) & ~(size_t)255;
    return p;
  };
  int* flag = (int*)take(4);
  int* rowptr = (int*)take((size_t)4 * (N + 1));
  int* scur = (int*)take((size_t)4 * NSUB);
  float* dinv = (float*)take((size_t)4 * N);
  int* csr = (int*)take((size_t)4 * E);
  unsigned short* hsA = (unsigned short*)take((size_t)2 * N * 64);
  unsigned short* hsB = (unsigned short*)take((size_t)2 * N * 64);
  unsigned* ebuf2 = (unsigned*)take((size_t)4 * NSUB * cap2);
  (void)ws_size;

  hipMemsetAsync(scur, 0, (size_t)4 * NSUB, stream);

  k_part<<<512, 1024, 0, stream>>>(ei, E, flag, cap2, scur, ebuf2, N);
  k_build<<<NSUB, 512, 0, stream>>>(ebuf2, scur, cap2, rowptr, dinv, csr, N);

  const int TILES = (N + 63) / 64;
  // layer 1 transform: x (f32) @ W1 -> hsA
  k_gemm_mfma<128, false><<<TILES, 256, 0, stream>>>(x, W1, dinv, hsA, N);
  // fused agg1(b1) + transform W2 -> hsB
  k_agg_gemm<<<TILES, 256, 0, stream>>>(hsA, rowptr, csr, dinv, b1, W2, hsB, N);
  // fused agg2(b2) + transform W3 -> hsA
  k_agg_gemm<<<TILES, 256, 0, stream>>>(hsB, rowptr, csr, dinv, b2, W3, hsA, N);
  // agg3(b3) -> bf16 node features into hsB (dead buffer)
  k_agg<<<4096, 256, 0, stream>>>(hsA, rowptr, csr, dinv, b3, (unsigned*)hsB, N);

  k_poolcls<<<G, 256, 0, stream>>>(hsB, batch, flag, Wc, bc, out, N);
}

// Round 16
// 309.139 us; speedup vs baseline: 1.4052x; 1.0680x over previous
//
#include <hip/hip_runtime.h>

// ---------------------------------------------------------------------------
// MalwareGNN: 3-layer GCN (transform -> normalized aggregate) + mean pool + FC
//   * CSR build: k_part (512x1024, inline int64-detect, packed u32 edges) ->
//     k_build (inline scur-scan, register-stashed edges: no 2nd ebuf2 read)
//   * layer 1: MFMA GEMM x(f32)@W1 -> hsA (bf16, dinv-scaled)
//   * FUSED agg+gemm (1->2, 2->3): block owns 64 nodes; gather-agg into
//     swizzled LDS X-tile -> in-block K=64 MFMA -> hs out (hsA/hsB dbuf)
//   * FUSED agg3+pool: tile-based gather-agg; per-wave f32 partial sums per
//     graph (batch sorted); atomicAdd flush at graph boundaries -> pooled
//   * k_cls: per-graph count (binary search) + divide + 10-class FC
//   Gather is AT STRUCTURAL FLOOR (158MB L2-miss @ ~3TB/s, R10-R12 A/Bs).
//   8 dispatches: memset, part, build, gemm1, agg_gemm x2, agg_pool, cls.
// ---------------------------------------------------------------------------

#define NSUB 512
#define MAXNODES 256 // >= ceil(N/NSUB); N=100k -> 196 (also packing bound)

typedef __attribute__((ext_vector_type(8))) short bf16x8;
typedef __attribute__((ext_vector_type(4))) float f32x4;

__device__ __forceinline__ unsigned short f2bf(float x) {
  unsigned u = __float_as_uint(x);
  u += 0x7FFFu + ((u >> 16) & 1u);  // RNE
  return (unsigned short)(u >> 16);
}
__device__ __forceinline__ float bf2f(unsigned short h) {
  return __uint_as_float((unsigned)h << 16);
}
__device__ __forceinline__ float uf(unsigned u) { return __uint_as_float(u); }

// low 4B of index i (values < 2^31 so low word == value)
__device__ __forceinline__ int idx32(const int* p, long long i, bool wide) {
  return __builtin_nontemporal_load(p + (wide ? 2 * i : i));
}

// single-pass 512-bin partition, packed 4B edges; per-block int64 detection
__global__ __launch_bounds__(1024) void k_part(const void* __restrict__ eiv, int E,
                                               int* __restrict__ flag, int cap2,
                                               int* __restrict__ scur,
                                               unsigned* __restrict__ ebuf2, int N) {
  __shared__ int cnt[NSUB];
  __shared__ int base[NSUB];
  __shared__ int off[NSUB];
  __shared__ int s_any;
  const unsigned* eu = (const unsigned*)eiv;
  const int* ei = (const int*)eiv;
  const int tid = threadIdx.x;
  if (tid == 0) s_any = 0;
  __syncthreads();
  unsigned vv = 0;
  for (int i = tid; i < 8192; i += 1024) vv |= eu[2 * i + 1];
  if (vv) atomicOr(&s_any, 1);
  for (int i = tid; i < NSUB; i += 1024) { cnt[i] = 0; off[i] = 0; }
  __syncthreads();
  const bool wide = (s_any == 0);  // int64: high words of first 8192 all zero
  if (blockIdx.x == 0 && tid == 0) *flag = wide ? 1 : 0;
  const int chunk = (E + gridDim.x - 1) / gridDim.x;
  const int c0 = blockIdx.x * chunk;
  const int c1 = (c0 + chunk < E) ? c0 + chunk : E;
  for (int e = c0 + tid; e < c1; e += 1024) {
    const int d = idx32(ei, (long long)E + e, wide);
    const int b = (int)(((long long)d * NSUB) / N);
    atomicAdd(&cnt[b], 1);
  }
  __syncthreads();
  for (int i = tid; i < NSUB; i += 1024) base[i] = atomicAdd(&scur[i], cnt[i]);
  __syncthreads();
  const long long cap = (long long)NSUB * cap2;
  for (int e = c0 + tid; e < c1; e += 1024) {
    const int d = idx32(ei, (long long)E + e, wide);
    const int s = idx32(ei, e, wide);
    const int b = (int)(((long long)d * NSUB) / N);
    const int nlo = (int)(((long long)N * b + NSUB - 1) / NSUB);
    const int o = atomicAdd(&off[b], 1);
    long long pos = (long long)b * cap2 + base[b] + o;
    if (pos >= cap) pos = cap - 1;  // paranoia clamp (slack makes this dead)
    ebuf2[pos] = ((unsigned)(d - nlo) << 24) | (unsigned)s;
  }
}

// FUSED per-sub-bucket (512 thr): inline scur scan -> hist (edges stashed in
// registers) -> prefix -> rowptr+dinv -> scatter from registers
#define STASHJ 16
__global__ __launch_bounds__(512) void k_build(const unsigned* __restrict__ ebuf2,
                                               const int* __restrict__ scur, int cap2,
                                               int* __restrict__ rowptr,
                                               float* __restrict__ dinv,
                                               int* __restrict__ csr, int N) {
  __shared__ int sc[NSUB];
  __shared__ int hist[256];
  __shared__ int pref[256];
  const int s = blockIdx.x;
  const int t = threadIdx.x;
  if (t < NSUB) sc[t] = scur[t];
  __syncthreads();
  for (int off = 1; off < NSUB; off <<= 1) {
    int tv = 0;
    if (t < NSUB && t >= off) tv = sc[t - off];
    __syncthreads();
    if (t < NSUB) sc[t] += tv;
    __syncthreads();
  }
  const int mycnt = scur[s];
  const int sb = sc[s] - mycnt;  // exclusive base for this sub-bucket
  const int total = sc[NSUB - 1];
  int nlo = (int)(((long long)N * s + NSUB - 1) / NSUB);
  int nhi = (int)(((long long)N * (s + 1) + NSUB - 1) / NSUB);
  if (nhi > N) nhi = N;
  const int nn = nhi - nlo;
  if (t < 256) hist[t] = 0;
  __syncthreads();
  const long long e0 = (long long)s * cap2;
  const long long e1 = e0 + mycnt;
  unsigned stash[STASHJ];
#pragma unroll
  for (int j = 0; j < STASHJ; ++j) {
    const long long e = e0 + t + (long long)j * 512;
    if (e < e1) {
      const unsigned v = __builtin_nontemporal_load(&ebuf2[e]);
      stash[j] = v;
      atomicAdd(&hist[v >> 24], 1);
    }
  }
  for (long long e = e0 + t + (long long)STASHJ * 512; e < e1; e += 512) {
    const unsigned v = __builtin_nontemporal_load(&ebuf2[e]);
    atomicAdd(&hist[v >> 24], 1);
  }
  __syncthreads();
  int h = 0;
  if (t < 256) {
    h = hist[t];
    pref[t] = h;
  }
  __syncthreads();
  for (int off = 1; off < 256; off <<= 1) {
    int tv = 0;
    if (t < 256 && t >= off) tv = pref[t - off];
    __syncthreads();
    if (t < 256) pref[t] += tv;
    __syncthreads();
  }
  if (t < 256) {
    const int cur0 = sb + pref[t] - h;  // exclusive prefix -> cursor
    if (t < nn) {
      rowptr[nlo + t] = cur0;
      dinv[nlo + t] = rsqrtf((float)(h + 1));  // +1 self loop
    }
    hist[t] = cur0;  // LDS cursors
  }
  if (s == NSUB - 1 && t == 0) rowptr[N] = total;
  __syncthreads();
#pragma unroll
  for (int j = 0; j < STASHJ; ++j) {
    const long long e = e0 + t + (long long)j * 512;
    if (e < e1) {
      const unsigned v = stash[j];
      const int pos = atomicAdd(&hist[v >> 24], 1);
      csr[pos] = (int)(v & 0x00FFFFFFu);
    }
  }
  for (long long e = e0 + t + (long long)STASHJ * 512; e < e1; e += 512) {
    const unsigned v = ebuf2[e];
    const int pos = atomicAdd(&hist[v >> 24], 1);
    csr[pos] = (int)(v & 0x00FFFFFFu);
  }
}

// ---- HS = bf16(dinv * (X @ W)) via MFMA; layer-1 (f32 input, K=128) --------
template <int K, bool BF16IN>
__global__ __launch_bounds__(256) void k_gemm_mfma(const void* __restrict__ Xv,
                                                   const float* __restrict__ Wg,
                                                   const float* __restrict__ dinv,
                                                   unsigned short* __restrict__ HS,
                                                   int N) {
  __shared__ short Xl[64 * K];
  __shared__ short Wt[64 * K];
  const int t = threadIdx.x;
  const long long r0 = (long long)blockIdx.x * 64;
  const int rows = (int)((N - r0) < 64 ? (N - r0) : 64);

  for (int idx = t; idx < K * 64; idx += 256) {
    const int k = idx >> 6, n = idx & 63;
    Wt[n * K + (((k >> 3) ^ (n & 7)) << 3) + (k & 7)] = (short)f2bf(Wg[idx]);
  }
  const int CH = K / 8;
#pragma unroll
  for (int p = 0; p < K / 32; ++p) {
    const int c = p * 256 + t;  // c < 64*CH
    const int row = c / CH, ch = c % CH;
    const int src = (row < rows) ? row : 0;
    bf16x8 h;
    if constexpr (BF16IN) {
      h = *(const bf16x8*)&((const unsigned short*)Xv)[(r0 + src) * K + ch * 8];
    } else {
      const float* X = (const float*)Xv;
      const float4 v0 = *(const float4*)&X[(r0 + src) * K + ch * 8];
      const float4 v1 = *(const float4*)&X[(r0 + src) * K + ch * 8 + 4];
      h[0] = (short)f2bf(v0.x); h[1] = (short)f2bf(v0.y);
      h[2] = (short)f2bf(v0.z); h[3] = (short)f2bf(v0.w);
      h[4] = (short)f2bf(v1.x); h[5] = (short)f2bf(v1.y);
      h[6] = (short)f2bf(v1.z); h[7] = (short)f2bf(v1.w);
    }
    *(bf16x8*)&Xl[row * K + ((ch ^ (row & 7)) << 3)] = h;
  }
  __syncthreads();

  const int lane = t & 63, w = t >> 6;
  const int lo = lane & 15, hi = lane >> 4;
  const int rowa = w * 16 + lo;

  f32x4 acc[4];
#pragma unroll
  for (int i = 0; i < 4; ++i) acc[i] = (f32x4){0.f, 0.f, 0.f, 0.f};

  bf16x8 a[K / 32];
#pragma unroll
  for (int kk = 0; kk < K / 32; ++kk)
    a[kk] = *(const bf16x8*)&Xl[rowa * K + (((kk * 4 + hi) ^ (rowa & 7)) << 3)];

#pragma unroll
  for (int n0 = 0; n0 < 4; ++n0) {
    const int n = n0 * 16 + lo;
#pragma unroll
    for (int kk = 0; kk < K / 32; ++kk) {
      const bf16x8 b = *(const bf16x8*)&Wt[n * K + (((kk * 4 + hi) ^ (n & 7)) << 3)];
      acc[n0] = __builtin_amdgcn_mfma_f32_16x16x32_bf16(a[kk], b, acc[n0], 0, 0, 0);
    }
  }

  float dv[4];
#pragma unroll
  for (int r = 0; r < 4; ++r) {
    const int rr = w * 16 + hi * 4 + r;
    dv[r] = dinv[r0 + (rr < rows ? rr : 0)];
  }
#pragma unroll
  for (int n0 = 0; n0 < 4; ++n0) {
#pragma unroll
    for (int r = 0; r < 4; ++r) {
      const int rr = w * 16 + hi * 4 + r;
      if (rr < rows)
        HS[(r0 + rr) * 64 + n0 * 16 + lo] = f2bf(dv[r] * acc[n0][r]);
    }
  }
}

// ---- FUSED agg + next-layer GEMM (K=64) ------------------------------------
__global__ __launch_bounds__(256) void k_agg_gemm(
    const unsigned short* __restrict__ HSin, const int* __restrict__ rowptr,
    const int* __restrict__ csr, const float* __restrict__ dinv,
    const float* __restrict__ bias, const float* __restrict__ Wg,
    unsigned short* __restrict__ HSout, int N) {
  __shared__ short Xl[64 * 64];
  __shared__ short Wt[64 * 64];
  const int t = threadIdx.x;
  const long long r0 = (long long)blockIdx.x * 64;
  const int rows = (int)((N - r0) < 64 ? (N - r0) : 64);
  for (int idx = t; idx < 64 * 64; idx += 256) {
    const int k = idx >> 6, n = idx & 63;
    Wt[n * 64 + (((k >> 3) ^ (n & 7)) << 3) + (k & 7)] = (short)f2bf(Wg[idx]);
  }
  if (rows < 64) {
    for (int i = t; i < 64 * 64; i += 256) Xl[i] = 0;
  }
  __syncthreads();

  const int lane = t & 63;
  const int wid = t >> 6;
  const int c4 = lane & 15;
  const int q = lane >> 4;
  const float bb0 = bias[4 * c4 + 0], bb1 = bias[4 * c4 + 1];
  const float bb2 = bias[4 * c4 + 2], bb3 = bias[4 * c4 + 3];
  const uint2* __restrict__ H8 = (const uint2*)HSin;
  const unsigned M = 0xffff0000u;
  for (int i = 0; i < 16; ++i) {
    const int row = wid * 16 + i;
    if (row >= rows) break;  // wave-uniform
    const int node = (int)(r0 + row);
    const int s0 = rowptr[node], s1 = rowptr[node + 1];
    float a0 = 0.f, a1 = 0.f, a2 = 0.f, a3 = 0.f;
    float c0 = 0.f, c1 = 0.f, c2 = 0.f, c3 = 0.f;
    if (q == 0) {  // self loop
      const uint2 u = H8[(long long)node * 16 + c4];
      a0 += uf(u.x << 16); a1 += uf(u.x & M);
      a2 += uf(u.y << 16); a3 += uf(u.y & M);
    }
    for (int base = s0; base < s1; base += 64) {
      int m = s1 - base;
      if (m > 64) m = 64;
      const int idx = (base + lane < s1) ? csr[base + lane] : 0;
      const int ng = m >> 2;
      int g = 0;
      for (; g + 2 <= ng; g += 2) {
        const int e0 = __shfl(idx, 4 * g + q, 64);
        const int e1 = __shfl(idx, 4 * g + 4 + q, 64);
        const uint2 u0 = H8[(long long)e0 * 16 + c4];
        const uint2 u1 = H8[(long long)e1 * 16 + c4];
        a0 += uf(u0.x << 16); a1 += uf(u0.x & M);
        a2 += uf(u0.y << 16); a3 += uf(u0.y & M);
        c0 += uf(u1.x << 16); c1 += uf(u1.x & M);
        c2 += uf(u1.y << 16); c3 += uf(u1.y & M);
      }
      for (; g < ng; ++g) {
        const int e0 = __shfl(idx, 4 * g + q, 64);
        const uint2 u0 = H8[(long long)e0 * 16 + c4];
        a0 += uf(u0.x << 16); a1 += uf(u0.x & M);
        a2 += uf(u0.y << 16); a3 += uf(u0.y & M);
      }
      const int rm = m & 3;
      if (rm) {
        const int e = __shfl(idx, (m & ~3) + (q < rm ? q : 0), 64);
        if (q < rm) {
          const uint2 u = H8[(long long)e * 16 + c4];
          a0 += uf(u.x << 16); a1 += uf(u.x & M);
          a2 += uf(u.y << 16); a3 += uf(u.y & M);
        }
      }
    }
    a0 += c0; a1 += c1; a2 += c2; a3 += c3;
    a0 += __shfl_xor(a0, 16, 64); a0 += __shfl_xor(a0, 32, 64);
    a1 += __shfl_xor(a1, 16, 64); a1 += __shfl_xor(a1, 32, 64);
    a2 += __shfl_xor(a2, 16, 64); a2 += __shfl_xor(a2, 32, 64);
    a3 += __shfl_xor(a3, 16, 64); a3 += __shfl_xor(a3, 32, 64);
    if (q == 0) {
      const float dv = dinv[node];
      const unsigned short o0 = f2bf(fmaxf(fmaf(dv, a0, bb0), 0.f));
      const unsigned short o1 = f2bf(fmaxf(fmaf(dv, a1, bb1), 0.f));
      const unsigned short o2 = f2bf(fmaxf(fmaf(dv, a2, bb2), 0.f));
      const unsigned short o3 = f2bf(fmaxf(fmaf(dv, a3, bb3), 0.f));
      uint2 o;
      o.x = (unsigned)o0 | ((unsigned)o1 << 16);
      o.y = (unsigned)o2 | ((unsigned)o3 << 16);
      const int ch = c4 >> 1;
      *(uint2*)&Xl[row * 64 + ((ch ^ (row & 7)) << 3) + (c4 & 1) * 4] = o;
    }
  }
  __syncthreads();

  const int lo = lane & 15, hi = lane >> 4;
  const int rowa = wid * 16 + lo;
  f32x4 acc[4];
#pragma unroll
  for (int i = 0; i < 4; ++i) acc[i] = (f32x4){0.f, 0.f, 0.f, 0.f};
  bf16x8 a[2];
#pragma unroll
  for (int kk = 0; kk < 2; ++kk)
    a[kk] = *(const bf16x8*)&Xl[rowa * 64 + (((kk * 4 + hi) ^ (rowa & 7)) << 3)];
#pragma unroll
  for (int n0 = 0; n0 < 4; ++n0) {
    const int n = n0 * 16 + lo;
#pragma unroll
    for (int kk = 0; kk < 2; ++kk) {
      const bf16x8 b = *(const bf16x8*)&Wt[n * 64 + (((kk * 4 + hi) ^ (n & 7)) << 3)];
      acc[n0] = __builtin_amdgcn_mfma_f32_16x16x32_bf16(a[kk], b, acc[n0], 0, 0, 0);
    }
  }
  float dvv[4];
#pragma unroll
  for (int r = 0; r < 4; ++r) {
    const int rr = wid * 16 + hi * 4 + r;
    dvv[r] = dinv[r0 + (rr < rows ? rr : 0)];
  }
#pragma unroll
  for (int n0 = 0; n0 < 4; ++n0) {
#pragma unroll
    for (int r = 0; r < 4; ++r) {
      const int rr = wid * 16 + hi * 4 + r;
      if (rr < rows)
        HSout[(r0 + rr) * 64 + n0 * 16 + lo] = f2bf(dvv[r] * acc[n0][r]);
    }
  }
}

// ---- FUSED agg3 + pool: tile-based gather, per-wave graph partial sums -----
__global__ __launch_bounds__(256) void k_agg_pool(
    const unsigned short* __restrict__ HS, const int* __restrict__ rowptr,
    const int* __restrict__ csr, const float* __restrict__ dinv,
    const float* __restrict__ bias, const void* __restrict__ batch,
    const int* __restrict__ flag, float* __restrict__ pooled, int N) {
  const int t = threadIdx.x;
  const long long r0 = (long long)blockIdx.x * 64;
  const int rows = (int)((N - r0) < 64 ? (N - r0) : 64);
  const int lane = t & 63;
  const int wid = t >> 6;
  const int c4 = lane & 15;
  const int q = lane >> 4;
  const bool wideB = (*flag != 0);
  const int* bi = (const int*)batch;
  const float bb0 = bias[4 * c4 + 0], bb1 = bias[4 * c4 + 1];
  const float bb2 = bias[4 * c4 + 2], bb3 = bias[4 * c4 + 3];
  const uint2* __restrict__ H8 = (const uint2*)HS;
  const unsigned M = 0xffff0000u;
  float ps0 = 0.f, ps1 = 0.f, ps2 = 0.f, ps3 = 0.f;
  int gcur = -1;
  for (int i = 0; i < 16; ++i) {
    const int row = wid * 16 + i;
    if (row >= rows) break;  // wave-uniform
    const int node = (int)(r0 + row);
    const int g = wideB ? (int)((const long long*)batch)[node] : bi[node];
    const int s0 = rowptr[node], s1 = rowptr[node + 1];
    float a0 = 0.f, a1 = 0.f, a2 = 0.f, a3 = 0.f;
    float c0 = 0.f, c1 = 0.f, c2 = 0.f, c3 = 0.f;
    if (q == 0) {  // self loop
      const uint2 u = H8[(long long)node * 16 + c4];
      a0 += uf(u.x << 16); a1 += uf(u.x & M);
      a2 += uf(u.y << 16); a3 += uf(u.y & M);
    }
    for (int base = s0; base < s1; base += 64) {
      int m = s1 - base;
      if (m > 64) m = 64;
      const int idx = (base + lane < s1) ? csr[base + lane] : 0;
      const int ng = m >> 2;
      int gg = 0;
      for (; gg + 2 <= ng; gg += 2) {
        const int e0 = __shfl(idx, 4 * gg + q, 64);
        const int e1 = __shfl(idx, 4 * gg + 4 + q, 64);
        const uint2 u0 = H8[(long long)e0 * 16 + c4];
        const uint2 u1 = H8[(long long)e1 * 16 + c4];
        a0 += uf(u0.x << 16); a1 += uf(u0.x & M);
        a2 += uf(u0.y << 16); a3 += uf(u0.y & M);
        c0 += uf(u1.x << 16); c1 += uf(u1.x & M);
        c2 += uf(u1.y << 16); c3 += uf(u1.y & M);
      }
      for (; gg < ng; ++gg) {
        const int e0 = __shfl(idx, 4 * gg + q, 64);
        const uint2 u0 = H8[(long long)e0 * 16 + c4];
        a0 += uf(u0.x << 16); a1 += uf(u0.x & M);
        a2 += uf(u0.y << 16); a3 += uf(u0.y & M);
      }
      const int rm = m & 3;
      if (rm) {
        const int e = __shfl(idx, (m & ~3) + (q < rm ? q : 0), 64);
        if (q < rm) {
          const uint2 u = H8[(long long)e * 16 + c4];
          a0 += uf(u.x << 16); a1 += uf(u.x & M);
          a2 += uf(u.y << 16); a3 += uf(u.y & M);
        }
      }
    }
    a0 += c0; a1 += c1; a2 += c2; a3 += c3;
    a0 += __shfl_xor(a0, 16, 64); a0 += __shfl_xor(a0, 32, 64);
    a1 += __shfl_xor(a1, 16, 64); a1 += __shfl_xor(a1, 32, 64);
    a2 += __shfl_xor(a2, 16, 64); a2 += __shfl_xor(a2, 32, 64);
    a3 += __shfl_xor(a3, 16, 64); a3 += __shfl_xor(a3, 32, 64);
    // flush on graph boundary (wave-uniform g)
    if (g != gcur) {
      if (gcur >= 0 && q == 0) {
        atomicAdd(&pooled[gcur * 64 + 4 * c4 + 0], ps0);
        atomicAdd(&pooled[gcur * 64 + 4 * c4 + 1], ps1);
        atomicAdd(&pooled[gcur * 64 + 4 * c4 + 2], ps2);
        atomicAdd(&pooled[gcur * 64 + 4 * c4 + 3], ps3);
      }
      ps0 = ps1 = ps2 = ps3 = 0.f;
      gcur = g;
    }
    if (q == 0) {
      const float dv = dinv[node];
      ps0 += fmaxf(fmaf(dv, a0, bb0), 0.f);
      ps1 += fmaxf(fmaf(dv, a1, bb1), 0.f);
      ps2 += fmaxf(fmaf(dv, a2, bb2), 0.f);
      ps3 += fmaxf(fmaf(dv, a3, bb3), 0.f);
    }
  }
  if (gcur >= 0 && q == 0) {
    atomicAdd(&pooled[gcur * 64 + 4 * c4 + 0], ps0);
    atomicAdd(&pooled[gcur * 64 + 4 * c4 + 1], ps1);
    atomicAdd(&pooled[gcur * 64 + 4 * c4 + 2], ps2);
    atomicAdd(&pooled[gcur * 64 + 4 * c4 + 3], ps3);
  }
}

// ---- per-graph count + divide + FC ------------------------------------------
__global__ __launch_bounds__(64) void k_cls(const float* __restrict__ pooled,
                                            const void* __restrict__ batch,
                                            const int* __restrict__ flag,
                                            const float* __restrict__ Wc,
                                            const float* __restrict__ bc,
                                            float* __restrict__ out, int N) {
  __shared__ int se[2];
  __shared__ float pl[64];
  const bool wide = (*flag != 0);
  const int g = blockIdx.x;
  if (threadIdx.x < 2) {
    int target = g + threadIdx.x;
    int lo = 0, hi = N;
    while (lo < hi) {
      int mid = (lo + hi) >> 1;
      long long v = wide ? ((const long long*)batch)[mid] : (long long)((const int*)batch)[mid];
      if (v < target) lo = mid + 1; else hi = mid;
    }
    se[threadIdx.x] = lo;
  }
  __syncthreads();
  const float cnt = (float)(se[1] - se[0]);
  pl[threadIdx.x] = pooled[g * 64 + threadIdx.x] / fmaxf(cnt, 1.f);
  __syncthreads();
  if (threadIdx.x < 10) {
    float a = bc[threadIdx.x];
#pragma unroll
    for (int h = 0; h < 64; ++h) a += pl[h] * Wc[h * 10 + threadIdx.x];
    out[g * 10 + threadIdx.x] = a;
  }
}

extern "C" void kernel_launch(void* const* d_in, const int* in_sizes, int n_in,
                              void* d_out, int out_size, void* d_ws, size_t ws_size,
                              hipStream_t stream) {
  const float* x = (const float*)d_in[0];
  const void* ei = d_in[1];
  const void* batch = d_in[2];
  const float* W1 = (const float*)d_in[3];
  const float* b1 = (const float*)d_in[4];
  const float* W2 = (const float*)d_in[5];
  const float* b2 = (const float*)d_in[6];
  const float* W3 = (const float*)d_in[7];
  const float* b3 = (const float*)d_in[8];
  const float* Wc = (const float*)d_in[9];
  const float* bc = (const float*)d_in[10];
  float* out = (float*)d_out;

  const int N = in_sizes[0] / 128;
  const int E = in_sizes[1] / 2;
  const int G = out_size / 10;
  const int cap2 = E / NSUB + E / NSUB / 8 + 64;  // ~12.5% slack (>=10 sigma)

  char* W = (char*)d_ws;
  size_t off = 0;
  auto take = [&](size_t b) -> void* {
    void* p = W + off;
    off += (b + 255) & ~(size_t)255;
    return p;
  };
  int* flag = (int*)take(4);
  int* rowptr = (int*)take((size_t)4 * (N + 1));
  int* scur = (int*)take((size_t)4 * NSUB);            // 2048B, 256-aligned
  float* pooled = (float*)take((size_t)4 * G * 64);    // contiguous after scur
  float* dinv = (float*)take((size_t)4 * N);
  int* csr = (int*)take((size_t)4 * E);
  unsigned short* hsA = (unsigned short*)take((size_t)2 * N * 64);
  unsigned short* hsB = (unsigned short*)take((size_t)2 * N * 64);
  unsigned* ebuf2 = (unsigned*)take((size_t)4 * NSUB * cap2);
  (void)ws_size;

  // one memset covers scur (2048B) + pooled (4*G*64) — contiguous takes
  hipMemsetAsync(scur, 0, (size_t)2048 + (size_t)4 * G * 64, stream);

  k_part<<<512, 1024, 0, stream>>>(ei, E, flag, cap2, scur, ebuf2, N);
  k_build<<<NSUB, 512, 0, stream>>>(ebuf2, scur, cap2, rowptr, dinv, csr, N);

  const int TILES = (N + 63) / 64;
  // layer 1 transform: x (f32) @ W1 -> hsA
  k_gemm_mfma<128, false><<<TILES, 256, 0, stream>>>(x, W1, dinv, hsA, N);
  // fused agg1(b1) + transform W2 -> hsB
  k_agg_gemm<<<TILES, 256, 0, stream>>>(hsA, rowptr, csr, dinv, b1, W2, hsB, N);
  // fused agg2(b2) + transform W3 -> hsA
  k_agg_gemm<<<TILES, 256, 0, stream>>>(hsB, rowptr, csr, dinv, b2, W3, hsA, N);
  // fused agg3(b3) + mean-pool accumulation -> pooled
  k_agg_pool<<<TILES, 256, 0, stream>>>(hsA, rowptr, csr, dinv, b3, batch, flag,
                                        pooled, N);
  // count + divide + FC
  k_cls<<<G, 64, 0, stream>>>(pooled, batch, flag, Wc, bc, out, N);
}

// Round 17
// 292.975 us; speedup vs baseline: 1.4827x; 1.0552x over previous
//
#include <hip/hip_runtime.h>

// ---------------------------------------------------------------------------
// MalwareGNN: 3-layer GCN (transform -> normalized aggregate) + mean pool + FC
//   * CSR build: k_part (512x1024, single ei read: packed edges stashed in
//     registers between count & write passes) -> k_build (inline scur-scan,
//     register-stashed edges)
//   * layer 1: MFMA GEMM x(f32)@W1 -> hsA (bf16, dinv-scaled)
//   * FUSED agg+gemm (1->2, 2->3): 512 thr / 8 waves x 8 nodes; gather-agg
//     into swizzled LDS X-tile -> in-block K=64 MFMA (8 waves: 4 row-groups
//     x 2 col-pairs) -> hs out
//   * FUSED agg3+pool (512 thr): per-wave f32 partial sums per graph
//     (batch sorted); atomicAdd flush at graph boundaries -> pooled
//   * k_cls: per-graph count (binary search) + divide + 10-class FC
//   Gather is AT STRUCTURAL FLOOR (158MB L2-miss @ ~3TB/s, R10-R12 A/Bs).
// ---------------------------------------------------------------------------

#define NSUB 512
#define MAXNODES 256 // >= ceil(N/NSUB); N=100k -> 196 (also packing bound)
#define PSTASH 8

typedef __attribute__((ext_vector_type(8))) short bf16x8;
typedef __attribute__((ext_vector_type(4))) float f32x4;

__device__ __forceinline__ unsigned short f2bf(float x) {
  unsigned u = __float_as_uint(x);
  u += 0x7FFFu + ((u >> 16) & 1u);  // RNE
  return (unsigned short)(u >> 16);
}
__device__ __forceinline__ float bf2f(unsigned short h) {
  return __uint_as_float((unsigned)h << 16);
}
__device__ __forceinline__ float uf(unsigned u) { return __uint_as_float(u); }

// low 4B of index i (values < 2^31 so low word == value)
__device__ __forceinline__ int idx32(const int* p, long long i, bool wide) {
  return __builtin_nontemporal_load(p + (wide ? 2 * i : i));
}

// single-pass 512-bin partition; edges read ONCE (packed into registers in
// the count pass, written from registers in the write pass)
__global__ __launch_bounds__(1024) void k_part(const void* __restrict__ eiv, int E,
                                               int* __restrict__ flag, int cap2,
                                               int* __restrict__ scur,
                                               unsigned* __restrict__ ebuf2, int N) {
  __shared__ int cnt[NSUB];
  __shared__ int base[NSUB];
  __shared__ int off[NSUB];
  __shared__ int s_any;
  const unsigned* eu = (const unsigned*)eiv;
  const int* ei = (const int*)eiv;
  const int tid = threadIdx.x;
  if (tid == 0) s_any = 0;
  __syncthreads();
  unsigned vv = 0;
  for (int i = tid; i < 8192; i += 1024) vv |= eu[2 * i + 1];
  if (vv) atomicOr(&s_any, 1);
  for (int i = tid; i < NSUB; i += 1024) { cnt[i] = 0; off[i] = 0; }
  __syncthreads();
  const bool wide = (s_any == 0);  // int64: high words of first 8192 all zero
  if (blockIdx.x == 0 && tid == 0) *flag = wide ? 1 : 0;
  const int chunk = (E + gridDim.x - 1) / gridDim.x;
  const int c0 = blockIdx.x * chunk;
  const int c1 = (c0 + chunk < E) ? c0 + chunk : E;
  // count pass + stash packed edges (chunk <= PSTASH*1024 for 512 blocks)
  unsigned pk[PSTASH];
  int pb[PSTASH];
#pragma unroll
  for (int j = 0; j < PSTASH; ++j) {
    pb[j] = -1;
    const int e = c0 + j * 1024 + tid;
    if (e < c1) {
      const int d = idx32(ei, (long long)E + e, wide);
      const int s = idx32(ei, e, wide);
      const int b = (int)(((long long)d * NSUB) / N);
      const int nlo = (int)(((long long)N * b + NSUB - 1) / NSUB);
      pk[j] = ((unsigned)(d - nlo) << 24) | (unsigned)s;
      pb[j] = b;
      atomicAdd(&cnt[b], 1);
    }
  }
  for (int e = c0 + PSTASH * 1024 + tid; e < c1; e += 1024) {  // safety tail
    const int d = idx32(ei, (long long)E + e, wide);
    const int b = (int)(((long long)d * NSUB) / N);
    atomicAdd(&cnt[b], 1);
  }
  __syncthreads();
  for (int i = tid; i < NSUB; i += 1024) base[i] = atomicAdd(&scur[i], cnt[i]);
  __syncthreads();
  const long long cap = (long long)NSUB * cap2;
#pragma unroll
  for (int j = 0; j < PSTASH; ++j) {
    if (pb[j] >= 0) {
      const int b = pb[j];
      const int o = atomicAdd(&off[b], 1);
      long long pos = (long long)b * cap2 + base[b] + o;
      if (pos >= cap) pos = cap - 1;  // paranoia clamp (slack makes this dead)
      ebuf2[pos] = pk[j];
    }
  }
  for (int e = c0 + PSTASH * 1024 + tid; e < c1; e += 1024) {  // safety tail
    const int d = idx32(ei, (long long)E + e, wide);
    const int s = idx32(ei, e, wide);
    const int b = (int)(((long long)d * NSUB) / N);
    const int nlo = (int)(((long long)N * b + NSUB - 1) / NSUB);
    const int o = atomicAdd(&off[b], 1);
    long long pos = (long long)b * cap2 + base[b] + o;
    if (pos >= cap) pos = cap - 1;
    ebuf2[pos] = ((unsigned)(d - nlo) << 24) | (unsigned)s;
  }
}

// FUSED per-sub-bucket (512 thr): inline scur scan -> hist (edges stashed in
// registers) -> prefix -> rowptr+dinv -> scatter from registers
#define STASHJ 16
__global__ __launch_bounds__(512) void k_build(const unsigned* __restrict__ ebuf2,
                                               const int* __restrict__ scur, int cap2,
                                               int* __restrict__ rowptr,
                                               float* __restrict__ dinv,
                                               int* __restrict__ csr, int N) {
  __shared__ int sc[NSUB];
  __shared__ int hist[256];
  __shared__ int pref[256];
  const int s = blockIdx.x;
  const int t = threadIdx.x;
  if (t < NSUB) sc[t] = scur[t];
  __syncthreads();
  for (int off = 1; off < NSUB; off <<= 1) {
    int tv = 0;
    if (t < NSUB && t >= off) tv = sc[t - off];
    __syncthreads();
    if (t < NSUB) sc[t] += tv;
    __syncthreads();
  }
  const int mycnt = scur[s];
  const int sb = sc[s] - mycnt;  // exclusive base for this sub-bucket
  const int total = sc[NSUB - 1];
  int nlo = (int)(((long long)N * s + NSUB - 1) / NSUB);
  int nhi = (int)(((long long)N * (s + 1) + NSUB - 1) / NSUB);
  if (nhi > N) nhi = N;
  const int nn = nhi - nlo;
  if (t < 256) hist[t] = 0;
  __syncthreads();
  const long long e0 = (long long)s * cap2;
  const long long e1 = e0 + mycnt;
  unsigned stash[STASHJ];
#pragma unroll
  for (int j = 0; j < STASHJ; ++j) {
    const long long e = e0 + t + (long long)j * 512;
    if (e < e1) {
      const unsigned v = __builtin_nontemporal_load(&ebuf2[e]);
      stash[j] = v;
      atomicAdd(&hist[v >> 24], 1);
    }
  }
  for (long long e = e0 + t + (long long)STASHJ * 512; e < e1; e += 512) {
    const unsigned v = __builtin_nontemporal_load(&ebuf2[e]);
    atomicAdd(&hist[v >> 24], 1);
  }
  __syncthreads();
  int h = 0;
  if (t < 256) {
    h = hist[t];
    pref[t] = h;
  }
  __syncthreads();
  for (int off = 1; off < 256; off <<= 1) {
    int tv = 0;
    if (t < 256 && t >= off) tv = pref[t - off];
    __syncthreads();
    if (t < 256) pref[t] += tv;
    __syncthreads();
  }
  if (t < 256) {
    const int cur0 = sb + pref[t] - h;  // exclusive prefix -> cursor
    if (t < nn) {
      rowptr[nlo + t] = cur0;
      dinv[nlo + t] = rsqrtf((float)(h + 1));  // +1 self loop
    }
    hist[t] = cur0;  // LDS cursors
  }
  if (s == NSUB - 1 && t == 0) rowptr[N] = total;
  __syncthreads();
#pragma unroll
  for (int j = 0; j < STASHJ; ++j) {
    const long long e = e0 + t + (long long)j * 512;
    if (e < e1) {
      const unsigned v = stash[j];
      const int pos = atomicAdd(&hist[v >> 24], 1);
      csr[pos] = (int)(v & 0x00FFFFFFu);
    }
  }
  for (long long e = e0 + t + (long long)STASHJ * 512; e < e1; e += 512) {
    const unsigned v = ebuf2[e];
    const int pos = atomicAdd(&hist[v >> 24], 1);
    csr[pos] = (int)(v & 0x00FFFFFFu);
  }
}

// ---- HS = bf16(dinv * (X @ W)) via MFMA; layer-1 (f32 input, K=128) --------
template <int K, bool BF16IN>
__global__ __launch_bounds__(256) void k_gemm_mfma(const void* __restrict__ Xv,
                                                   const float* __restrict__ Wg,
                                                   const float* __restrict__ dinv,
                                                   unsigned short* __restrict__ HS,
                                                   int N) {
  __shared__ short Xl[64 * K];
  __shared__ short Wt[64 * K];
  const int t = threadIdx.x;
  const long long r0 = (long long)blockIdx.x * 64;
  const int rows = (int)((N - r0) < 64 ? (N - r0) : 64);

  for (int idx = t; idx < K * 64; idx += 256) {
    const int k = idx >> 6, n = idx & 63;
    Wt[n * K + (((k >> 3) ^ (n & 7)) << 3) + (k & 7)] = (short)f2bf(Wg[idx]);
  }
  const int CH = K / 8;
#pragma unroll
  for (int p = 0; p < K / 32; ++p) {
    const int c = p * 256 + t;  // c < 64*CH
    const int row = c / CH, ch = c % CH;
    const int src = (row < rows) ? row : 0;
    bf16x8 h;
    if constexpr (BF16IN) {
      h = *(const bf16x8*)&((const unsigned short*)Xv)[(r0 + src) * K + ch * 8];
    } else {
      const float* X = (const float*)Xv;
      const float4 v0 = *(const float4*)&X[(r0 + src) * K + ch * 8];
      const float4 v1 = *(const float4*)&X[(r0 + src) * K + ch * 8 + 4];
      h[0] = (short)f2bf(v0.x); h[1] = (short)f2bf(v0.y);
      h[2] = (short)f2bf(v0.z); h[3] = (short)f2bf(v0.w);
      h[4] = (short)f2bf(v1.x); h[5] = (short)f2bf(v1.y);
      h[6] = (short)f2bf(v1.z); h[7] = (short)f2bf(v1.w);
    }
    *(bf16x8*)&Xl[row * K + ((ch ^ (row & 7)) << 3)] = h;
  }
  __syncthreads();

  const int lane = t & 63, w = t >> 6;
  const int lo = lane & 15, hi = lane >> 4;
  const int rowa = w * 16 + lo;

  f32x4 acc[4];
#pragma unroll
  for (int i = 0; i < 4; ++i) acc[i] = (f32x4){0.f, 0.f, 0.f, 0.f};

  bf16x8 a[K / 32];
#pragma unroll
  for (int kk = 0; kk < K / 32; ++kk)
    a[kk] = *(const bf16x8*)&Xl[rowa * K + (((kk * 4 + hi) ^ (rowa & 7)) << 3)];

#pragma unroll
  for (int n0 = 0; n0 < 4; ++n0) {
    const int n = n0 * 16 + lo;
#pragma unroll
    for (int kk = 0; kk < K / 32; ++kk) {
      const bf16x8 b = *(const bf16x8*)&Wt[n * K + (((kk * 4 + hi) ^ (n & 7)) << 3)];
      acc[n0] = __builtin_amdgcn_mfma_f32_16x16x32_bf16(a[kk], b, acc[n0], 0, 0, 0);
    }
  }

  float dv[4];
#pragma unroll
  for (int r = 0; r < 4; ++r) {
    const int rr = w * 16 + hi * 4 + r;
    dv[r] = dinv[r0 + (rr < rows ? rr : 0)];
  }
#pragma unroll
  for (int n0 = 0; n0 < 4; ++n0) {
#pragma unroll
    for (int r = 0; r < 4; ++r) {
      const int rr = w * 16 + hi * 4 + r;
      if (rr < rows)
        HS[(r0 + rr) * 64 + n0 * 16 + lo] = f2bf(dv[r] * acc[n0][r]);
    }
  }
}

// ---- FUSED agg + next-layer GEMM (K=64), 512 threads / 8 waves -------------
// Gather: wave owns 8 rows. MFMA: wave w -> rows (w&3)*16, cols (w>>2)*32.
__global__ __launch_bounds__(512) void k_agg_gemm(
    const unsigned short* __restrict__ HSin, const int* __restrict__ rowptr,
    const int* __restrict__ csr, const float* __restrict__ dinv,
    const float* __restrict__ bias, const float* __restrict__ Wg,
    unsigned short* __restrict__ HSout, int N) {
  __shared__ short Xl[64 * 64];
  __shared__ short Wt[64 * 64];
  const int t = threadIdx.x;
  const long long r0 = (long long)blockIdx.x * 64;
  const int rows = (int)((N - r0) < 64 ? (N - r0) : 64);
  for (int idx = t; idx < 64 * 64; idx += 512) {
    const int k = idx >> 6, n = idx & 63;
    Wt[n * 64 + (((k >> 3) ^ (n & 7)) << 3) + (k & 7)] = (short)f2bf(Wg[idx]);
  }
  if (rows < 64) {
    for (int i = t; i < 64 * 64; i += 512) Xl[i] = 0;
  }
  __syncthreads();

  const int lane = t & 63;
  const int wid = t >> 6;
  const int c4 = lane & 15;
  const int q = lane >> 4;
  const float bb0 = bias[4 * c4 + 0], bb1 = bias[4 * c4 + 1];
  const float bb2 = bias[4 * c4 + 2], bb3 = bias[4 * c4 + 3];
  const uint2* __restrict__ H8 = (const uint2*)HSin;
  const unsigned M = 0xffff0000u;
  for (int i = 0; i < 8; ++i) {
    const int row = wid * 8 + i;
    if (row >= rows) break;  // wave-uniform
    const int node = (int)(r0 + row);
    const int s0 = rowptr[node], s1 = rowptr[node + 1];
    float a0 = 0.f, a1 = 0.f, a2 = 0.f, a3 = 0.f;
    float c0 = 0.f, c1 = 0.f, c2 = 0.f, c3 = 0.f;
    if (q == 0) {  // self loop
      const uint2 u = H8[(long long)node * 16 + c4];
      a0 += uf(u.x << 16); a1 += uf(u.x & M);
      a2 += uf(u.y << 16); a3 += uf(u.y & M);
    }
    for (int base = s0; base < s1; base += 64) {
      int m = s1 - base;
      if (m > 64) m = 64;
      const int idx = (base + lane < s1) ? csr[base + lane] : 0;
      const int ng = m >> 2;
      int g = 0;
      for (; g + 2 <= ng; g += 2) {
        const int e0 = __shfl(idx, 4 * g + q, 64);
        const int e1 = __shfl(idx, 4 * g + 4 + q, 64);
        const uint2 u0 = H8[(long long)e0 * 16 + c4];
        const uint2 u1 = H8[(long long)e1 * 16 + c4];
        a0 += uf(u0.x << 16); a1 += uf(u0.x & M);
        a2 += uf(u0.y << 16); a3 += uf(u0.y & M);
        c0 += uf(u1.x << 16); c1 += uf(u1.x & M);
        c2 += uf(u1.y << 16); c3 += uf(u1.y & M);
      }
      for (; g < ng; ++g) {
        const int e0 = __shfl(idx, 4 * g + q, 64);
        const uint2 u0 = H8[(long long)e0 * 16 + c4];
        a0 += uf(u0.x << 16); a1 += uf(u0.x & M);
        a2 += uf(u0.y << 16); a3 += uf(u0.y & M);
      }
      const int rm = m & 3;
      if (rm) {
        const int e = __shfl(idx, (m & ~3) + (q < rm ? q : 0), 64);
        if (q < rm) {
          const uint2 u = H8[(long long)e * 16 + c4];
          a0 += uf(u.x << 16); a1 += uf(u.x & M);
          a2 += uf(u.y << 16); a3 += uf(u.y & M);
        }
      }
    }
    a0 += c0; a1 += c1; a2 += c2; a3 += c3;
    a0 += __shfl_xor(a0, 16, 64); a0 += __shfl_xor(a0, 32, 64);
    a1 += __shfl_xor(a1, 16, 64); a1 += __shfl_xor(a1, 32, 64);
    a2 += __shfl_xor(a2, 16, 64); a2 += __shfl_xor(a2, 32, 64);
    a3 += __shfl_xor(a3, 16, 64); a3 += __shfl_xor(a3, 32, 64);
    if (q == 0) {
      const float dv = dinv[node];
      const unsigned short o0 = f2bf(fmaxf(fmaf(dv, a0, bb0), 0.f));
      const unsigned short o1 = f2bf(fmaxf(fmaf(dv, a1, bb1), 0.f));
      const unsigned short o2 = f2bf(fmaxf(fmaf(dv, a2, bb2), 0.f));
      const unsigned short o3 = f2bf(fmaxf(fmaf(dv, a3, bb3), 0.f));
      uint2 o;
      o.x = (unsigned)o0 | ((unsigned)o1 << 16);
      o.y = (unsigned)o2 | ((unsigned)o3 << 16);
      const int ch = c4 >> 1;
      *(uint2*)&Xl[row * 64 + ((ch ^ (row & 7)) << 3) + (c4 & 1) * 4] = o;
    }
  }
  __syncthreads();

  // MFMA: 8 waves = 4 row-groups x 2 col-pairs
  const int lo = lane & 15, hi = lane >> 4;
  const int wrow = (wid & 3) * 16;
  const int wcol = (wid >> 2) * 2;  // first n0 of this wave's pair
  const int rowa = wrow + lo;
  f32x4 acc[2];
#pragma unroll
  for (int i = 0; i < 2; ++i) acc[i] = (f32x4){0.f, 0.f, 0.f, 0.f};
  bf16x8 a[2];
#pragma unroll
  for (int kk = 0; kk < 2; ++kk)
    a[kk] = *(const bf16x8*)&Xl[rowa * 64 + (((kk * 4 + hi) ^ (rowa & 7)) << 3)];
#pragma unroll
  for (int p = 0; p < 2; ++p) {
    const int n = (wcol + p) * 16 + lo;
#pragma unroll
    for (int kk = 0; kk < 2; ++kk) {
      const bf16x8 b = *(const bf16x8*)&Wt[n * 64 + (((kk * 4 + hi) ^ (n & 7)) << 3)];
      acc[p] = __builtin_amdgcn_mfma_f32_16x16x32_bf16(a[kk], b, acc[p], 0, 0, 0);
    }
  }
  float dvv[4];
#pragma unroll
  for (int r = 0; r < 4; ++r) {
    const int rr = wrow + hi * 4 + r;
    dvv[r] = dinv[r0 + (rr < rows ? rr : 0)];
  }
#pragma unroll
  for (int p = 0; p < 2; ++p) {
#pragma unroll
    for (int r = 0; r < 4; ++r) {
      const int rr = wrow + hi * 4 + r;
      if (rr < rows)
        HSout[(r0 + rr) * 64 + (wcol + p) * 16 + lo] = f2bf(dvv[r] * acc[p][r]);
    }
  }
}

// ---- FUSED agg3 + pool (512 thr): per-wave graph partial sums --------------
__global__ __launch_bounds__(512) void k_agg_pool(
    const unsigned short* __restrict__ HS, const int* __restrict__ rowptr,
    const int* __restrict__ csr, const float* __restrict__ dinv,
    const float* __restrict__ bias, const void* __restrict__ batch,
    const int* __restrict__ flag, float* __restrict__ pooled, int N) {
  const int t = threadIdx.x;
  const long long r0 = (long long)blockIdx.x * 64;
  const int rows = (int)((N - r0) < 64 ? (N - r0) : 64);
  const int lane = t & 63;
  const int wid = t >> 6;
  const int c4 = lane & 15;
  const int q = lane >> 4;
  const bool wideB = (*flag != 0);
  const int* bi = (const int*)batch;
  const float bb0 = bias[4 * c4 + 0], bb1 = bias[4 * c4 + 1];
  const float bb2 = bias[4 * c4 + 2], bb3 = bias[4 * c4 + 3];
  const uint2* __restrict__ H8 = (const uint2*)HS;
  const unsigned M = 0xffff0000u;
  float ps0 = 0.f, ps1 = 0.f, ps2 = 0.f, ps3 = 0.f;
  int gcur = -1;
  for (int i = 0; i < 8; ++i) {
    const int row = wid * 8 + i;
    if (row >= rows) break;  // wave-uniform
    const int node = (int)(r0 + row);
    const int g = wideB ? (int)((const long long*)batch)[node] : bi[node];
    const int s0 = rowptr[node], s1 = rowptr[node + 1];
    float a0 = 0.f, a1 = 0.f, a2 = 0.f, a3 = 0.f;
    float c0 = 0.f, c1 = 0.f, c2 = 0.f, c3 = 0.f;
    if (q == 0) {  // self loop
      const uint2 u = H8[(long long)node * 16 + c4];
      a0 += uf(u.x << 16); a1 += uf(u.x & M);
      a2 += uf(u.y << 16); a3 += uf(u.y & M);
    }
    for (int base = s0; base < s1; base += 64) {
      int m = s1 - base;
      if (m > 64) m = 64;
      const int idx = (base + lane < s1) ? csr[base + lane] : 0;
      const int ng = m >> 2;
      int gg = 0;
      for (; gg + 2 <= ng; gg += 2) {
        const int e0 = __shfl(idx, 4 * gg + q, 64);
        const int e1 = __shfl(idx, 4 * gg + 4 + q, 64);
        const uint2 u0 = H8[(long long)e0 * 16 + c4];
        const uint2 u1 = H8[(long long)e1 * 16 + c4];
        a0 += uf(u0.x << 16); a1 += uf(u0.x & M);
        a2 += uf(u0.y << 16); a3 += uf(u0.y & M);
        c0 += uf(u1.x << 16); c1 += uf(u1.x & M);
        c2 += uf(u1.y << 16); c3 += uf(u1.y & M);
      }
      for (; gg < ng; ++gg) {
        const int e0 = __shfl(idx, 4 * gg + q, 64);
        const uint2 u0 = H8[(long long)e0 * 16 + c4];
        a0 += uf(u0.x << 16); a1 += uf(u0.x & M);
        a2 += uf(u0.y << 16); a3 += uf(u0.y & M);
      }
      const int rm = m & 3;
      if (rm) {
        const int e = __shfl(idx, (m & ~3) + (q < rm ? q : 0), 64);
        if (q < rm) {
          const uint2 u = H8[(long long)e * 16 + c4];
          a0 += uf(u.x << 16); a1 += uf(u.x & M);
          a2 += uf(u.y << 16); a3 += uf(u.y & M);
        }
      }
    }
    a0 += c0; a1 += c1; a2 += c2; a3 += c3;
    a0 += __shfl_xor(a0, 16, 64); a0 += __shfl_xor(a0, 32, 64);
    a1 += __shfl_xor(a1, 16, 64); a1 += __shfl_xor(a1, 32, 64);
    a2 += __shfl_xor(a2, 16, 64); a2 += __shfl_xor(a2, 32, 64);
    a3 += __shfl_xor(a3, 16, 64); a3 += __shfl_xor(a3, 32, 64);
    if (g != gcur) {  // flush on graph boundary (wave-uniform g)
      if (gcur >= 0 && q == 0) {
        atomicAdd(&pooled[gcur * 64 + 4 * c4 + 0], ps0);
        atomicAdd(&pooled[gcur * 64 + 4 * c4 + 1], ps1);
        atomicAdd(&pooled[gcur * 64 + 4 * c4 + 2], ps2);
        atomicAdd(&pooled[gcur * 64 + 4 * c4 + 3], ps3);
      }
      ps0 = ps1 = ps2 = ps3 = 0.f;
      gcur = g;
    }
    if (q == 0) {
      const float dv = dinv[node];
      ps0 += fmaxf(fmaf(dv, a0, bb0), 0.f);
      ps1 += fmaxf(fmaf(dv, a1, bb1), 0.f);
      ps2 += fmaxf(fmaf(dv, a2, bb2), 0.f);
      ps3 += fmaxf(fmaf(dv, a3, bb3), 0.f);
    }
  }
  if (gcur >= 0 && q == 0) {
    atomicAdd(&pooled[gcur * 64 + 4 * c4 + 0], ps0);
    atomicAdd(&pooled[gcur * 64 + 4 * c4 + 1], ps1);
    atomicAdd(&pooled[gcur * 64 + 4 * c4 + 2], ps2);
    atomicAdd(&pooled[gcur * 64 + 4 * c4 + 3], ps3);
  }
}

// ---- per-graph count + divide + FC ------------------------------------------
__global__ __launch_bounds__(64) void k_cls(const float* __restrict__ pooled,
                                            const void* __restrict__ batch,
                                            const int* __restrict__ flag,
                                            const float* __restrict__ Wc,
                                            const float* __restrict__ bc,
                                            float* __restrict__ out, int N) {
  __shared__ int se[2];
  __shared__ float pl[64];
  const bool wide = (*flag != 0);
  const int g = blockIdx.x;
  if (threadIdx.x < 2) {
    int target = g + threadIdx.x;
    int lo = 0, hi = N;
    while (lo < hi) {
      int mid = (lo + hi) >> 1;
      long long v = wide ? ((const long long*)batch)[mid] : (long long)((const int*)batch)[mid];
      if (v < target) lo = mid + 1; else hi = mid;
    }
    se[threadIdx.x] = lo;
  }
  __syncthreads();
  const float cnt = (float)(se[1] - se[0]);
  pl[threadIdx.x] = pooled[g * 64 + threadIdx.x] / fmaxf(cnt, 1.f);
  __syncthreads();
  if (threadIdx.x < 10) {
    float a = bc[threadIdx.x];
#pragma unroll
    for (int h = 0; h < 64; ++h) a += pl[h] * Wc[h * 10 + threadIdx.x];
    out[g * 10 + threadIdx.x] = a;
  }
}

extern "C" void kernel_launch(void* const* d_in, const int* in_sizes, int n_in,
                              void* d_out, int out_size, void* d_ws, size_t ws_size,
                              hipStream_t stream) {
  const float* x = (const float*)d_in[0];
  const void* ei = d_in[1];
  const void* batch = d_in[2];
  const float* W1 = (const float*)d_in[3];
  const float* b1 = (const float*)d_in[4];
  const float* W2 = (const float*)d_in[5];
  const float* b2 = (const float*)d_in[6];
  const float* W3 = (const float*)d_in[7];
  const float* b3 = (const float*)d_in[8];
  const float* Wc = (const float*)d_in[9];
  const float* bc = (const float*)d_in[10];
  float* out = (float*)d_out;

  const int N = in_sizes[0] / 128;
  const int E = in_sizes[1] / 2;
  const int G = out_size / 10;
  const int cap2 = E / NSUB + E / NSUB / 8 + 64;  // ~12.5% slack (>=10 sigma)

  char* W = (char*)d_ws;
  size_t off = 0;
  auto take = [&](size_t b) -> void* {
    void* p = W + off;
    off += (b + 255) & ~(size_t)255;
    return p;
  };
  int* flag = (int*)take(4);
  int* rowptr = (int*)take((size_t)4 * (N + 1));
  int* scur = (int*)take((size_t)4 * NSUB);            // 2048B, 256-aligned
  float* pooled = (float*)take((size_t)4 * G * 64);    // contiguous after scur
  float* dinv = (float*)take((size_t)4 * N);
  int* csr = (int*)take((size_t)4 * E);
  unsigned short* hsA = (unsigned short*)take((size_t)2 * N * 64);
  unsigned short* hsB = (unsigned short*)take((size_t)2 * N * 64);
  unsigned* ebuf2 = (unsigned*)take((size_t)4 * NSUB * cap2);
  (void)ws_size;

  // one memset covers scur (2048B) + pooled (4*G*64) — contiguous takes
  hipMemsetAsync(scur, 0, (size_t)2048 + (size_t)4 * G * 64, stream);

  k_part<<<512, 1024, 0, stream>>>(ei, E, flag, cap2, scur, ebuf2, N);
  k_build<<<NSUB, 512, 0, stream>>>(ebuf2, scur, cap2, rowptr, dinv, csr, N);

  const int TILES = (N + 63) / 64;
  // layer 1 transform: x (f32) @ W1 -> hsA
  k_gemm_mfma<128, false><<<TILES, 256, 0, stream>>>(x, W1, dinv, hsA, N);
  // fused agg1(b1) + transform W2 -> hsB
  k_agg_gemm<<<TILES, 512, 0, stream>>>(hsA, rowptr, csr, dinv, b1, W2, hsB, N);
  // fused agg2(b2) + transform W3 -> hsA
  k_agg_gemm<<<TILES, 512, 0, stream>>>(hsB, rowptr, csr, dinv, b2, W3, hsA, N);
  // fused agg3(b3) + mean-pool accumulation -> pooled
  k_agg_pool<<<TILES, 512, 0, stream>>>(hsA, rowptr, csr, dinv, b3, batch, flag,
                                        pooled, N);
  // count + divide + FC
  k_cls<<<G, 64, 0, stream>>>(pooled, batch, flag, Wc, bc, out, N);
}